// Round 8
// baseline (1536.564 us; speedup 1.0000x reference)
//
#include <hip/hip_runtime.h>
#include <math.h>

// B=8, C=128, H=128, W=128, D_INNER=256, D_STATE=64, HEADDIM=32, NHEADS=8,
// D_CONV=4, GN_GROUPS=8, D_XBC=384, D_INPROJ=648.
// Inputs f32 (probed via gn_g word0). OUTPUT IS F32 (reference output dtype).
// d_out = [out_2d: 16,777,216 f32][offset: 131,072 f32].
// h1 (f32) is staged in d_out's out_2d region.
// NOTE: Round 7 bench failed with UnresponsiveContainer (infra); this is an
// unchanged resubmit of the v4-GEMM kernel for a clean measurement.

__device__ __forceinline__ float b2f(unsigned short u) {
  return __uint_as_float(((unsigned int)u) << 16);
}
__device__ __forceinline__ bool in_is_f32(const void* gng) {
  return ((const unsigned int*)gng)[0] == 0x3F800000u;
}

// Sum over the 4-lane quad (lane&3 butterfly). DPP quad_perm keeps it on the
// VALU pipe (ds_bpermute would hit the LDS pipe we're trying to unload).
__device__ __forceinline__ float quad_sum(float v) {
#if __has_builtin(__builtin_amdgcn_update_dpp)
  int p = __builtin_amdgcn_update_dpp(0, __float_as_int(v), 0xB1, 0xF, 0xF, true);
  v += __int_as_float(p);  // xor 1 (quad_perm [1,0,3,2])
  p = __builtin_amdgcn_update_dpp(0, __float_as_int(v), 0x4E, 0xF, 0xF, true);
  v += __int_as_float(p);  // xor 2 (quad_perm [2,3,0,1])
#else
  v += __shfl_xor(v, 1, 64);
  v += __shfl_xor(v, 2, 64);
#endif
  return v;
}

#define P_DWW 0
#define P_CW 3200
#define P_CB 4736
#define P_GNG 5120
#define P_GNB 5248
#define P_PWW 5376
#define P_PWB 5504
#define P_DTB 5505
#define P_ALOG 5513
#define P_DSKIP 5521
#define P_NG 5529

__global__ void k_prep_params(const void* dww, const void* cw, const void* cb,
                              const void* gng, const void* gnb, const void* pww,
                              const void* pwb, const void* dtbias, const void* alog,
                              const void* dskip, const void* ng, float* __restrict__ P,
                              float* __restrict__ gst) {
  bool f = in_is_f32(gng);
  int tid = threadIdx.x;
  if (tid < 128) gst[tid] = 0.f;
  auto cvt = [&](const void* src, int n, int off) {
    for (int i = tid; i < n; i += 256)
      P[off + i] = f ? ((const float*)src)[i] : b2f(((const unsigned short*)src)[i]);
  };
  cvt(dww, 3200, P_DWW);
  cvt(cw, 1536, P_CW);
  cvt(cb, 384, P_CB);
  cvt(gng, 128, P_GNG);
  cvt(gnb, 128, P_GNB);
  cvt(pww, 128, P_PWW);
  cvt(pwb, 1, P_PWB);
  cvt(dtbias, 8, P_DTB);
  cvt(alog, 8, P_ALOG);
  cvt(dskip, 8, P_DSKIP);
  cvt(ng, 256, P_NG);
}

__global__ void k_prep_w(const void* wproj, const void* outw, const void* gng,
                         float* __restrict__ wprojf, float* __restrict__ outwf) {
  bool f = in_is_f32(gng);
  int stride = gridDim.x * blockDim.x;
  for (int i = blockIdx.x * blockDim.x + threadIdx.x; i < 82944; i += stride)
    wprojf[i] = f ? ((const float*)wproj)[i] : b2f(((const unsigned short*)wproj)[i]);
  for (int i = blockIdx.x * blockDim.x + threadIdx.x; i < 32768; i += stride)
    outwf[i] = f ? ((const float*)outw)[i] : b2f(((const unsigned short*)outw)[i]);
}

// ---------------- K1 v2: depthwise 5x5 conv + group stats ------------------------
// f32 tile, column-sliding walk with 5-slot output ring (compile-time indices).
template <int H0>
__device__ __forceinline__ void dw_col(const float* __restrict__ t,
                                       const float* __restrict__ w, int col,
                                       float* __restrict__ h1, size_t outbase,
                                       float& s, float& sq) {
  float acc[5] = {0.f, 0.f, 0.f, 0.f, 0.f};
#pragma unroll
  for (int u = 0; u < 5; ++u) {
    int r = H0 + u;
    const float* row = t + r * 136 + col + 2;
    float v0 = row[0], v1 = row[1], v2 = row[2], v3 = row[3], v4 = row[4];
#pragma unroll
    for (int ky = 0; ky <= u; ++ky) {
      int sl = (H0 + u + 5 - ky) % 5;
      acc[sl] += w[ky * 5 + 0] * v0 + w[ky * 5 + 1] * v1 + w[ky * 5 + 2] * v2 +
                 w[ky * 5 + 3] * v3 + w[ky * 5 + 4] * v4;
    }
    if (u == 4) {
      int sl = H0 % 5;
      float ov = acc[sl];
      h1[outbase + (size_t)H0 * 128 + col] = ov;
      s += ov; sq += ov * ov;
      acc[sl] = 0.f;
    }
  }
  for (int o = 1; o < 13; ++o) {
#pragma unroll
    for (int u = 0; u < 5; ++u) {
      int r = H0 + o * 5 + u;
      const float* row = t + r * 136 + col + 2;
      float v0 = row[0], v1 = row[1], v2 = row[2], v3 = row[3], v4 = row[4];
#pragma unroll
      for (int ky = 0; ky < 5; ++ky) {
        int sl = (H0 + u + 5 - ky) % 5;
        acc[sl] += w[ky * 5 + 0] * v0 + w[ky * 5 + 1] * v1 + w[ky * 5 + 2] * v2 +
                   w[ky * 5 + 3] * v3 + w[ky * 5 + 4] * v4;
      }
      int dy = r - 4;
      int sl = (H0 + u + 1) % 5;
      float ov = acc[sl];
      h1[outbase + (size_t)dy * 128 + col] = ov;
      s += ov; sq += ov * ov;
      acc[sl] = 0.f;
    }
  }
#pragma unroll
  for (int u = 0; u < 3; ++u) {
    int r = H0 + 65 + u;
    const float* row = t + r * 136 + col + 2;
    float v0 = row[0], v1 = row[1], v2 = row[2], v3 = row[3], v4 = row[4];
#pragma unroll
    for (int ky = 0; ky < 5; ++ky) {
      int sl = (H0 + u + 5 - ky) % 5;
      acc[sl] += w[ky * 5 + 0] * v0 + w[ky * 5 + 1] * v1 + w[ky * 5 + 2] * v2 +
                 w[ky * 5 + 3] * v3 + w[ky * 5 + 4] * v4;
    }
    int dy = r - 4;
    int sl = (H0 + u + 1) % 5;
    float ov = acc[sl];
    h1[outbase + (size_t)dy * 128 + col] = ov;
    s += ov; sq += ov * ov;
    acc[sl] = 0.f;
  }
}

__global__ __launch_bounds__(256) void k_dwconv_v2(const void* __restrict__ x,
                                                   const void* __restrict__ gng,
                                                   const float* __restrict__ P,
                                                   float* __restrict__ h1,
                                                   float* __restrict__ gst) {
  int bc = blockIdx.x;
  int b = bc >> 7, chan = bc & 127;
  bool f32x = in_is_f32(gng);
  __shared__ __align__(16) float t[132 * 136];  // 71,808 B
  __shared__ float red[8];
  for (int i = threadIdx.x; i < (132 * 136) / 4; i += 256)
    ((float4*)t)[i] = make_float4(0.f, 0.f, 0.f, 0.f);
  __syncthreads();
  const float* xf = (const float*)x + (size_t)bc * 16384;
  const unsigned short* xb = (const unsigned short*)x + (size_t)bc * 16384;
  for (int i = threadIdx.x; i < 4096; i += 256) {
    int dy = i >> 5, dc = (i & 31) * 4;
    float4 v;
    if (f32x) {
      v = *(const float4*)&xf[i * 4];
    } else {
      ushort4 r4 = *(const ushort4*)&xb[i * 4];
      v = make_float4(b2f(r4.x), b2f(r4.y), b2f(r4.z), b2f(r4.w));
    }
    *(float4*)&t[(dy + 2) * 136 + dc + 4] = v;
  }
  float w[25];
#pragma unroll
  for (int k = 0; k < 25; ++k) w[k] = P[P_DWW + chan * 25 + k];
  __syncthreads();
  int col = threadIdx.x & 127;
  float s = 0.f, sq = 0.f;
  size_t outbase = (size_t)bc * 16384;
  if (threadIdx.x < 128) dw_col<0>(t, w, col, h1, outbase, s, sq);
  else                   dw_col<64>(t, w, col, h1, outbase, s, sq);
  for (int o = 32; o; o >>= 1) { s += __shfl_down(s, o, 64); sq += __shfl_down(sq, o, 64); }
  int wv = threadIdx.x >> 6;
  if ((threadIdx.x & 63) == 0) { red[wv] = s; red[4 + wv] = sq; }
  __syncthreads();
  if (threadIdx.x == 0) {
    float ts = red[0] + red[1] + red[2] + red[3];
    float tq = red[4] + red[5] + red[6] + red[7];
    int g = (b << 3) + (chan >> 4);
    atomicAdd(&gst[g * 2], ts);
    atomicAdd(&gst[g * 2 + 1], tq);
  }
}

__global__ void k_stats(const float* __restrict__ gst, float* __restrict__ mr) {
  int g = threadIdx.x;
  if (g < 64) {
    const float invN = 1.f / 262144.f;
    float mean = gst[g * 2] * invN;
    float var = gst[g * 2 + 1] * invN - mean * mean;
    mr[g * 2] = mean;
    mr[g * 2 + 1] = rsqrtf(var + 1e-5f);
  }
}

// ---------------- K3: GN + exact GELU + 1x1 conv + tanh*8 -> offset (f32 out) ----
__global__ __launch_bounds__(128) void k_gn_off(const float* __restrict__ h1,
                                                const float* __restrict__ mr,
                                                const float* __restrict__ P,
                                                float* __restrict__ offf,
                                                float* __restrict__ dout) {
  int bh = blockIdx.x;
  int b = bh >> 7, h = bh & 127;
  int w = threadIdx.x;
  float acc = 0.f;
  for (int c = 0; c < 128; ++c) {
    float v = h1[(((size_t)(b * 128 + c)) * 128 + h) * 128 + w];
    int g = b * 8 + (c >> 4);
    float nv = (v - mr[g * 2]) * mr[g * 2 + 1] * P[P_GNG + c] + P[P_GNB + c];
    float ge = 0.5f * nv * (1.f + erff(nv * 0.70710678118f));
    acc += ge * P[P_PWW + c];
  }
  float off = acc + P[P_PWB];
  float ofv = tanhf(off) * 8.0f;
  offf[bh * 128 + w] = ofv;
  dout[16777216 + bh * 128 + w] = ofv;
}

// ---------------- K4 v2: grid sample + transpose, 256 threads --------------------
__global__ __launch_bounds__(256) void k_deform_v2(const void* __restrict__ x,
                                                   const void* __restrict__ gng,
                                                   const float* __restrict__ offf,
                                                   float* __restrict__ seqc,
                                                   int s0) {
  int bh = s0 + blockIdx.x;
  int b = bh >> 7, h = bh & 127;
  int w = threadIdx.x & 127;
  int half = threadIdx.x >> 7;  // 0..1
  bool f32x = in_is_f32(gng);
  __shared__ float t[128 * 129];
  float ofv = offf[bh * 128 + w];
  float gy = -1.f + (2.f / 127.f) * (float)h + ofv * (2.f / 127.f);
  gy = fminf(fmaxf(gy, -1.f), 1.f);
  float py = (gy + 1.f) * 0.5f * 127.f;
  py = fminf(fmaxf(py, 0.f), 127.f);
  float y0f = floorf(py);
  float wy = py - y0f;
  int y0 = (int)y0f;
  int y1 = min(y0 + 1, 127);
  const float* xfb = (const float*)x + (size_t)b * 128 * 16384;
  const unsigned short* xbb = (const unsigned short*)x + (size_t)b * 128 * 16384;
  for (int c = half * 64; c < half * 64 + 64; ++c) {
    size_t o0 = (size_t)c * 16384 + y0 * 128 + w;
    size_t o1 = (size_t)c * 16384 + y1 * 128 + w;
    float v0, v1;
    if (f32x) { v0 = xfb[o0]; v1 = xfb[o1]; }
    else      { v0 = b2f(xbb[o0]); v1 = b2f(xbb[o1]); }
    t[c * 129 + w] = v0 + wy * (v1 - v0);
  }
  __syncthreads();
  int c = threadIdx.x & 127;
  float* sp = seqc + (size_t)blockIdx.x * 16384;
  for (int l = half * 64; l < half * 64 + 64; ++l) sp[l * 128 + c] = t[c * 129 + l];
}

// ---------------- G1 v4: zxbcdt = seq @ wproj^T — 128x128 tile, 8x8/thread -------
// v3 (64x64, 4x4) was LDS-BW bound: 32 B LDS per 32 FLOP (1 FLOP/B) vs the CU
// balance point of 4 FLOP/B -> 46 TF, VALUBusy 56%. v4: 8x8/thread = 64 B per
// 128 FLOP; A-reads are 16-lane broadcast (4 distinct addrs/wave, ~free).
// LDS 33.8 KB -> 4 blocks/CU; launch_bounds(256,4) caps VGPR at 128 (acc 64).
__global__ __launch_bounds__(256, 4) void k_gemm1_v4(const float* __restrict__ seqp,
                                                     const float* __restrict__ wproj,
                                                     const float* __restrict__ P,
                                                     float* __restrict__ z,
                                                     float* __restrict__ xbc,
                                                     float* __restrict__ dtb) {
  __shared__ float As[32 * 132];  // [k][m]
  __shared__ float Bs[32 * 132];  // [k][e]
  int m0 = blockIdx.x * 128;
  int e0 = blockIdx.y * 128;      // 0,128,...,640 (y=5 masked to 648)
  int tx = threadIdx.x & 15;      // e octet
  int ty = threadIdx.x >> 4;      // m octet
  float acc[8][8] = {};
  for (int kt = 0; kt < 128; kt += 32) {
    for (int i = threadIdx.x; i < 1024; i += 256) {
      int m = i >> 3, k4 = (i & 7) * 4;
      float4 v = *(const float4*)&seqp[(size_t)(m0 + m) * 128 + kt + k4];
      As[(k4 + 0) * 132 + m] = v.x;
      As[(k4 + 1) * 132 + m] = v.y;
      As[(k4 + 2) * 132 + m] = v.z;
      As[(k4 + 3) * 132 + m] = v.w;
      int e = e0 + m;
      float4 wv = (e < 648) ? *(const float4*)&wproj[(size_t)e * 128 + kt + k4]
                            : make_float4(0.f, 0.f, 0.f, 0.f);
      Bs[(k4 + 0) * 132 + m] = wv.x;
      Bs[(k4 + 1) * 132 + m] = wv.y;
      Bs[(k4 + 2) * 132 + m] = wv.z;
      Bs[(k4 + 3) * 132 + m] = wv.w;
    }
    __syncthreads();
#pragma unroll 4
    for (int k = 0; k < 32; ++k) {
      const float* ar = &As[k * 132 + ty * 8];
      const float* br = &Bs[k * 132 + tx * 8];
      float4 a0 = *(const float4*)ar, a1 = *(const float4*)(ar + 4);
      float4 b0 = *(const float4*)br, b1 = *(const float4*)(br + 4);
      float av[8] = {a0.x, a0.y, a0.z, a0.w, a1.x, a1.y, a1.z, a1.w};
      float bv[8] = {b0.x, b0.y, b0.z, b0.w, b1.x, b1.y, b1.z, b1.w};
#pragma unroll
      for (int i = 0; i < 8; ++i)
#pragma unroll
        for (int j = 0; j < 8; ++j) acc[i][j] += av[i] * bv[j];
    }
    __syncthreads();
  }
#pragma unroll
  for (int i = 0; i < 8; ++i) {
    int m = m0 + ty * 8 + i;
#pragma unroll
    for (int j = 0; j < 8; ++j) {
      int e = e0 + tx * 8 + j;
      float v = acc[i][j];
      if (e < 256) {
        z[(size_t)m * 256 + e] = v;
      } else if (e < 640) {
        xbc[(size_t)m * 384 + (e - 256)] = v;
      } else if (e < 648) {
        float dv = v + P[P_DTB + e - 640];
        float sp = (dv > 20.f) ? dv : log1pf(__expf(dv));
        dtb[(size_t)m * 8 + (e - 640)] = sp;
      }
    }
  }
}

// ---------------- K5 v3: causal conv1d + SiLU, IN-PLACE --------------------------
__global__ __launch_bounds__(256) void k_conv1d_v3(float* __restrict__ xbc,
                                                   const float* __restrict__ P) {
  float* buf = xbc + (size_t)blockIdx.x * 49152;   // 128*384
  for (int e = threadIdx.x; e < 384; e += 256) {
    float w0 = P[P_CW + e * 4 + 0], w1 = P[P_CW + e * 4 + 1];
    float w2 = P[P_CW + e * 4 + 2], w3 = P[P_CW + e * 4 + 3];
    float bb = P[P_CB + e];
    float x0 = 0.f, x1 = 0.f, x2 = 0.f;
    for (int l = 0; l < 128; ++l) {
      float x3 = buf[l * 384 + e];
      float a = bb + w0 * x0 + w1 * x1 + w2 * x2 + w3 * x3;
      buf[l * 384 + e] = a / (1.f + __expf(-a));
      x0 = x1; x1 = x2; x2 = x3;
    }
  }
}

// ---------------- K6 v5: selective scan — (d,s)-split, 512 threads ---------------
__global__ __launch_bounds__(512) void k_scan_v5(const float* __restrict__ pc,
                                                 const float* __restrict__ dtb,
                                                 const float* __restrict__ P,
                                                 float* __restrict__ ys) {
  int seq = blockIdx.x;
  int head = threadIdx.x >> 6;          // 0..7 (one wave per head)
  int dduo = (threadIdx.x >> 2) & 15;   // d = dduo*2 + {0,1}
  int squad = threadIdx.x & 3;          // s-range squad*16 .. +15
  float A = -__expf(P[P_ALOG + head]);
  float Dk = P[P_DSKIP + head];
  float h0[16], h1[16];
#pragma unroll
  for (int s = 0; s < 16; ++s) { h0[s] = 0.f; h1[s] = 0.f; }
  __shared__ __align__(16) float sROW[16][384];  // x[0..255] | B[256..319] | C[320..383]
  __shared__ float sDT[16][8];
  const float* base = pc + (size_t)seq * 49152;
  const float* dtp = dtb + (size_t)seq * 1024;
  float* yp = ys + (size_t)seq * 32768;
  const int sbase = 256 + squad * 16;
  const int cbase = sbase + 64;
  for (int lt = 0; lt < 128; lt += 16) {
    const float* gsrc = base + (size_t)lt * 384;
    for (int i = threadIdx.x; i < 1536; i += 512) {
      int ll = i / 96, c4 = i % 96;
      *(float4*)&sROW[ll][c4 * 4] = *(const float4*)&gsrc[ll * 384 + c4 * 4];
    }
    if (threadIdx.x < 128)
      sDT[threadIdx.x >> 3][threadIdx.x & 7] =
          dtp[(lt + (threadIdx.x >> 3)) * 8 + (threadIdx.x & 7)];
    __syncthreads();
#pragma unroll 1
    for (int ll = 0; ll < 16; ++ll) {
      float dt = sDT[ll][head];
      float dA = __expf(dt * A);
      float2 xv = *(const float2*)&sROW[ll][head * 32 + dduo * 2];
      float c0 = dt * xv.x, c1 = dt * xv.y;
      float a0 = 0.f, b0 = 0.f, a1 = 0.f, b1 = 0.f;
#pragma unroll
      for (int s4 = 0; s4 < 4; ++s4) {
        float4 bb = *(const float4*)&sROW[ll][sbase + s4 * 4];
        float4 cc = *(const float4*)&sROW[ll][cbase + s4 * 4];
        h0[s4 * 4 + 0] = h0[s4 * 4 + 0] * dA + c0 * bb.x; a0 += h0[s4 * 4 + 0] * cc.x;
        h0[s4 * 4 + 1] = h0[s4 * 4 + 1] * dA + c0 * bb.y; b0 += h0[s4 * 4 + 1] * cc.y;
        h0[s4 * 4 + 2] = h0[s4 * 4 + 2] * dA + c0 * bb.z; a0 += h0[s4 * 4 + 2] * cc.z;
        h0[s4 * 4 + 3] = h0[s4 * 4 + 3] * dA + c0 * bb.w; b0 += h0[s4 * 4 + 3] * cc.w;
        h1[s4 * 4 + 0] = h1[s4 * 4 + 0] * dA + c1 * bb.x; a1 += h1[s4 * 4 + 0] * cc.x;
        h1[s4 * 4 + 1] = h1[s4 * 4 + 1] * dA + c1 * bb.y; b1 += h1[s4 * 4 + 1] * cc.y;
        h1[s4 * 4 + 2] = h1[s4 * 4 + 2] * dA + c1 * bb.z; a1 += h1[s4 * 4 + 2] * cc.z;
        h1[s4 * 4 + 3] = h1[s4 * 4 + 3] * dA + c1 * bb.w; b1 += h1[s4 * 4 + 3] * cc.w;
      }
      float y0 = quad_sum(a0 + b0);
      float y1 = quad_sum(a1 + b1);
      if (squad == 0) {
        float2 o = make_float2(y0 + Dk * xv.x, y1 + Dk * xv.y);
        *(float2*)&yp[(size_t)(lt + ll) * 256 + head * 32 + dduo * 2] = o;
      }
    }
    __syncthreads();
  }
}

// ---------------- K7 v3: gate + RMS norm, IN-PLACE (ynorm over ys) ---------------
__global__ __launch_bounds__(256) void k_gate_v3(float* __restrict__ ys,
                                                 const float* __restrict__ z,
                                                 const float* __restrict__ P) {
  int l = blockIdx.x;
  int e = threadIdx.x;
  __shared__ float red[4];
  float yv = ys[(size_t)l * 256 + e];
  float zv = z[(size_t)l * 256 + e];
  float g = zv / (1.f + __expf(-zv));
  float y = yv * g;
  float ss = y * y;
  for (int o = 32; o; o >>= 1) ss += __shfl_down(ss, o, 64);
  if ((threadIdx.x & 63) == 0) red[threadIdx.x >> 6] = ss;
  __syncthreads();
  float tot = red[0] + red[1] + red[2] + red[3];
  float r = rsqrtf(tot * (1.f / 256.f) + 1e-5f);
  ys[(size_t)l * 256 + e] = y * r * P[P_NG + e];
}

// ---------------- G2 v4: out GEMM — 128x128 tile, 8x8/thread, f32 NCHW store -----
__global__ __launch_bounds__(256, 4) void k_gemm2_v4(const float* __restrict__ ynorm,
                                                     const float* __restrict__ outw,
                                                     float* __restrict__ dout,
                                                     int tok0) {
  __shared__ float As[32 * 132];  // [k][token]
  __shared__ float Bs[32 * 132];  // [k][c]
  int t0 = blockIdx.x * 128;
  int tx = threadIdx.x & 15;      // c octet
  int ty = threadIdx.x >> 4;      // token octet
  float acc[8][8] = {};
  for (int kt = 0; kt < 256; kt += 32) {
    for (int i = threadIdx.x; i < 1024; i += 256) {
      int m = i >> 3, k4 = (i & 7) * 4;
      float4 v = *(const float4*)&ynorm[(size_t)(t0 + m) * 256 + kt + k4];
      As[(k4 + 0) * 132 + m] = v.x;
      As[(k4 + 1) * 132 + m] = v.y;
      As[(k4 + 2) * 132 + m] = v.z;
      As[(k4 + 3) * 132 + m] = v.w;
      float4 wv = *(const float4*)&outw[(size_t)m * 256 + kt + k4];
      Bs[(k4 + 0) * 132 + m] = wv.x;
      Bs[(k4 + 1) * 132 + m] = wv.y;
      Bs[(k4 + 2) * 132 + m] = wv.z;
      Bs[(k4 + 3) * 132 + m] = wv.w;
    }
    __syncthreads();
#pragma unroll 4
    for (int k = 0; k < 32; ++k) {
      const float* ar = &As[k * 132 + ty * 8];
      const float* br = &Bs[k * 132 + tx * 8];
      float4 a0 = *(const float4*)ar, a1 = *(const float4*)(ar + 4);
      float4 b0 = *(const float4*)br, b1 = *(const float4*)(br + 4);
      float av[8] = {a0.x, a0.y, a0.z, a0.w, a1.x, a1.y, a1.z, a1.w};
      float bv[8] = {b0.x, b0.y, b0.z, b0.w, b1.x, b1.y, b1.z, b1.w};
#pragma unroll
      for (int i = 0; i < 8; ++i)
#pragma unroll
        for (int j = 0; j < 8; ++j) acc[i][j] += av[i] * bv[j];
    }
    __syncthreads();
  }
#pragma unroll
  for (int i = 0; i < 8; ++i) {
    int l = tok0 + t0 + ty * 8 + i;
    int b = l >> 14, rem = l & 16383;
    int hh = rem >> 7, ww = rem & 127;
#pragma unroll
    for (int j = 0; j < 8; ++j) {
      int cc = tx * 8 + j;
      dout[(((size_t)(b * 128 + cc) * 128 + hh) * 128 + ww)] = acc[i][j];
    }
  }
}

extern "C" void kernel_launch(void* const* d_in, const int* in_sizes, int n_in,
                              void* d_out, int out_size, void* d_ws, size_t ws_size,
                              hipStream_t stream) {
  const void* x      = d_in[0];
  const void* dww    = d_in[1];
  const void* gng    = d_in[2];
  const void* gnb    = d_in[3];
  const void* pww    = d_in[4];
  const void* pwb    = d_in[5];
  const void* wproj  = d_in[6];
  const void* cw     = d_in[7];
  const void* cb     = d_in[8];
  const void* dtbias = d_in[9];
  const void* alog   = d_in[10];
  const void* dskip  = d_in[11];
  const void* ng     = d_in[12];
  const void* outw   = d_in[13];
  float* out = (float*)d_out;

  char* ws = (char*)d_ws;
  float* gst    = (float*)(ws + 0);
  float* mr     = (float*)(ws + 4096);
  float* P      = (float*)(ws + 8192);
  float* wprojf = (float*)(ws + 40960);
  float* outwf  = (float*)(ws + 372736);
  float* offf   = (float*)(ws + 503808);
  char* cbase   = ws + 1028096;

  // h1 (f32, 67,108,864 B) lives in d_out's out_2d region.
  float* h1f = out;

  // Per-sequence chunk bytes (in-place conv1d + gate):
  //   seq 65536 + z 131072 + xbc 196608 + dtb 4096 + ys 131072 = 528384.
  const int opts[11] = {1024, 512, 256, 128, 64, 32, 16, 8, 4, 2, 1};
  int CH = 1;
  for (int i = 0; i < 11; ++i) {
    if (1028096ull + (unsigned long long)opts[i] * 528384ull <= (unsigned long long)ws_size) {
      CH = opts[i];
      break;
    }
  }
  int NC = 1024 / CH;

  float* seqf = (float*)(cbase);
  float* zf   = (float*)(cbase + (size_t)CH * 65536);
  float* xbcf = (float*)(cbase + (size_t)CH * 196608);
  float* dtbf = (float*)(cbase + (size_t)CH * 393216);
  float* ysf  = (float*)(cbase + (size_t)CH * 397312);

  k_prep_params<<<1, 256, 0, stream>>>(dww, cw, cb, gng, gnb, pww, pwb, dtbias,
                                       alog, dskip, ng, P, gst);
  k_prep_w<<<128, 256, 0, stream>>>(wproj, outw, gng, wprojf, outwf);
  k_dwconv_v2<<<1024, 256, 0, stream>>>(x, gng, P, h1f, gst);
  k_stats<<<1, 64, 0, stream>>>(gst, mr);
  k_gn_off<<<1024, 128, 0, stream>>>(h1f, mr, P, offf, out);

  for (int c = 0; c < NC; ++c) {
    int s0 = c * CH;
    k_deform_v2<<<CH, 256, 0, stream>>>(x, gng, offf, seqf, s0);
    k_gemm1_v4<<<dim3(CH, 6), 256, 0, stream>>>(seqf, wprojf, P, zf, xbcf, dtbf);
    k_conv1d_v3<<<CH, 256, 0, stream>>>(xbcf, P);
    k_scan_v5<<<CH, 512, 0, stream>>>(xbcf, dtbf, P, ysf);
    k_gate_v3<<<CH * 128, 256, 0, stream>>>(ysf, zf, P);
    k_gemm2_v4<<<CH, 256, 0, stream>>>(ysf, outwf, out, s0 * 128);
  }
}

// Round 9
// 924.513 us; speedup vs baseline: 1.6620x; 1.6620x over previous
//
#include <hip/hip_runtime.h>
#include <math.h>

// B=8, C=128, H=128, W=128, D_INNER=256, D_STATE=64, HEADDIM=32, NHEADS=8,
// D_CONV=4, GN_GROUPS=8, D_XBC=384, D_INPROJ=648.
// Inputs f32 (probed via gn_g word0). OUTPUT IS F32 (reference output dtype).
// d_out = [out_2d: 16,777,216 f32][offset: 131,072 f32].
// h1 (f32) is staged in d_out's out_2d region.
//
// Round-8 post-mortem: v4 8x8 VALU tile regressed (VGPR cap 128 via
// launch_bounds(256,4) -> acc pushed to AGPR shuffling, occupancy 25%, 11M
// bank-conflict cycles). f32 VALU ceiling is 157 TF anyway; this round both
// GEMMs move to bf16 MFMA (2.5 PF pipe). dt (exp-sensitive) stays f32 via k_dt.

typedef __bf16 bf16x8 __attribute__((ext_vector_type(8)));
typedef float f32x4 __attribute__((ext_vector_type(4)));

__device__ __forceinline__ float b2f(unsigned short u) {
  return __uint_as_float(((unsigned int)u) << 16);
}
__device__ __forceinline__ unsigned short f2b(float f) {
  unsigned int u = __float_as_uint(f);
  unsigned int r = (u + 0x7FFFu + ((u >> 16) & 1u)) >> 16;  // RNE
  return (unsigned short)r;
}
__device__ __forceinline__ bool in_is_f32(const void* gng) {
  return ((const unsigned int*)gng)[0] == 0x3F800000u;
}

// Sum over the 4-lane quad (lane&3 butterfly) on the VALU pipe.
__device__ __forceinline__ float quad_sum(float v) {
#if __has_builtin(__builtin_amdgcn_update_dpp)
  int p = __builtin_amdgcn_update_dpp(0, __float_as_int(v), 0xB1, 0xF, 0xF, true);
  v += __int_as_float(p);  // xor 1
  p = __builtin_amdgcn_update_dpp(0, __float_as_int(v), 0x4E, 0xF, 0xF, true);
  v += __int_as_float(p);  // xor 2
#else
  v += __shfl_xor(v, 1, 64);
  v += __shfl_xor(v, 2, 64);
#endif
  return v;
}

#define P_DWW 0
#define P_CW 3200
#define P_CB 4736
#define P_GNG 5120
#define P_GNB 5248
#define P_PWW 5376
#define P_PWB 5504
#define P_DTB 5505
#define P_ALOG 5513
#define P_DSKIP 5521
#define P_NG 5529
#define P_WDT 5792   // wproj rows 640..647 in f32 (8*128) for the dt path

__global__ void k_prep_params(const void* dww, const void* cw, const void* cb,
                              const void* gng, const void* gnb, const void* pww,
                              const void* pwb, const void* dtbias, const void* alog,
                              const void* dskip, const void* ng, const void* wproj,
                              float* __restrict__ P, float* __restrict__ gst) {
  bool f = in_is_f32(gng);
  int tid = threadIdx.x;
  if (tid < 128) gst[tid] = 0.f;
  auto cvt = [&](const void* src, int n, int off) {
    for (int i = tid; i < n; i += 256)
      P[off + i] = f ? ((const float*)src)[i] : b2f(((const unsigned short*)src)[i]);
  };
  cvt(dww, 3200, P_DWW);
  cvt(cw, 1536, P_CW);
  cvt(cb, 384, P_CB);
  cvt(gng, 128, P_GNG);
  cvt(gnb, 128, P_GNB);
  cvt(pww, 128, P_PWW);
  cvt(pwb, 1, P_PWB);
  cvt(dtbias, 8, P_DTB);
  cvt(alog, 8, P_ALOG);
  cvt(dskip, 8, P_DSKIP);
  cvt(ng, 256, P_NG);
  // dt weight rows (e=640..647), kept in f32 for the exp-sensitive path.
  for (int i = tid; i < 1024; i += 256)
    P[P_WDT + i] = f ? ((const float*)wproj)[81920 + i]
                     : b2f(((const unsigned short*)wproj)[81920 + i]);
}

// Weights -> bf16 (direct copy if inputs already bf16).
__global__ void k_prep_w(const void* wproj, const void* outw, const void* gng,
                         unsigned short* __restrict__ wprojh,
                         unsigned short* __restrict__ outwh) {
  bool f = in_is_f32(gng);
  int stride = gridDim.x * blockDim.x;
  for (int i = blockIdx.x * blockDim.x + threadIdx.x; i < 82944; i += stride)
    wprojh[i] = f ? f2b(((const float*)wproj)[i]) : ((const unsigned short*)wproj)[i];
  for (int i = blockIdx.x * blockDim.x + threadIdx.x; i < 32768; i += stride)
    outwh[i] = f ? f2b(((const float*)outw)[i]) : ((const unsigned short*)outw)[i];
}

// ---------------- K1 v2: depthwise 5x5 conv + group stats ------------------------
template <int H0>
__device__ __forceinline__ void dw_col(const float* __restrict__ t,
                                       const float* __restrict__ w, int col,
                                       float* __restrict__ h1, size_t outbase,
                                       float& s, float& sq) {
  float acc[5] = {0.f, 0.f, 0.f, 0.f, 0.f};
#pragma unroll
  for (int u = 0; u < 5; ++u) {
    int r = H0 + u;
    const float* row = t + r * 136 + col + 2;
    float v0 = row[0], v1 = row[1], v2 = row[2], v3 = row[3], v4 = row[4];
#pragma unroll
    for (int ky = 0; ky <= u; ++ky) {
      int sl = (H0 + u + 5 - ky) % 5;
      acc[sl] += w[ky * 5 + 0] * v0 + w[ky * 5 + 1] * v1 + w[ky * 5 + 2] * v2 +
                 w[ky * 5 + 3] * v3 + w[ky * 5 + 4] * v4;
    }
    if (u == 4) {
      int sl = H0 % 5;
      float ov = acc[sl];
      h1[outbase + (size_t)H0 * 128 + col] = ov;
      s += ov; sq += ov * ov;
      acc[sl] = 0.f;
    }
  }
  for (int o = 1; o < 13; ++o) {
#pragma unroll
    for (int u = 0; u < 5; ++u) {
      int r = H0 + o * 5 + u;
      const float* row = t + r * 136 + col + 2;
      float v0 = row[0], v1 = row[1], v2 = row[2], v3 = row[3], v4 = row[4];
#pragma unroll
      for (int ky = 0; ky < 5; ++ky) {
        int sl = (H0 + u + 5 - ky) % 5;
        acc[sl] += w[ky * 5 + 0] * v0 + w[ky * 5 + 1] * v1 + w[ky * 5 + 2] * v2 +
                   w[ky * 5 + 3] * v3 + w[ky * 5 + 4] * v4;
      }
      int dy = r - 4;
      int sl = (H0 + u + 1) % 5;
      float ov = acc[sl];
      h1[outbase + (size_t)dy * 128 + col] = ov;
      s += ov; sq += ov * ov;
      acc[sl] = 0.f;
    }
  }
#pragma unroll
  for (int u = 0; u < 3; ++u) {
    int r = H0 + 65 + u;
    const float* row = t + r * 136 + col + 2;
    float v0 = row[0], v1 = row[1], v2 = row[2], v3 = row[3], v4 = row[4];
#pragma unroll
    for (int ky = 0; ky < 5; ++ky) {
      int sl = (H0 + u + 5 - ky) % 5;
      acc[sl] += w[ky * 5 + 0] * v0 + w[ky * 5 + 1] * v1 + w[ky * 5 + 2] * v2 +
                 w[ky * 5 + 3] * v3 + w[ky * 5 + 4] * v4;
    }
    int dy = r - 4;
    int sl = (H0 + u + 1) % 5;
    float ov = acc[sl];
    h1[outbase + (size_t)dy * 128 + col] = ov;
    s += ov; sq += ov * ov;
    acc[sl] = 0.f;
  }
}

__global__ __launch_bounds__(256) void k_dwconv_v2(const void* __restrict__ x,
                                                   const void* __restrict__ gng,
                                                   const float* __restrict__ P,
                                                   float* __restrict__ h1,
                                                   float* __restrict__ gst) {
  int bc = blockIdx.x;
  int b = bc >> 7, chan = bc & 127;
  bool f32x = in_is_f32(gng);
  __shared__ __align__(16) float t[132 * 136];  // 71,808 B
  __shared__ float red[8];
  for (int i = threadIdx.x; i < (132 * 136) / 4; i += 256)
    ((float4*)t)[i] = make_float4(0.f, 0.f, 0.f, 0.f);
  __syncthreads();
  const float* xf = (const float*)x + (size_t)bc * 16384;
  const unsigned short* xb = (const unsigned short*)x + (size_t)bc * 16384;
  for (int i = threadIdx.x; i < 4096; i += 256) {
    int dy = i >> 5, dc = (i & 31) * 4;
    float4 v;
    if (f32x) {
      v = *(const float4*)&xf[i * 4];
    } else {
      ushort4 r4 = *(const ushort4*)&xb[i * 4];
      v = make_float4(b2f(r4.x), b2f(r4.y), b2f(r4.z), b2f(r4.w));
    }
    *(float4*)&t[(dy + 2) * 136 + dc + 4] = v;
  }
  float w[25];
#pragma unroll
  for (int k = 0; k < 25; ++k) w[k] = P[P_DWW + chan * 25 + k];
  __syncthreads();
  int col = threadIdx.x & 127;
  float s = 0.f, sq = 0.f;
  size_t outbase = (size_t)bc * 16384;
  if (threadIdx.x < 128) dw_col<0>(t, w, col, h1, outbase, s, sq);
  else                   dw_col<64>(t, w, col, h1, outbase, s, sq);
  for (int o = 32; o; o >>= 1) { s += __shfl_down(s, o, 64); sq += __shfl_down(sq, o, 64); }
  int wv = threadIdx.x >> 6;
  if ((threadIdx.x & 63) == 0) { red[wv] = s; red[4 + wv] = sq; }
  __syncthreads();
  if (threadIdx.x == 0) {
    float ts = red[0] + red[1] + red[2] + red[3];
    float tq = red[4] + red[5] + red[6] + red[7];
    int g = (b << 3) + (chan >> 4);
    atomicAdd(&gst[g * 2], ts);
    atomicAdd(&gst[g * 2 + 1], tq);
  }
}

__global__ void k_stats(const float* __restrict__ gst, float* __restrict__ mr) {
  int g = threadIdx.x;
  if (g < 64) {
    const float invN = 1.f / 262144.f;
    float mean = gst[g * 2] * invN;
    float var = gst[g * 2 + 1] * invN - mean * mean;
    mr[g * 2] = mean;
    mr[g * 2 + 1] = rsqrtf(var + 1e-5f);
  }
}

// ---------------- K3: GN + exact GELU + 1x1 conv + tanh*8 -> offset (f32 out) ----
__global__ __launch_bounds__(128) void k_gn_off(const float* __restrict__ h1,
                                                const float* __restrict__ mr,
                                                const float* __restrict__ P,
                                                float* __restrict__ offf,
                                                float* __restrict__ dout) {
  int bh = blockIdx.x;
  int b = bh >> 7, h = bh & 127;
  int w = threadIdx.x;
  float acc = 0.f;
  for (int c = 0; c < 128; ++c) {
    float v = h1[(((size_t)(b * 128 + c)) * 128 + h) * 128 + w];
    int g = b * 8 + (c >> 4);
    float nv = (v - mr[g * 2]) * mr[g * 2 + 1] * P[P_GNG + c] + P[P_GNB + c];
    float ge = 0.5f * nv * (1.f + erff(nv * 0.70710678118f));
    acc += ge * P[P_PWW + c];
  }
  float off = acc + P[P_PWB];
  float ofv = tanhf(off) * 8.0f;
  offf[bh * 128 + w] = ofv;
  dout[16777216 + bh * 128 + w] = ofv;
}

// ---------------- K4 v3: grid sample + transpose -> seq f32 + bf16 ---------------
__global__ __launch_bounds__(256) void k_deform_v3(const void* __restrict__ x,
                                                   const void* __restrict__ gng,
                                                   const float* __restrict__ offf,
                                                   float* __restrict__ seqc,
                                                   unsigned short* __restrict__ seqb,
                                                   int s0) {
  int bh = s0 + blockIdx.x;
  int b = bh >> 7, h = bh & 127;
  int w = threadIdx.x & 127;
  int half = threadIdx.x >> 7;  // 0..1
  bool f32x = in_is_f32(gng);
  __shared__ float t[128 * 129];
  float ofv = offf[bh * 128 + w];
  float gy = -1.f + (2.f / 127.f) * (float)h + ofv * (2.f / 127.f);
  gy = fminf(fmaxf(gy, -1.f), 1.f);
  float py = (gy + 1.f) * 0.5f * 127.f;
  py = fminf(fmaxf(py, 0.f), 127.f);
  float y0f = floorf(py);
  float wy = py - y0f;
  int y0 = (int)y0f;
  int y1 = min(y0 + 1, 127);
  const float* xfb = (const float*)x + (size_t)b * 128 * 16384;
  const unsigned short* xbb = (const unsigned short*)x + (size_t)b * 128 * 16384;
  for (int c = half * 64; c < half * 64 + 64; ++c) {
    size_t o0 = (size_t)c * 16384 + y0 * 128 + w;
    size_t o1 = (size_t)c * 16384 + y1 * 128 + w;
    float v0, v1;
    if (f32x) { v0 = xfb[o0]; v1 = xfb[o1]; }
    else      { v0 = b2f(xbb[o0]); v1 = b2f(xbb[o1]); }
    t[c * 129 + w] = v0 + wy * (v1 - v0);
  }
  __syncthreads();
  int c = threadIdx.x & 127;
  float* sp = seqc + (size_t)blockIdx.x * 16384;
  unsigned short* spb = seqb + (size_t)blockIdx.x * 16384;
  for (int l = half * 64; l < half * 64 + 64; ++l) {
    float v = t[c * 129 + l];
    sp[l * 128 + c] = v;
    spb[l * 128 + c] = f2b(v);
  }
}

// ---------------- G1 MFMA: z/xBC = seq @ wproj^T (bf16 in, f32 out) --------------
// 128x128 block, 4 waves (2x2 of 64x64), 4x4 fragments of 16x16x32 MFMA, whole
// K=128 LDS-resident. Rows padded 128->136 bf16 (272 B: bank stride 4 -> max
// 2-way conflicts). e range 0..639 only (dt handled by k_dt in f32).
// A/B fragments: row/col = lane&15, k = (lane>>4)*8+j (symmetric k-map: any
// internal k-permutation cancels). C/D: col=lane&15, row=(lane>>4)*4+reg.
__global__ __launch_bounds__(256) void k_gemm1_mf(const unsigned short* __restrict__ seqb,
                                                  const unsigned short* __restrict__ wprojh,
                                                  float* __restrict__ z,
                                                  float* __restrict__ xbc) {
  __shared__ __align__(16) unsigned short Al[128 * 136];
  __shared__ __align__(16) unsigned short Bl[128 * 136];
  int m0 = blockIdx.x * 128;
  int e0 = blockIdx.y * 128;   // 0..512; covers e<640 exactly
  for (int i = threadIdx.x; i < 2048; i += 256) {
    int row = i >> 4, ch = i & 15;
    *(float4*)&Al[row * 136 + ch * 8] =
        *(const float4*)&seqb[(size_t)(m0 + row) * 128 + ch * 8];
    *(float4*)&Bl[row * 136 + ch * 8] =
        *(const float4*)&wprojh[(size_t)(e0 + row) * 128 + ch * 8];
  }
  __syncthreads();
  int lane = threadIdx.x & 63;
  int wv = threadIdx.x >> 6;
  int wm = wv >> 1, wn = wv & 1;
  int lr = lane & 15;
  int kb = lane >> 4;
  f32x4 acc[4][4] = {};
#pragma unroll
  for (int kk = 0; kk < 4; ++kk) {
    bf16x8 af[4], bf[4];
#pragma unroll
    for (int f = 0; f < 4; ++f)
      af[f] = *(const bf16x8*)&Al[(wm * 64 + f * 16 + lr) * 136 + kk * 32 + kb * 8];
#pragma unroll
    for (int f = 0; f < 4; ++f)
      bf[f] = *(const bf16x8*)&Bl[(wn * 64 + f * 16 + lr) * 136 + kk * 32 + kb * 8];
#pragma unroll
    for (int fm = 0; fm < 4; ++fm)
#pragma unroll
      for (int fn = 0; fn < 4; ++fn)
        acc[fm][fn] = __builtin_amdgcn_mfma_f32_16x16x32_bf16(af[fm], bf[fn],
                                                              acc[fm][fn], 0, 0, 0);
  }
#pragma unroll
  for (int fm = 0; fm < 4; ++fm)
#pragma unroll
    for (int fn = 0; fn < 4; ++fn) {
      int e = e0 + wn * 64 + fn * 16 + lr;
#pragma unroll
      for (int r = 0; r < 4; ++r) {
        int m = m0 + wm * 64 + fm * 16 + kb * 4 + r;
        float v = acc[fm][fn][r];
        if (e < 256) z[(size_t)m * 256 + e] = v;
        else         xbc[(size_t)m * 384 + (e - 256)] = v;
      }
    }
}

// ---------------- K_dt: dt columns in f32 (exp-sensitive path) -------------------
__global__ __launch_bounds__(256) void k_dt(const float* __restrict__ seqf,
                                            const float* __restrict__ P,
                                            float* __restrict__ dtb) {
  int bb = blockIdx.x;            // CH*4 blocks; 32 tokens each
  int sq = bb >> 2, q = bb & 3;
  __shared__ float ss[32 * 133];
  __shared__ float wt[1024];
  const float* sp = seqf + (size_t)sq * 16384 + q * 32 * 128;
  for (int i = threadIdx.x; i < 4096; i += 256) {
    int t = i >> 7, k = i & 127;
    ss[t * 133 + k] = sp[i];
  }
  for (int i = threadIdx.x; i < 1024; i += 256) wt[i] = P[P_WDT + i];
  __syncthreads();
  int head = threadIdx.x >> 5, t = threadIdx.x & 31;
  const float* wh = &wt[head * 128];
  const float* sr = &ss[t * 133];
  float acc = 0.f;
#pragma unroll 8
  for (int k = 0; k < 128; ++k) acc += sr[k] * wh[k];
  float dv = acc + P[P_DTB + head];
  float spv = (dv > 20.f) ? dv : log1pf(__expf(dv));
  dtb[((size_t)sq * 128 + q * 32 + t) * 8 + head] = spv;
}

// ---------------- K5 v3: causal conv1d + SiLU, IN-PLACE --------------------------
__global__ __launch_bounds__(256) void k_conv1d_v3(float* __restrict__ xbc,
                                                   const float* __restrict__ P) {
  float* buf = xbc + (size_t)blockIdx.x * 49152;   // 128*384
  for (int e = threadIdx.x; e < 384; e += 256) {
    float w0 = P[P_CW + e * 4 + 0], w1 = P[P_CW + e * 4 + 1];
    float w2 = P[P_CW + e * 4 + 2], w3 = P[P_CW + e * 4 + 3];
    float bb = P[P_CB + e];
    float x0 = 0.f, x1 = 0.f, x2 = 0.f;
    for (int l = 0; l < 128; ++l) {
      float x3 = buf[l * 384 + e];
      float a = bb + w0 * x0 + w1 * x1 + w2 * x2 + w3 * x3;
      buf[l * 384 + e] = a / (1.f + __expf(-a));
      x0 = x1; x1 = x2; x2 = x3;
    }
  }
}

// ---------------- K6 v5: selective scan — (d,s)-split, 512 threads ---------------
__global__ __launch_bounds__(512) void k_scan_v5(const float* __restrict__ pc,
                                                 const float* __restrict__ dtb,
                                                 const float* __restrict__ P,
                                                 float* __restrict__ ys) {
  int seq = blockIdx.x;
  int head = threadIdx.x >> 6;          // one wave per head
  int dduo = (threadIdx.x >> 2) & 15;   // d = dduo*2 + {0,1}
  int squad = threadIdx.x & 3;          // s-range squad*16 .. +15
  float A = -__expf(P[P_ALOG + head]);
  float Dk = P[P_DSKIP + head];
  float h0[16], h1[16];
#pragma unroll
  for (int s = 0; s < 16; ++s) { h0[s] = 0.f; h1[s] = 0.f; }
  __shared__ __align__(16) float sROW[16][384];
  __shared__ float sDT[16][8];
  const float* base = pc + (size_t)seq * 49152;
  const float* dtp = dtb + (size_t)seq * 1024;
  float* yp = ys + (size_t)seq * 32768;
  const int sbase = 256 + squad * 16;
  const int cbase = sbase + 64;
  for (int lt = 0; lt < 128; lt += 16) {
    const float* gsrc = base + (size_t)lt * 384;
    for (int i = threadIdx.x; i < 1536; i += 512) {
      int ll = i / 96, c4 = i % 96;
      *(float4*)&sROW[ll][c4 * 4] = *(const float4*)&gsrc[ll * 384 + c4 * 4];
    }
    if (threadIdx.x < 128)
      sDT[threadIdx.x >> 3][threadIdx.x & 7] =
          dtp[(lt + (threadIdx.x >> 3)) * 8 + (threadIdx.x & 7)];
    __syncthreads();
#pragma unroll 1
    for (int ll = 0; ll < 16; ++ll) {
      float dt = sDT[ll][head];
      float dA = __expf(dt * A);
      float2 xv = *(const float2*)&sROW[ll][head * 32 + dduo * 2];
      float c0 = dt * xv.x, c1 = dt * xv.y;
      float a0 = 0.f, b0 = 0.f, a1 = 0.f, b1 = 0.f;
#pragma unroll
      for (int s4 = 0; s4 < 4; ++s4) {
        float4 bb = *(const float4*)&sROW[ll][sbase + s4 * 4];
        float4 cc = *(const float4*)&sROW[ll][cbase + s4 * 4];
        h0[s4 * 4 + 0] = h0[s4 * 4 + 0] * dA + c0 * bb.x; a0 += h0[s4 * 4 + 0] * cc.x;
        h0[s4 * 4 + 1] = h0[s4 * 4 + 1] * dA + c0 * bb.y; b0 += h0[s4 * 4 + 1] * cc.y;
        h0[s4 * 4 + 2] = h0[s4 * 4 + 2] * dA + c0 * bb.z; a0 += h0[s4 * 4 + 2] * cc.z;
        h0[s4 * 4 + 3] = h0[s4 * 4 + 3] * dA + c0 * bb.w; b0 += h0[s4 * 4 + 3] * cc.w;
        h1[s4 * 4 + 0] = h1[s4 * 4 + 0] * dA + c1 * bb.x; a1 += h1[s4 * 4 + 0] * cc.x;
        h1[s4 * 4 + 1] = h1[s4 * 4 + 1] * dA + c1 * bb.y; b1 += h1[s4 * 4 + 1] * cc.y;
        h1[s4 * 4 + 2] = h1[s4 * 4 + 2] * dA + c1 * bb.z; a1 += h1[s4 * 4 + 2] * cc.z;
        h1[s4 * 4 + 3] = h1[s4 * 4 + 3] * dA + c1 * bb.w; b1 += h1[s4 * 4 + 3] * cc.w;
      }
      float y0 = quad_sum(a0 + b0);
      float y1 = quad_sum(a1 + b1);
      if (squad == 0) {
        float2 o = make_float2(y0 + Dk * xv.x, y1 + Dk * xv.y);
        *(float2*)&yp[(size_t)(lt + ll) * 256 + head * 32 + dduo * 2] = o;
      }
    }
    __syncthreads();
  }
}

// ---------------- K7 v4: gate + RMS norm -> ynorm bf16 ---------------------------
__global__ __launch_bounds__(256) void k_gate_v4(const float* __restrict__ ys,
                                                 const float* __restrict__ z,
                                                 const float* __restrict__ P,
                                                 unsigned short* __restrict__ ynb) {
  int l = blockIdx.x;
  int e = threadIdx.x;
  __shared__ float red[4];
  float yv = ys[(size_t)l * 256 + e];
  float zv = z[(size_t)l * 256 + e];
  float g = zv / (1.f + __expf(-zv));
  float y = yv * g;
  float ss = y * y;
  for (int o = 32; o; o >>= 1) ss += __shfl_down(ss, o, 64);
  if ((threadIdx.x & 63) == 0) red[threadIdx.x >> 6] = ss;
  __syncthreads();
  float tot = red[0] + red[1] + red[2] + red[3];
  float r = rsqrtf(tot * (1.f / 256.f) + 1e-5f);
  ynb[(size_t)l * 256 + e] = f2b(y * r * P[P_NG + e]);
}

// ---------------- G2 MFMA: out = ynorm @ outw^T (bf16 in, f32 NCHW out) ----------
// Same structure as G1; K=256 in two 128-wide LDS-resident steps.
__global__ __launch_bounds__(256) void k_gemm2_mf(const unsigned short* __restrict__ ynb,
                                                  const unsigned short* __restrict__ outwh,
                                                  float* __restrict__ dout,
                                                  int tok0) {
  __shared__ __align__(16) unsigned short Al[128 * 136];
  __shared__ __align__(16) unsigned short Bl[128 * 136];
  int t0 = blockIdx.x * 128;
  int lane = threadIdx.x & 63;
  int wv = threadIdx.x >> 6;
  int wm = wv >> 1, wn = wv & 1;
  int lr = lane & 15;
  int kb = lane >> 4;
  f32x4 acc[4][4] = {};
  for (int kt = 0; kt < 256; kt += 128) {
    for (int i = threadIdx.x; i < 2048; i += 256) {
      int row = i >> 4, ch = i & 15;
      *(float4*)&Al[row * 136 + ch * 8] =
          *(const float4*)&ynb[(size_t)(t0 + row) * 256 + kt + ch * 8];
      *(float4*)&Bl[row * 136 + ch * 8] =
          *(const float4*)&outwh[(size_t)row * 256 + kt + ch * 8];
    }
    __syncthreads();
#pragma unroll
    for (int kk = 0; kk < 4; ++kk) {
      bf16x8 af[4], bf[4];
#pragma unroll
      for (int f = 0; f < 4; ++f)
        af[f] = *(const bf16x8*)&Al[(wm * 64 + f * 16 + lr) * 136 + kk * 32 + kb * 8];
#pragma unroll
      for (int f = 0; f < 4; ++f)
        bf[f] = *(const bf16x8*)&Bl[(wn * 64 + f * 16 + lr) * 136 + kk * 32 + kb * 8];
#pragma unroll
      for (int fm = 0; fm < 4; ++fm)
#pragma unroll
        for (int fn = 0; fn < 4; ++fn)
          acc[fm][fn] = __builtin_amdgcn_mfma_f32_16x16x32_bf16(af[fm], bf[fn],
                                                                acc[fm][fn], 0, 0, 0);
    }
    __syncthreads();
  }
#pragma unroll
  for (int fm = 0; fm < 4; ++fm)
#pragma unroll
    for (int fn = 0; fn < 4; ++fn) {
      int cc = wn * 64 + fn * 16 + lr;
#pragma unroll
      for (int r = 0; r < 4; ++r) {
        int l = tok0 + t0 + wm * 64 + fm * 16 + kb * 4 + r;
        int b = l >> 14, rem = l & 16383;
        int hh = rem >> 7, ww = rem & 127;
        dout[(((size_t)(b * 128 + cc) * 128 + hh) * 128 + ww)] = acc[fm][fn][r];
      }
    }
}

extern "C" void kernel_launch(void* const* d_in, const int* in_sizes, int n_in,
                              void* d_out, int out_size, void* d_ws, size_t ws_size,
                              hipStream_t stream) {
  const void* x      = d_in[0];
  const void* dww    = d_in[1];
  const void* gng    = d_in[2];
  const void* gnb    = d_in[3];
  const void* pww    = d_in[4];
  const void* pwb    = d_in[5];
  const void* wproj  = d_in[6];
  const void* cw     = d_in[7];
  const void* cb     = d_in[8];
  const void* dtbias = d_in[9];
  const void* alog   = d_in[10];
  const void* dskip  = d_in[11];
  const void* ng     = d_in[12];
  const void* outw   = d_in[13];
  float* out = (float*)d_out;

  char* ws = (char*)d_ws;
  float* gst            = (float*)(ws + 0);
  float* mr             = (float*)(ws + 4096);
  float* P              = (float*)(ws + 8192);
  unsigned short* wpjh  = (unsigned short*)(ws + 40960);   // 648*128*2 = 165,888
  unsigned short* outwh = (unsigned short*)(ws + 372736);  // 128*256*2 = 65,536
  float* offf           = (float*)(ws + 503808);
  char* cbase           = ws + 1028096;

  // h1 (f32) lives in d_out's out_2d region.
  float* h1f = out;

  // Per-sequence chunk bytes:
  //   seqf 65536 + seqbf 32768 + z 131072 + xbc 196608 + dtb 4096
  //   + ys 131072 + ynbf 65536 = 626,688.
  const int opts[11] = {1024, 512, 256, 128, 64, 32, 16, 8, 4, 2, 1};
  int CH = 1;
  for (int i = 0; i < 11; ++i) {
    if (1028096ull + (unsigned long long)opts[i] * 626688ull <= (unsigned long long)ws_size) {
      CH = opts[i];
      break;
    }
  }
  int NC = 1024 / CH;

  float* seqf          = (float*)(cbase);
  unsigned short* seqb = (unsigned short*)(cbase + (size_t)CH * 65536);
  float* zf            = (float*)(cbase + (size_t)CH * 98304);
  float* xbcf          = (float*)(cbase + (size_t)CH * 229376);
  float* dtbf          = (float*)(cbase + (size_t)CH * 425984);
  float* ysf           = (float*)(cbase + (size_t)CH * 430080);
  unsigned short* ynbf = (unsigned short*)(cbase + (size_t)CH * 561152);

  k_prep_params<<<1, 256, 0, stream>>>(dww, cw, cb, gng, gnb, pww, pwb, dtbias,
                                       alog, dskip, ng, wproj, P, gst);
  k_prep_w<<<128, 256, 0, stream>>>(wproj, outw, gng, wpjh, outwh);
  k_dwconv_v2<<<1024, 256, 0, stream>>>(x, gng, P, h1f, gst);
  k_stats<<<1, 64, 0, stream>>>(gst, mr);
  k_gn_off<<<1024, 128, 0, stream>>>(h1f, mr, P, offf, out);

  for (int c = 0; c < NC; ++c) {
    int s0 = c * CH;
    k_deform_v3<<<CH, 256, 0, stream>>>(x, gng, offf, seqf, seqb, s0);
    k_gemm1_mf<<<dim3(CH, 5), 256, 0, stream>>>(seqb, wpjh, zf, xbcf);
    k_dt<<<CH * 4, 256, 0, stream>>>(seqf, P, dtbf);
    k_conv1d_v3<<<CH, 256, 0, stream>>>(xbcf, P);
    k_scan_v5<<<CH, 512, 0, stream>>>(xbcf, dtbf, P, ysf);
    k_gate_v4<<<CH * 128, 256, 0, stream>>>(ysf, zf, P, ynbf);
    k_gemm2_mf<<<CH, 256, 0, stream>>>(ynbf, outwh, out, s0 * 128);
  }
}

// Round 10
// 898.200 us; speedup vs baseline: 1.7107x; 1.0293x over previous
//
#include <hip/hip_runtime.h>
#include <math.h>

// B=8, C=128, H=128, W=128, D_INNER=256, D_STATE=64, HEADDIM=32, NHEADS=8,
// D_CONV=4, GN_GROUPS=8, D_XBC=384, D_INPROJ=648.
// Inputs f32 (probed via gn_g word0). OUTPUT IS F32 (reference output dtype).
// d_out = [out_2d: 16,777,216 f32][offset: 131,072 f32].
// h1 (f32) is staged in d_out's out_2d region.
//
// Round-9 -> 10: scan was LDS-instruction-bound (8 waves x 10 LDS ops/l on the
// CU-shared pipe). v6: (a) thread owns 4d x 16s -> 4 waves x 10 ops = half the
// LDS instructions per CU; launch_bounds(256,1) keeps h[64] in VGPRs (v4's
// spill came from the compiler's occupancy heuristic); (b) conv1d+SiLU fused
// into scan staging (19-row raw window in LDS) -> conv1d kernel's 100MB/chunk
// HBM round trip eliminated.

typedef __bf16 bf16x8 __attribute__((ext_vector_type(8)));
typedef float f32x4 __attribute__((ext_vector_type(4)));

__device__ __forceinline__ float b2f(unsigned short u) {
  return __uint_as_float(((unsigned int)u) << 16);
}
__device__ __forceinline__ unsigned short f2b(float f) {
  unsigned int u = __float_as_uint(f);
  unsigned int r = (u + 0x7FFFu + ((u >> 16) & 1u)) >> 16;  // RNE
  return (unsigned short)r;
}
__device__ __forceinline__ bool in_is_f32(const void* gng) {
  return ((const unsigned int*)gng)[0] == 0x3F800000u;
}

// Sum over the 4-lane quad (lane&3 butterfly) on the VALU pipe.
__device__ __forceinline__ float quad_sum(float v) {
#if __has_builtin(__builtin_amdgcn_update_dpp)
  int p = __builtin_amdgcn_update_dpp(0, __float_as_int(v), 0xB1, 0xF, 0xF, true);
  v += __int_as_float(p);  // xor 1
  p = __builtin_amdgcn_update_dpp(0, __float_as_int(v), 0x4E, 0xF, 0xF, true);
  v += __int_as_float(p);  // xor 2
#else
  v += __shfl_xor(v, 1, 64);
  v += __shfl_xor(v, 2, 64);
#endif
  return v;
}

#define P_DWW 0
#define P_CW 3200
#define P_CB 4736
#define P_GNG 5120
#define P_GNB 5248
#define P_PWW 5376
#define P_PWB 5504
#define P_DTB 5505
#define P_ALOG 5513
#define P_DSKIP 5521
#define P_NG 5529
#define P_WDT 5792   // wproj rows 640..647 in f32 (8*128) for the dt path

__global__ void k_prep_params(const void* dww, const void* cw, const void* cb,
                              const void* gng, const void* gnb, const void* pww,
                              const void* pwb, const void* dtbias, const void* alog,
                              const void* dskip, const void* ng, const void* wproj,
                              float* __restrict__ P, float* __restrict__ gst) {
  bool f = in_is_f32(gng);
  int tid = threadIdx.x;
  if (tid < 128) gst[tid] = 0.f;
  auto cvt = [&](const void* src, int n, int off) {
    for (int i = tid; i < n; i += 256)
      P[off + i] = f ? ((const float*)src)[i] : b2f(((const unsigned short*)src)[i]);
  };
  cvt(dww, 3200, P_DWW);
  cvt(cw, 1536, P_CW);
  cvt(cb, 384, P_CB);
  cvt(gng, 128, P_GNG);
  cvt(gnb, 128, P_GNB);
  cvt(pww, 128, P_PWW);
  cvt(pwb, 1, P_PWB);
  cvt(dtbias, 8, P_DTB);
  cvt(alog, 8, P_ALOG);
  cvt(dskip, 8, P_DSKIP);
  cvt(ng, 256, P_NG);
  for (int i = tid; i < 1024; i += 256)
    P[P_WDT + i] = f ? ((const float*)wproj)[81920 + i]
                     : b2f(((const unsigned short*)wproj)[81920 + i]);
}

// Weights -> bf16 (direct copy if inputs already bf16).
__global__ void k_prep_w(const void* wproj, const void* outw, const void* gng,
                         unsigned short* __restrict__ wprojh,
                         unsigned short* __restrict__ outwh) {
  bool f = in_is_f32(gng);
  int stride = gridDim.x * blockDim.x;
  for (int i = blockIdx.x * blockDim.x + threadIdx.x; i < 82944; i += stride)
    wprojh[i] = f ? f2b(((const float*)wproj)[i]) : ((const unsigned short*)wproj)[i];
  for (int i = blockIdx.x * blockDim.x + threadIdx.x; i < 32768; i += stride)
    outwh[i] = f ? f2b(((const float*)outw)[i]) : ((const unsigned short*)outw)[i];
}

// ---------------- K1 v2: depthwise 5x5 conv + group stats ------------------------
template <int H0>
__device__ __forceinline__ void dw_col(const float* __restrict__ t,
                                       const float* __restrict__ w, int col,
                                       float* __restrict__ h1, size_t outbase,
                                       float& s, float& sq) {
  float acc[5] = {0.f, 0.f, 0.f, 0.f, 0.f};
#pragma unroll
  for (int u = 0; u < 5; ++u) {
    int r = H0 + u;
    const float* row = t + r * 136 + col + 2;
    float v0 = row[0], v1 = row[1], v2 = row[2], v3 = row[3], v4 = row[4];
#pragma unroll
    for (int ky = 0; ky <= u; ++ky) {
      int sl = (H0 + u + 5 - ky) % 5;
      acc[sl] += w[ky * 5 + 0] * v0 + w[ky * 5 + 1] * v1 + w[ky * 5 + 2] * v2 +
                 w[ky * 5 + 3] * v3 + w[ky * 5 + 4] * v4;
    }
    if (u == 4) {
      int sl = H0 % 5;
      float ov = acc[sl];
      h1[outbase + (size_t)H0 * 128 + col] = ov;
      s += ov; sq += ov * ov;
      acc[sl] = 0.f;
    }
  }
  for (int o = 1; o < 13; ++o) {
#pragma unroll
    for (int u = 0; u < 5; ++u) {
      int r = H0 + o * 5 + u;
      const float* row = t + r * 136 + col + 2;
      float v0 = row[0], v1 = row[1], v2 = row[2], v3 = row[3], v4 = row[4];
#pragma unroll
      for (int ky = 0; ky < 5; ++ky) {
        int sl = (H0 + u + 5 - ky) % 5;
        acc[sl] += w[ky * 5 + 0] * v0 + w[ky * 5 + 1] * v1 + w[ky * 5 + 2] * v2 +
                   w[ky * 5 + 3] * v3 + w[ky * 5 + 4] * v4;
      }
      int dy = r - 4;
      int sl = (H0 + u + 1) % 5;
      float ov = acc[sl];
      h1[outbase + (size_t)dy * 128 + col] = ov;
      s += ov; sq += ov * ov;
      acc[sl] = 0.f;
    }
  }
#pragma unroll
  for (int u = 0; u < 3; ++u) {
    int r = H0 + 65 + u;
    const float* row = t + r * 136 + col + 2;
    float v0 = row[0], v1 = row[1], v2 = row[2], v3 = row[3], v4 = row[4];
#pragma unroll
    for (int ky = 0; ky < 5; ++ky) {
      int sl = (H0 + u + 5 - ky) % 5;
      acc[sl] += w[ky * 5 + 0] * v0 + w[ky * 5 + 1] * v1 + w[ky * 5 + 2] * v2 +
                 w[ky * 5 + 3] * v3 + w[ky * 5 + 4] * v4;
    }
    int dy = r - 4;
    int sl = (H0 + u + 1) % 5;
    float ov = acc[sl];
    h1[outbase + (size_t)dy * 128 + col] = ov;
    s += ov; sq += ov * ov;
    acc[sl] = 0.f;
  }
}

__global__ __launch_bounds__(256) void k_dwconv_v2(const void* __restrict__ x,
                                                   const void* __restrict__ gng,
                                                   const float* __restrict__ P,
                                                   float* __restrict__ h1,
                                                   float* __restrict__ gst) {
  int bc = blockIdx.x;
  int b = bc >> 7, chan = bc & 127;
  bool f32x = in_is_f32(gng);
  __shared__ __align__(16) float t[132 * 136];  // 71,808 B
  __shared__ float red[8];
  for (int i = threadIdx.x; i < (132 * 136) / 4; i += 256)
    ((float4*)t)[i] = make_float4(0.f, 0.f, 0.f, 0.f);
  __syncthreads();
  const float* xf = (const float*)x + (size_t)bc * 16384;
  const unsigned short* xb = (const unsigned short*)x + (size_t)bc * 16384;
  for (int i = threadIdx.x; i < 4096; i += 256) {
    int dy = i >> 5, dc = (i & 31) * 4;
    float4 v;
    if (f32x) {
      v = *(const float4*)&xf[i * 4];
    } else {
      ushort4 r4 = *(const ushort4*)&xb[i * 4];
      v = make_float4(b2f(r4.x), b2f(r4.y), b2f(r4.z), b2f(r4.w));
    }
    *(float4*)&t[(dy + 2) * 136 + dc + 4] = v;
  }
  float w[25];
#pragma unroll
  for (int k = 0; k < 25; ++k) w[k] = P[P_DWW + chan * 25 + k];
  __syncthreads();
  int col = threadIdx.x & 127;
  float s = 0.f, sq = 0.f;
  size_t outbase = (size_t)bc * 16384;
  if (threadIdx.x < 128) dw_col<0>(t, w, col, h1, outbase, s, sq);
  else                   dw_col<64>(t, w, col, h1, outbase, s, sq);
  for (int o = 32; o; o >>= 1) { s += __shfl_down(s, o, 64); sq += __shfl_down(sq, o, 64); }
  int wv = threadIdx.x >> 6;
  if ((threadIdx.x & 63) == 0) { red[wv] = s; red[4 + wv] = sq; }
  __syncthreads();
  if (threadIdx.x == 0) {
    float ts = red[0] + red[1] + red[2] + red[3];
    float tq = red[4] + red[5] + red[6] + red[7];
    int g = (b << 3) + (chan >> 4);
    atomicAdd(&gst[g * 2], ts);
    atomicAdd(&gst[g * 2 + 1], tq);
  }
}

__global__ void k_stats(const float* __restrict__ gst, float* __restrict__ mr) {
  int g = threadIdx.x;
  if (g < 64) {
    const float invN = 1.f / 262144.f;
    float mean = gst[g * 2] * invN;
    float var = gst[g * 2 + 1] * invN - mean * mean;
    mr[g * 2] = mean;
    mr[g * 2 + 1] = rsqrtf(var + 1e-5f);
  }
}

// ---------------- K3: GN + exact GELU + 1x1 conv + tanh*8 -> offset (f32 out) ----
__global__ __launch_bounds__(128) void k_gn_off(const float* __restrict__ h1,
                                                const float* __restrict__ mr,
                                                const float* __restrict__ P,
                                                float* __restrict__ offf,
                                                float* __restrict__ dout) {
  int bh = blockIdx.x;
  int b = bh >> 7, h = bh & 127;
  int w = threadIdx.x;
  float acc = 0.f;
  for (int c = 0; c < 128; ++c) {
    float v = h1[(((size_t)(b * 128 + c)) * 128 + h) * 128 + w];
    int g = b * 8 + (c >> 4);
    float nv = (v - mr[g * 2]) * mr[g * 2 + 1] * P[P_GNG + c] + P[P_GNB + c];
    float ge = 0.5f * nv * (1.f + erff(nv * 0.70710678118f));
    acc += ge * P[P_PWW + c];
  }
  float off = acc + P[P_PWB];
  float ofv = tanhf(off) * 8.0f;
  offf[bh * 128 + w] = ofv;
  dout[16777216 + bh * 128 + w] = ofv;
}

// ---------------- K4 v3: grid sample + transpose -> seq f32 + bf16 ---------------
__global__ __launch_bounds__(256) void k_deform_v3(const void* __restrict__ x,
                                                   const void* __restrict__ gng,
                                                   const float* __restrict__ offf,
                                                   float* __restrict__ seqc,
                                                   unsigned short* __restrict__ seqb,
                                                   int s0) {
  int bh = s0 + blockIdx.x;
  int b = bh >> 7, h = bh & 127;
  int w = threadIdx.x & 127;
  int half = threadIdx.x >> 7;  // 0..1
  bool f32x = in_is_f32(gng);
  __shared__ float t[128 * 129];
  float ofv = offf[bh * 128 + w];
  float gy = -1.f + (2.f / 127.f) * (float)h + ofv * (2.f / 127.f);
  gy = fminf(fmaxf(gy, -1.f), 1.f);
  float py = (gy + 1.f) * 0.5f * 127.f;
  py = fminf(fmaxf(py, 0.f), 127.f);
  float y0f = floorf(py);
  float wy = py - y0f;
  int y0 = (int)y0f;
  int y1 = min(y0 + 1, 127);
  const float* xfb = (const float*)x + (size_t)b * 128 * 16384;
  const unsigned short* xbb = (const unsigned short*)x + (size_t)b * 128 * 16384;
  for (int c = half * 64; c < half * 64 + 64; ++c) {
    size_t o0 = (size_t)c * 16384 + y0 * 128 + w;
    size_t o1 = (size_t)c * 16384 + y1 * 128 + w;
    float v0, v1;
    if (f32x) { v0 = xfb[o0]; v1 = xfb[o1]; }
    else      { v0 = b2f(xbb[o0]); v1 = b2f(xbb[o1]); }
    t[c * 129 + w] = v0 + wy * (v1 - v0);
  }
  __syncthreads();
  int c = threadIdx.x & 127;
  float* sp = seqc + (size_t)blockIdx.x * 16384;
  unsigned short* spb = seqb + (size_t)blockIdx.x * 16384;
  for (int l = half * 64; l < half * 64 + 64; ++l) {
    float v = t[c * 129 + l];
    sp[l * 128 + c] = v;
    spb[l * 128 + c] = f2b(v);
  }
}

// ---------------- G1 MFMA: z/xBC = seq @ wproj^T (bf16 in, f32 out) --------------
__global__ __launch_bounds__(256) void k_gemm1_mf(const unsigned short* __restrict__ seqb,
                                                  const unsigned short* __restrict__ wprojh,
                                                  float* __restrict__ z,
                                                  float* __restrict__ xbc) {
  __shared__ __align__(16) unsigned short Al[128 * 136];
  __shared__ __align__(16) unsigned short Bl[128 * 136];
  int m0 = blockIdx.x * 128;
  int e0 = blockIdx.y * 128;   // 0..512; covers e<640 exactly
  for (int i = threadIdx.x; i < 2048; i += 256) {
    int row = i >> 4, ch = i & 15;
    *(float4*)&Al[row * 136 + ch * 8] =
        *(const float4*)&seqb[(size_t)(m0 + row) * 128 + ch * 8];
    *(float4*)&Bl[row * 136 + ch * 8] =
        *(const float4*)&wprojh[(size_t)(e0 + row) * 128 + ch * 8];
  }
  __syncthreads();
  int lane = threadIdx.x & 63;
  int wv = threadIdx.x >> 6;
  int wm = wv >> 1, wn = wv & 1;
  int lr = lane & 15;
  int kb = lane >> 4;
  f32x4 acc[4][4] = {};
#pragma unroll
  for (int kk = 0; kk < 4; ++kk) {
    bf16x8 af[4], bf[4];
#pragma unroll
    for (int f = 0; f < 4; ++f)
      af[f] = *(const bf16x8*)&Al[(wm * 64 + f * 16 + lr) * 136 + kk * 32 + kb * 8];
#pragma unroll
    for (int f = 0; f < 4; ++f)
      bf[f] = *(const bf16x8*)&Bl[(wn * 64 + f * 16 + lr) * 136 + kk * 32 + kb * 8];
#pragma unroll
    for (int fm = 0; fm < 4; ++fm)
#pragma unroll
      for (int fn = 0; fn < 4; ++fn)
        acc[fm][fn] = __builtin_amdgcn_mfma_f32_16x16x32_bf16(af[fm], bf[fn],
                                                              acc[fm][fn], 0, 0, 0);
  }
#pragma unroll
  for (int fm = 0; fm < 4; ++fm)
#pragma unroll
    for (int fn = 0; fn < 4; ++fn) {
      int e = e0 + wn * 64 + fn * 16 + lr;
#pragma unroll
      for (int r = 0; r < 4; ++r) {
        int m = m0 + wm * 64 + fm * 16 + kb * 4 + r;
        float v = acc[fm][fn][r];
        if (e < 256) z[(size_t)m * 256 + e] = v;
        else         xbc[(size_t)m * 384 + (e - 256)] = v;
      }
    }
}

// ---------------- K_dt: dt columns in f32 (exp-sensitive path) -------------------
__global__ __launch_bounds__(256) void k_dt(const float* __restrict__ seqf,
                                            const float* __restrict__ P,
                                            float* __restrict__ dtb) {
  int bb = blockIdx.x;            // CH*4 blocks; 32 tokens each
  int sq = bb >> 2, q = bb & 3;
  __shared__ float ss[32 * 133];
  __shared__ float wt[1024];
  const float* sp = seqf + (size_t)sq * 16384 + q * 32 * 128;
  for (int i = threadIdx.x; i < 4096; i += 256) {
    int t = i >> 7, k = i & 127;
    ss[t * 133 + k] = sp[i];
  }
  for (int i = threadIdx.x; i < 1024; i += 256) wt[i] = P[P_WDT + i];
  __syncthreads();
  int head = threadIdx.x >> 5, t = threadIdx.x & 31;
  const float* wh = &wt[head * 128];
  const float* sr = &ss[t * 133];
  float acc = 0.f;
#pragma unroll 8
  for (int k = 0; k < 128; ++k) acc += sr[k] * wh[k];
  float dv = acc + P[P_DTB + head];
  float spv = (dv > 20.f) ? dv : log1pf(__expf(dv));
  dtb[((size_t)sq * 128 + q * 32 + t) * 8 + head] = spv;
}

// ---------------- K6 v6: fused conv1d+SiLU+scan ----------------------------------
// Thread = (head, d-quad, squad): owns 4 d x 16 s = 64 h-states (VGPR-resident;
// launch_bounds(256,1) gives the allocator the full budget -- v4's spill came
// from the occupancy heuristic). Per l per thread: 4+4 b128 (B,C) + 1 b128 (xv)
// + dt = 10 LDS ops at 4 waves -> half of v5's per-CU LDS instruction count.
// Staging: 19 raw xbc rows (3-row causal history, zero-pad l<0) -> conv+SiLU
// computed per column into sROW. Eliminates the separate conv1d kernel.
__global__ __launch_bounds__(256, 1) void k_scan_v6(const float* __restrict__ xbc,
                                                    const float* __restrict__ dtb,
                                                    const float* __restrict__ P,
                                                    float* __restrict__ ys) {
  int seq = blockIdx.x;
  int head = threadIdx.x >> 5;          // 0..7 (2 heads per wave)
  int dq = (threadIdx.x >> 2) & 7;      // d = dq*4 + 0..3
  int squad = threadIdx.x & 3;          // s-range squad*16 .. +15
  float A = -__expf(P[P_ALOG + head]);
  float Dk = P[P_DSKIP + head];
  float h[4][16];
#pragma unroll
  for (int c = 0; c < 4; ++c)
#pragma unroll
    for (int s = 0; s < 16; ++s) h[c][s] = 0.f;
  __shared__ __align__(16) float sRAW[19][388];  // raw xbc rows lt-3..lt+15
  __shared__ __align__(16) float sROW[16][388];  // conv+SiLU rows lt..lt+15
  __shared__ float sDT[16][8];
  const float* base = xbc + (size_t)seq * 49152;
  const float* dtp = dtb + (size_t)seq * 1024;
  float* yp = ys + (size_t)seq * 32768;
  const int sbase = 256 + squad * 16;
  const int cbase = sbase + 64;
  for (int lt = 0; lt < 128; lt += 16) {
    // Stage raw rows l = lt-3 .. lt+15 (19 rows x 384 f32, float4).
    for (int i = threadIdx.x; i < 1824; i += 256) {
      int r = i / 96, c4 = (i % 96) * 4;
      int l = lt - 3 + r;
      float4 v = make_float4(0.f, 0.f, 0.f, 0.f);
      if (l >= 0) v = *(const float4*)&base[(size_t)l * 384 + c4];
      *(float4*)&sRAW[r][c4] = v;
    }
    if (threadIdx.x < 128)
      sDT[threadIdx.x >> 3][threadIdx.x & 7] =
          dtp[(lt + (threadIdx.x >> 3)) * 8 + (threadIdx.x & 7)];
    __syncthreads();
    // Conv pass: out[ll][e] = silu(b_e + sum_k w_e[k] * raw[ll+k][e]).
    for (int e = threadIdx.x; e < 384; e += 256) {
      float w0 = P[P_CW + e * 4 + 0], w1 = P[P_CW + e * 4 + 1];
      float w2 = P[P_CW + e * 4 + 2], w3 = P[P_CW + e * 4 + 3];
      float bb = P[P_CB + e];
      float x0 = sRAW[0][e], x1 = sRAW[1][e], x2 = sRAW[2][e];
#pragma unroll
      for (int ll = 0; ll < 16; ++ll) {
        float x3 = sRAW[ll + 3][e];
        float a = bb + w0 * x0 + w1 * x1 + w2 * x2 + w3 * x3;
        sROW[ll][e] = a / (1.f + __expf(-a));
        x0 = x1; x1 = x2; x2 = x3;
      }
    }
    __syncthreads();
#pragma unroll 2
    for (int ll = 0; ll < 16; ++ll) {
      float dt = sDT[ll][head];
      float dA = __expf(dt * A);
      float4 xv = *(const float4*)&sROW[ll][head * 32 + dq * 4];
      float cf[4] = {dt * xv.x, dt * xv.y, dt * xv.z, dt * xv.w};
      float acc[4] = {0.f, 0.f, 0.f, 0.f};
#pragma unroll
      for (int s4 = 0; s4 < 4; ++s4) {
        float4 bb4 = *(const float4*)&sROW[ll][sbase + s4 * 4];
        float4 cc4 = *(const float4*)&sROW[ll][cbase + s4 * 4];
        float bv[4] = {bb4.x, bb4.y, bb4.z, bb4.w};
        float cv[4] = {cc4.x, cc4.y, cc4.z, cc4.w};
#pragma unroll
        for (int c = 0; c < 4; ++c)
#pragma unroll
          for (int j = 0; j < 4; ++j) {
            h[c][s4 * 4 + j] = h[c][s4 * 4 + j] * dA + cf[c] * bv[j];
            acc[c] += h[c][s4 * 4 + j] * cv[j];
          }
      }
      float y0 = quad_sum(acc[0]);
      float y1 = quad_sum(acc[1]);
      float y2 = quad_sum(acc[2]);
      float y3 = quad_sum(acc[3]);
      if (squad == 0) {
        float4 o = make_float4(y0 + Dk * xv.x, y1 + Dk * xv.y,
                               y2 + Dk * xv.z, y3 + Dk * xv.w);
        *(float4*)&yp[(size_t)(lt + ll) * 256 + head * 32 + dq * 4] = o;
      }
    }
    __syncthreads();
  }
}

// ---------------- K7 v4: gate + RMS norm -> ynorm bf16 ---------------------------
__global__ __launch_bounds__(256) void k_gate_v4(const float* __restrict__ ys,
                                                 const float* __restrict__ z,
                                                 const float* __restrict__ P,
                                                 unsigned short* __restrict__ ynb) {
  int l = blockIdx.x;
  int e = threadIdx.x;
  __shared__ float red[4];
  float yv = ys[(size_t)l * 256 + e];
  float zv = z[(size_t)l * 256 + e];
  float g = zv / (1.f + __expf(-zv));
  float y = yv * g;
  float ss = y * y;
  for (int o = 32; o; o >>= 1) ss += __shfl_down(ss, o, 64);
  if ((threadIdx.x & 63) == 0) red[threadIdx.x >> 6] = ss;
  __syncthreads();
  float tot = red[0] + red[1] + red[2] + red[3];
  float r = rsqrtf(tot * (1.f / 256.f) + 1e-5f);
  ynb[(size_t)l * 256 + e] = f2b(y * r * P[P_NG + e]);
}

// ---------------- G2 MFMA: out = ynorm @ outw^T (bf16 in, f32 NCHW out) ----------
__global__ __launch_bounds__(256) void k_gemm2_mf(const unsigned short* __restrict__ ynb,
                                                  const unsigned short* __restrict__ outwh,
                                                  float* __restrict__ dout,
                                                  int tok0) {
  __shared__ __align__(16) unsigned short Al[128 * 136];
  __shared__ __align__(16) unsigned short Bl[128 * 136];
  int t0 = blockIdx.x * 128;
  int lane = threadIdx.x & 63;
  int wv = threadIdx.x >> 6;
  int wm = wv >> 1, wn = wv & 1;
  int lr = lane & 15;
  int kb = lane >> 4;
  f32x4 acc[4][4] = {};
  for (int kt = 0; kt < 256; kt += 128) {
    for (int i = threadIdx.x; i < 2048; i += 256) {
      int row = i >> 4, ch = i & 15;
      *(float4*)&Al[row * 136 + ch * 8] =
          *(const float4*)&ynb[(size_t)(t0 + row) * 256 + kt + ch * 8];
      *(float4*)&Bl[row * 136 + ch * 8] =
          *(const float4*)&outwh[(size_t)row * 256 + kt + ch * 8];
    }
    __syncthreads();
#pragma unroll
    for (int kk = 0; kk < 4; ++kk) {
      bf16x8 af[4], bf[4];
#pragma unroll
      for (int f = 0; f < 4; ++f)
        af[f] = *(const bf16x8*)&Al[(wm * 64 + f * 16 + lr) * 136 + kk * 32 + kb * 8];
#pragma unroll
      for (int f = 0; f < 4; ++f)
        bf[f] = *(const bf16x8*)&Bl[(wn * 64 + f * 16 + lr) * 136 + kk * 32 + kb * 8];
#pragma unroll
      for (int fm = 0; fm < 4; ++fm)
#pragma unroll
        for (int fn = 0; fn < 4; ++fn)
          acc[fm][fn] = __builtin_amdgcn_mfma_f32_16x16x32_bf16(af[fm], bf[fn],
                                                                acc[fm][fn], 0, 0, 0);
    }
    __syncthreads();
  }
#pragma unroll
  for (int fm = 0; fm < 4; ++fm)
#pragma unroll
    for (int fn = 0; fn < 4; ++fn) {
      int cc = wn * 64 + fn * 16 + lr;
#pragma unroll
      for (int r = 0; r < 4; ++r) {
        int l = tok0 + t0 + wm * 64 + fm * 16 + kb * 4 + r;
        int b = l >> 14, rem = l & 16383;
        int hh = rem >> 7, ww = rem & 127;
        dout[(((size_t)(b * 128 + cc) * 128 + hh) * 128 + ww)] = acc[fm][fn][r];
      }
    }
}

extern "C" void kernel_launch(void* const* d_in, const int* in_sizes, int n_in,
                              void* d_out, int out_size, void* d_ws, size_t ws_size,
                              hipStream_t stream) {
  const void* x      = d_in[0];
  const void* dww    = d_in[1];
  const void* gng    = d_in[2];
  const void* gnb    = d_in[3];
  const void* pww    = d_in[4];
  const void* pwb    = d_in[5];
  const void* wproj  = d_in[6];
  const void* cw     = d_in[7];
  const void* cb     = d_in[8];
  const void* dtbias = d_in[9];
  const void* alog   = d_in[10];
  const void* dskip  = d_in[11];
  const void* ng     = d_in[12];
  const void* outw   = d_in[13];
  float* out = (float*)d_out;

  char* ws = (char*)d_ws;
  float* gst            = (float*)(ws + 0);
  float* mr             = (float*)(ws + 4096);
  float* P              = (float*)(ws + 8192);
  unsigned short* wpjh  = (unsigned short*)(ws + 40960);   // 648*128*2 = 165,888
  unsigned short* outwh = (unsigned short*)(ws + 372736);  // 128*256*2 = 65,536
  float* offf           = (float*)(ws + 503808);
  char* cbase           = ws + 1028096;

  // h1 (f32) lives in d_out's out_2d region.
  float* h1f = out;

  // Per-sequence chunk bytes:
  //   seqf 65536 + seqbf 32768 + z 131072 + xbc 196608 + dtb 4096
  //   + ys 131072 + ynbf 65536 = 626,688.
  const int opts[11] = {1024, 512, 256, 128, 64, 32, 16, 8, 4, 2, 1};
  int CH = 1;
  for (int i = 0; i < 11; ++i) {
    if (1028096ull + (unsigned long long)opts[i] * 626688ull <= (unsigned long long)ws_size) {
      CH = opts[i];
      break;
    }
  }
  int NC = 1024 / CH;

  float* seqf          = (float*)(cbase);
  unsigned short* seqb = (unsigned short*)(cbase + (size_t)CH * 65536);
  float* zf            = (float*)(cbase + (size_t)CH * 98304);
  float* xbcf          = (float*)(cbase + (size_t)CH * 229376);
  float* dtbf          = (float*)(cbase + (size_t)CH * 425984);
  float* ysf           = (float*)(cbase + (size_t)CH * 430080);
  unsigned short* ynbf = (unsigned short*)(cbase + (size_t)CH * 561152);

  k_prep_params<<<1, 256, 0, stream>>>(dww, cw, cb, gng, gnb, pww, pwb, dtbias,
                                       alog, dskip, ng, wproj, P, gst);
  k_prep_w<<<128, 256, 0, stream>>>(wproj, outw, gng, wpjh, outwh);
  k_dwconv_v2<<<1024, 256, 0, stream>>>(x, gng, P, h1f, gst);
  k_stats<<<1, 64, 0, stream>>>(gst, mr);
  k_gn_off<<<1024, 128, 0, stream>>>(h1f, mr, P, offf, out);

  for (int c = 0; c < NC; ++c) {
    int s0 = c * CH;
    k_deform_v3<<<CH, 256, 0, stream>>>(x, gng, offf, seqf, seqb, s0);
    k_gemm1_mf<<<dim3(CH, 5), 256, 0, stream>>>(seqb, wpjh, zf, xbcf);
    k_dt<<<CH * 4, 256, 0, stream>>>(seqf, P, dtbf);
    k_scan_v6<<<CH, 256, 0, stream>>>(xbcf, dtbf, P, ysf);
    k_gate_v4<<<CH * 128, 256, 0, stream>>>(ysf, zf, P, ynbf);
    k_gemm2_mf<<<CH, 256, 0, stream>>>(ynbf, outwh, out, s0 * 128);
  }
}

// Round 11
// 802.741 us; speedup vs baseline: 1.9141x; 1.1189x over previous
//
#include <hip/hip_runtime.h>
#include <math.h>

// B=8, C=128, H=128, W=128, D_INNER=256, D_STATE=64, HEADDIM=32, NHEADS=8,
// D_CONV=4, GN_GROUPS=8, D_XBC=384, D_INPROJ=648.
// Inputs f32 (probed via gn_g word0). OUTPUT IS F32 (reference output dtype).
// d_out = [out_2d: 16,777,216 f32][offset: 131,072 f32].
// h1 (f32) is staged in d_out's out_2d region.
//
// Round-10 post-mortem: v6 fused conv but dropped scan to 4 waves/CU (grid is
// 1 block/CU; 256 threads = 4 waves) -> latency-hiding loss ate the LDS-op win
// (69 -> 112us). v7 = v5's 512-thread/8-wave geometry (measured 69us) + the
// conv fusion (conv1d kernel's 100MB/chunk HBM round trip stays eliminated).

typedef __bf16 bf16x8 __attribute__((ext_vector_type(8)));
typedef float f32x4 __attribute__((ext_vector_type(4)));

__device__ __forceinline__ float b2f(unsigned short u) {
  return __uint_as_float(((unsigned int)u) << 16);
}
__device__ __forceinline__ unsigned short f2b(float f) {
  unsigned int u = __float_as_uint(f);
  unsigned int r = (u + 0x7FFFu + ((u >> 16) & 1u)) >> 16;  // RNE
  return (unsigned short)r;
}
__device__ __forceinline__ bool in_is_f32(const void* gng) {
  return ((const unsigned int*)gng)[0] == 0x3F800000u;
}

// Sum over the 4-lane quad (lane&3 butterfly) on the VALU pipe.
__device__ __forceinline__ float quad_sum(float v) {
#if __has_builtin(__builtin_amdgcn_update_dpp)
  int p = __builtin_amdgcn_update_dpp(0, __float_as_int(v), 0xB1, 0xF, 0xF, true);
  v += __int_as_float(p);  // xor 1
  p = __builtin_amdgcn_update_dpp(0, __float_as_int(v), 0x4E, 0xF, 0xF, true);
  v += __int_as_float(p);  // xor 2
#else
  v += __shfl_xor(v, 1, 64);
  v += __shfl_xor(v, 2, 64);
#endif
  return v;
}

#define P_DWW 0
#define P_CW 3200
#define P_CB 4736
#define P_GNG 5120
#define P_GNB 5248
#define P_PWW 5376
#define P_PWB 5504
#define P_DTB 5505
#define P_ALOG 5513
#define P_DSKIP 5521
#define P_NG 5529
#define P_WDT 5792   // wproj rows 640..647 in f32 (8*128) for the dt path

__global__ void k_prep_params(const void* dww, const void* cw, const void* cb,
                              const void* gng, const void* gnb, const void* pww,
                              const void* pwb, const void* dtbias, const void* alog,
                              const void* dskip, const void* ng, const void* wproj,
                              float* __restrict__ P, float* __restrict__ gst) {
  bool f = in_is_f32(gng);
  int tid = threadIdx.x;
  if (tid < 128) gst[tid] = 0.f;
  auto cvt = [&](const void* src, int n, int off) {
    for (int i = tid; i < n; i += 256)
      P[off + i] = f ? ((const float*)src)[i] : b2f(((const unsigned short*)src)[i]);
  };
  cvt(dww, 3200, P_DWW);
  cvt(cw, 1536, P_CW);
  cvt(cb, 384, P_CB);
  cvt(gng, 128, P_GNG);
  cvt(gnb, 128, P_GNB);
  cvt(pww, 128, P_PWW);
  cvt(pwb, 1, P_PWB);
  cvt(dtbias, 8, P_DTB);
  cvt(alog, 8, P_ALOG);
  cvt(dskip, 8, P_DSKIP);
  cvt(ng, 256, P_NG);
  for (int i = tid; i < 1024; i += 256)
    P[P_WDT + i] = f ? ((const float*)wproj)[81920 + i]
                     : b2f(((const unsigned short*)wproj)[81920 + i]);
}

// Weights -> bf16 (direct copy if inputs already bf16).
__global__ void k_prep_w(const void* wproj, const void* outw, const void* gng,
                         unsigned short* __restrict__ wprojh,
                         unsigned short* __restrict__ outwh) {
  bool f = in_is_f32(gng);
  int stride = gridDim.x * blockDim.x;
  for (int i = blockIdx.x * blockDim.x + threadIdx.x; i < 82944; i += stride)
    wprojh[i] = f ? f2b(((const float*)wproj)[i]) : ((const unsigned short*)wproj)[i];
  for (int i = blockIdx.x * blockDim.x + threadIdx.x; i < 32768; i += stride)
    outwh[i] = f ? f2b(((const float*)outw)[i]) : ((const unsigned short*)outw)[i];
}

// ---------------- K1 v2: depthwise 5x5 conv + group stats ------------------------
template <int H0>
__device__ __forceinline__ void dw_col(const float* __restrict__ t,
                                       const float* __restrict__ w, int col,
                                       float* __restrict__ h1, size_t outbase,
                                       float& s, float& sq) {
  float acc[5] = {0.f, 0.f, 0.f, 0.f, 0.f};
#pragma unroll
  for (int u = 0; u < 5; ++u) {
    int r = H0 + u;
    const float* row = t + r * 136 + col + 2;
    float v0 = row[0], v1 = row[1], v2 = row[2], v3 = row[3], v4 = row[4];
#pragma unroll
    for (int ky = 0; ky <= u; ++ky) {
      int sl = (H0 + u + 5 - ky) % 5;
      acc[sl] += w[ky * 5 + 0] * v0 + w[ky * 5 + 1] * v1 + w[ky * 5 + 2] * v2 +
                 w[ky * 5 + 3] * v3 + w[ky * 5 + 4] * v4;
    }
    if (u == 4) {
      int sl = H0 % 5;
      float ov = acc[sl];
      h1[outbase + (size_t)H0 * 128 + col] = ov;
      s += ov; sq += ov * ov;
      acc[sl] = 0.f;
    }
  }
  for (int o = 1; o < 13; ++o) {
#pragma unroll
    for (int u = 0; u < 5; ++u) {
      int r = H0 + o * 5 + u;
      const float* row = t + r * 136 + col + 2;
      float v0 = row[0], v1 = row[1], v2 = row[2], v3 = row[3], v4 = row[4];
#pragma unroll
      for (int ky = 0; ky < 5; ++ky) {
        int sl = (H0 + u + 5 - ky) % 5;
        acc[sl] += w[ky * 5 + 0] * v0 + w[ky * 5 + 1] * v1 + w[ky * 5 + 2] * v2 +
                   w[ky * 5 + 3] * v3 + w[ky * 5 + 4] * v4;
      }
      int dy = r - 4;
      int sl = (H0 + u + 1) % 5;
      float ov = acc[sl];
      h1[outbase + (size_t)dy * 128 + col] = ov;
      s += ov; sq += ov * ov;
      acc[sl] = 0.f;
    }
  }
#pragma unroll
  for (int u = 0; u < 3; ++u) {
    int r = H0 + 65 + u;
    const float* row = t + r * 136 + col + 2;
    float v0 = row[0], v1 = row[1], v2 = row[2], v3 = row[3], v4 = row[4];
#pragma unroll
    for (int ky = 0; ky < 5; ++ky) {
      int sl = (H0 + u + 5 - ky) % 5;
      acc[sl] += w[ky * 5 + 0] * v0 + w[ky * 5 + 1] * v1 + w[ky * 5 + 2] * v2 +
                 w[ky * 5 + 3] * v3 + w[ky * 5 + 4] * v4;
    }
    int dy = r - 4;
    int sl = (H0 + u + 1) % 5;
    float ov = acc[sl];
    h1[outbase + (size_t)dy * 128 + col] = ov;
    s += ov; sq += ov * ov;
    acc[sl] = 0.f;
  }
}

__global__ __launch_bounds__(256) void k_dwconv_v2(const void* __restrict__ x,
                                                   const void* __restrict__ gng,
                                                   const float* __restrict__ P,
                                                   float* __restrict__ h1,
                                                   float* __restrict__ gst) {
  int bc = blockIdx.x;
  int b = bc >> 7, chan = bc & 127;
  bool f32x = in_is_f32(gng);
  __shared__ __align__(16) float t[132 * 136];  // 71,808 B
  __shared__ float red[8];
  for (int i = threadIdx.x; i < (132 * 136) / 4; i += 256)
    ((float4*)t)[i] = make_float4(0.f, 0.f, 0.f, 0.f);
  __syncthreads();
  const float* xf = (const float*)x + (size_t)bc * 16384;
  const unsigned short* xb = (const unsigned short*)x + (size_t)bc * 16384;
  for (int i = threadIdx.x; i < 4096; i += 256) {
    int dy = i >> 5, dc = (i & 31) * 4;
    float4 v;
    if (f32x) {
      v = *(const float4*)&xf[i * 4];
    } else {
      ushort4 r4 = *(const ushort4*)&xb[i * 4];
      v = make_float4(b2f(r4.x), b2f(r4.y), b2f(r4.z), b2f(r4.w));
    }
    *(float4*)&t[(dy + 2) * 136 + dc + 4] = v;
  }
  float w[25];
#pragma unroll
  for (int k = 0; k < 25; ++k) w[k] = P[P_DWW + chan * 25 + k];
  __syncthreads();
  int col = threadIdx.x & 127;
  float s = 0.f, sq = 0.f;
  size_t outbase = (size_t)bc * 16384;
  if (threadIdx.x < 128) dw_col<0>(t, w, col, h1, outbase, s, sq);
  else                   dw_col<64>(t, w, col, h1, outbase, s, sq);
  for (int o = 32; o; o >>= 1) { s += __shfl_down(s, o, 64); sq += __shfl_down(sq, o, 64); }
  int wv = threadIdx.x >> 6;
  if ((threadIdx.x & 63) == 0) { red[wv] = s; red[4 + wv] = sq; }
  __syncthreads();
  if (threadIdx.x == 0) {
    float ts = red[0] + red[1] + red[2] + red[3];
    float tq = red[4] + red[5] + red[6] + red[7];
    int g = (b << 3) + (chan >> 4);
    atomicAdd(&gst[g * 2], ts);
    atomicAdd(&gst[g * 2 + 1], tq);
  }
}

__global__ void k_stats(const float* __restrict__ gst, float* __restrict__ mr) {
  int g = threadIdx.x;
  if (g < 64) {
    const float invN = 1.f / 262144.f;
    float mean = gst[g * 2] * invN;
    float var = gst[g * 2 + 1] * invN - mean * mean;
    mr[g * 2] = mean;
    mr[g * 2 + 1] = rsqrtf(var + 1e-5f);
  }
}

// ---------------- K3: GN + exact GELU + 1x1 conv + tanh*8 -> offset (f32 out) ----
__global__ __launch_bounds__(128) void k_gn_off(const float* __restrict__ h1,
                                                const float* __restrict__ mr,
                                                const float* __restrict__ P,
                                                float* __restrict__ offf,
                                                float* __restrict__ dout) {
  int bh = blockIdx.x;
  int b = bh >> 7, h = bh & 127;
  int w = threadIdx.x;
  float acc = 0.f;
  for (int c = 0; c < 128; ++c) {
    float v = h1[(((size_t)(b * 128 + c)) * 128 + h) * 128 + w];
    int g = b * 8 + (c >> 4);
    float nv = (v - mr[g * 2]) * mr[g * 2 + 1] * P[P_GNG + c] + P[P_GNB + c];
    float ge = 0.5f * nv * (1.f + erff(nv * 0.70710678118f));
    acc += ge * P[P_PWW + c];
  }
  float off = acc + P[P_PWB];
  float ofv = tanhf(off) * 8.0f;
  offf[bh * 128 + w] = ofv;
  dout[16777216 + bh * 128 + w] = ofv;
}

// ---------------- K4 v3: grid sample + transpose -> seq f32 + bf16 ---------------
__global__ __launch_bounds__(256) void k_deform_v3(const void* __restrict__ x,
                                                   const void* __restrict__ gng,
                                                   const float* __restrict__ offf,
                                                   float* __restrict__ seqc,
                                                   unsigned short* __restrict__ seqb,
                                                   int s0) {
  int bh = s0 + blockIdx.x;
  int b = bh >> 7, h = bh & 127;
  int w = threadIdx.x & 127;
  int half = threadIdx.x >> 7;  // 0..1
  bool f32x = in_is_f32(gng);
  __shared__ float t[128 * 129];
  float ofv = offf[bh * 128 + w];
  float gy = -1.f + (2.f / 127.f) * (float)h + ofv * (2.f / 127.f);
  gy = fminf(fmaxf(gy, -1.f), 1.f);
  float py = (gy + 1.f) * 0.5f * 127.f;
  py = fminf(fmaxf(py, 0.f), 127.f);
  float y0f = floorf(py);
  float wy = py - y0f;
  int y0 = (int)y0f;
  int y1 = min(y0 + 1, 127);
  const float* xfb = (const float*)x + (size_t)b * 128 * 16384;
  const unsigned short* xbb = (const unsigned short*)x + (size_t)b * 128 * 16384;
  for (int c = half * 64; c < half * 64 + 64; ++c) {
    size_t o0 = (size_t)c * 16384 + y0 * 128 + w;
    size_t o1 = (size_t)c * 16384 + y1 * 128 + w;
    float v0, v1;
    if (f32x) { v0 = xfb[o0]; v1 = xfb[o1]; }
    else      { v0 = b2f(xbb[o0]); v1 = b2f(xbb[o1]); }
    t[c * 129 + w] = v0 + wy * (v1 - v0);
  }
  __syncthreads();
  int c = threadIdx.x & 127;
  float* sp = seqc + (size_t)blockIdx.x * 16384;
  unsigned short* spb = seqb + (size_t)blockIdx.x * 16384;
  for (int l = half * 64; l < half * 64 + 64; ++l) {
    float v = t[c * 129 + l];
    sp[l * 128 + c] = v;
    spb[l * 128 + c] = f2b(v);
  }
}

// ---------------- G1 MFMA: z/xBC = seq @ wproj^T (bf16 in, f32 out) --------------
__global__ __launch_bounds__(256) void k_gemm1_mf(const unsigned short* __restrict__ seqb,
                                                  const unsigned short* __restrict__ wprojh,
                                                  float* __restrict__ z,
                                                  float* __restrict__ xbc) {
  __shared__ __align__(16) unsigned short Al[128 * 136];
  __shared__ __align__(16) unsigned short Bl[128 * 136];
  int m0 = blockIdx.x * 128;
  int e0 = blockIdx.y * 128;   // 0..512; covers e<640 exactly
  for (int i = threadIdx.x; i < 2048; i += 256) {
    int row = i >> 4, ch = i & 15;
    *(float4*)&Al[row * 136 + ch * 8] =
        *(const float4*)&seqb[(size_t)(m0 + row) * 128 + ch * 8];
    *(float4*)&Bl[row * 136 + ch * 8] =
        *(const float4*)&wprojh[(size_t)(e0 + row) * 128 + ch * 8];
  }
  __syncthreads();
  int lane = threadIdx.x & 63;
  int wv = threadIdx.x >> 6;
  int wm = wv >> 1, wn = wv & 1;
  int lr = lane & 15;
  int kb = lane >> 4;
  f32x4 acc[4][4] = {};
#pragma unroll
  for (int kk = 0; kk < 4; ++kk) {
    bf16x8 af[4], bf[4];
#pragma unroll
    for (int f = 0; f < 4; ++f)
      af[f] = *(const bf16x8*)&Al[(wm * 64 + f * 16 + lr) * 136 + kk * 32 + kb * 8];
#pragma unroll
    for (int f = 0; f < 4; ++f)
      bf[f] = *(const bf16x8*)&Bl[(wn * 64 + f * 16 + lr) * 136 + kk * 32 + kb * 8];
#pragma unroll
    for (int fm = 0; fm < 4; ++fm)
#pragma unroll
      for (int fn = 0; fn < 4; ++fn)
        acc[fm][fn] = __builtin_amdgcn_mfma_f32_16x16x32_bf16(af[fm], bf[fn],
                                                              acc[fm][fn], 0, 0, 0);
  }
#pragma unroll
  for (int fm = 0; fm < 4; ++fm)
#pragma unroll
    for (int fn = 0; fn < 4; ++fn) {
      int e = e0 + wn * 64 + fn * 16 + lr;
#pragma unroll
      for (int r = 0; r < 4; ++r) {
        int m = m0 + wm * 64 + fm * 16 + kb * 4 + r;
        float v = acc[fm][fn][r];
        if (e < 256) z[(size_t)m * 256 + e] = v;
        else         xbc[(size_t)m * 384 + (e - 256)] = v;
      }
    }
}

// ---------------- K_dt: dt columns in f32 (exp-sensitive path) -------------------
__global__ __launch_bounds__(256) void k_dt(const float* __restrict__ seqf,
                                            const float* __restrict__ P,
                                            float* __restrict__ dtb) {
  int bb = blockIdx.x;            // CH*4 blocks; 32 tokens each
  int sq = bb >> 2, q = bb & 3;
  __shared__ float ss[32 * 133];
  __shared__ float wt[1024];
  const float* sp = seqf + (size_t)sq * 16384 + q * 32 * 128;
  for (int i = threadIdx.x; i < 4096; i += 256) {
    int t = i >> 7, k = i & 127;
    ss[t * 133 + k] = sp[i];
  }
  for (int i = threadIdx.x; i < 1024; i += 256) wt[i] = P[P_WDT + i];
  __syncthreads();
  int head = threadIdx.x >> 5, t = threadIdx.x & 31;
  const float* wh = &wt[head * 128];
  const float* sr = &ss[t * 133];
  float acc = 0.f;
#pragma unroll 8
  for (int k = 0; k < 128; ++k) acc += sr[k] * wh[k];
  float dv = acc + P[P_DTB + head];
  float spv = (dv > 20.f) ? dv : log1pf(__expf(dv));
  dtb[((size_t)sq * 128 + q * 32 + t) * 8 + head] = spv;
}

// ---------------- K6 v7: fused conv1d+SiLU+scan, 512 threads / 8 waves -----------
// Thread = (head, d-duo, squad): 2d x 16s = 32 states (v5's measured-69us
// geometry). Conv pass load-balanced over 768 (column, row-half) items so all
// 512 threads work. Main l-loop identical to v5. Grid = CH blocks = 1/CU, so
// 512 threads -> 8 waves/CU for latency hiding (v6's 256 -> 4 was the
// regression).
__global__ __launch_bounds__(512) void k_scan_v7(const float* __restrict__ xbc,
                                                 const float* __restrict__ dtb,
                                                 const float* __restrict__ P,
                                                 float* __restrict__ ys) {
  int seq = blockIdx.x;
  int head = threadIdx.x >> 6;          // one wave per head
  int dduo = (threadIdx.x >> 2) & 15;   // d = dduo*2 + {0,1}
  int squad = threadIdx.x & 3;          // s-range squad*16 .. +15
  float A = -__expf(P[P_ALOG + head]);
  float Dk = P[P_DSKIP + head];
  float h0[16], h1[16];
#pragma unroll
  for (int s = 0; s < 16; ++s) { h0[s] = 0.f; h1[s] = 0.f; }
  __shared__ __align__(16) float sRAW[19][388];  // raw xbc rows lt-3..lt+15
  __shared__ __align__(16) float sROW[16][388];  // conv+SiLU rows lt..lt+15
  __shared__ float sDT[16][8];
  const float* base = xbc + (size_t)seq * 49152;
  const float* dtp = dtb + (size_t)seq * 1024;
  float* yp = ys + (size_t)seq * 32768;
  const int sbase = 256 + squad * 16;
  const int cbase = sbase + 64;
  for (int lt = 0; lt < 128; lt += 16) {
    // Stage raw rows l = lt-3 .. lt+15 (19 rows x 384 f32, float4).
    for (int i = threadIdx.x; i < 1824; i += 512) {
      int r = i / 96, c4 = (i % 96) * 4;
      int l = lt - 3 + r;
      float4 v = make_float4(0.f, 0.f, 0.f, 0.f);
      if (l >= 0) v = *(const float4*)&base[(size_t)l * 384 + c4];
      *(float4*)&sRAW[r][c4] = v;
    }
    if (threadIdx.x < 128)
      sDT[threadIdx.x >> 3][threadIdx.x & 7] =
          dtp[(lt + (threadIdx.x >> 3)) * 8 + (threadIdx.x & 7)];
    __syncthreads();
    // Conv pass: 768 items = (column e, row-half). Output row ll needs raw
    // sRAW[ll..ll+3]; half hf covers ll = hf*8..hf*8+7.
    for (int i = threadIdx.x; i < 768; i += 512) {
      int hf = i / 384;
      int e = i - hf * 384;
      int r0 = hf * 8;
      float w0 = P[P_CW + e * 4 + 0], w1 = P[P_CW + e * 4 + 1];
      float w2 = P[P_CW + e * 4 + 2], w3 = P[P_CW + e * 4 + 3];
      float bb = P[P_CB + e];
      float x0 = sRAW[r0][e], x1 = sRAW[r0 + 1][e], x2 = sRAW[r0 + 2][e];
#pragma unroll
      for (int ll = 0; ll < 8; ++ll) {
        float x3 = sRAW[r0 + ll + 3][e];
        float a = bb + w0 * x0 + w1 * x1 + w2 * x2 + w3 * x3;
        sROW[r0 + ll][e] = a / (1.f + __expf(-a));
        x0 = x1; x1 = x2; x2 = x3;
      }
    }
    __syncthreads();
#pragma unroll 1
    for (int ll = 0; ll < 16; ++ll) {
      float dt = sDT[ll][head];
      float dA = __expf(dt * A);
      float2 xv = *(const float2*)&sROW[ll][head * 32 + dduo * 2];
      float c0 = dt * xv.x, c1 = dt * xv.y;
      float a0 = 0.f, b0 = 0.f, a1 = 0.f, b1 = 0.f;
#pragma unroll
      for (int s4 = 0; s4 < 4; ++s4) {
        float4 bb = *(const float4*)&sROW[ll][sbase + s4 * 4];
        float4 cc = *(const float4*)&sROW[ll][cbase + s4 * 4];
        h0[s4 * 4 + 0] = h0[s4 * 4 + 0] * dA + c0 * bb.x; a0 += h0[s4 * 4 + 0] * cc.x;
        h0[s4 * 4 + 1] = h0[s4 * 4 + 1] * dA + c0 * bb.y; b0 += h0[s4 * 4 + 1] * cc.y;
        h0[s4 * 4 + 2] = h0[s4 * 4 + 2] * dA + c0 * bb.z; a0 += h0[s4 * 4 + 2] * cc.z;
        h0[s4 * 4 + 3] = h0[s4 * 4 + 3] * dA + c0 * bb.w; b0 += h0[s4 * 4 + 3] * cc.w;
        h1[s4 * 4 + 0] = h1[s4 * 4 + 0] * dA + c1 * bb.x; a1 += h1[s4 * 4 + 0] * cc.x;
        h1[s4 * 4 + 1] = h1[s4 * 4 + 1] * dA + c1 * bb.y; b1 += h1[s4 * 4 + 1] * cc.y;
        h1[s4 * 4 + 2] = h1[s4 * 4 + 2] * dA + c1 * bb.z; a1 += h1[s4 * 4 + 2] * cc.z;
        h1[s4 * 4 + 3] = h1[s4 * 4 + 3] * dA + c1 * bb.w; b1 += h1[s4 * 4 + 3] * cc.w;
      }
      float y0 = quad_sum(a0 + b0);
      float y1 = quad_sum(a1 + b1);
      if (squad == 0) {
        float2 o = make_float2(y0 + Dk * xv.x, y1 + Dk * xv.y);
        *(float2*)&yp[(size_t)(lt + ll) * 256 + head * 32 + dduo * 2] = o;
      }
    }
    __syncthreads();
  }
}

// ---------------- K7 v4: gate + RMS norm -> ynorm bf16 ---------------------------
__global__ __launch_bounds__(256) void k_gate_v4(const float* __restrict__ ys,
                                                 const float* __restrict__ z,
                                                 const float* __restrict__ P,
                                                 unsigned short* __restrict__ ynb) {
  int l = blockIdx.x;
  int e = threadIdx.x;
  __shared__ float red[4];
  float yv = ys[(size_t)l * 256 + e];
  float zv = z[(size_t)l * 256 + e];
  float g = zv / (1.f + __expf(-zv));
  float y = yv * g;
  float ss = y * y;
  for (int o = 32; o; o >>= 1) ss += __shfl_down(ss, o, 64);
  if ((threadIdx.x & 63) == 0) red[threadIdx.x >> 6] = ss;
  __syncthreads();
  float tot = red[0] + red[1] + red[2] + red[3];
  float r = rsqrtf(tot * (1.f / 256.f) + 1e-5f);
  ynb[(size_t)l * 256 + e] = f2b(y * r * P[P_NG + e]);
}

// ---------------- G2 MFMA: out = ynorm @ outw^T (bf16 in, f32 NCHW out) ----------
__global__ __launch_bounds__(256) void k_gemm2_mf(const unsigned short* __restrict__ ynb,
                                                  const unsigned short* __restrict__ outwh,
                                                  float* __restrict__ dout,
                                                  int tok0) {
  __shared__ __align__(16) unsigned short Al[128 * 136];
  __shared__ __align__(16) unsigned short Bl[128 * 136];
  int t0 = blockIdx.x * 128;
  int lane = threadIdx.x & 63;
  int wv = threadIdx.x >> 6;
  int wm = wv >> 1, wn = wv & 1;
  int lr = lane & 15;
  int kb = lane >> 4;
  f32x4 acc[4][4] = {};
  for (int kt = 0; kt < 256; kt += 128) {
    for (int i = threadIdx.x; i < 2048; i += 256) {
      int row = i >> 4, ch = i & 15;
      *(float4*)&Al[row * 136 + ch * 8] =
          *(const float4*)&ynb[(size_t)(t0 + row) * 256 + kt + ch * 8];
      *(float4*)&Bl[row * 136 + ch * 8] =
          *(const float4*)&outwh[(size_t)row * 256 + kt + ch * 8];
    }
    __syncthreads();
#pragma unroll
    for (int kk = 0; kk < 4; ++kk) {
      bf16x8 af[4], bf[4];
#pragma unroll
      for (int f = 0; f < 4; ++f)
        af[f] = *(const bf16x8*)&Al[(wm * 64 + f * 16 + lr) * 136 + kk * 32 + kb * 8];
#pragma unroll
      for (int f = 0; f < 4; ++f)
        bf[f] = *(const bf16x8*)&Bl[(wn * 64 + f * 16 + lr) * 136 + kk * 32 + kb * 8];
#pragma unroll
      for (int fm = 0; fm < 4; ++fm)
#pragma unroll
        for (int fn = 0; fn < 4; ++fn)
          acc[fm][fn] = __builtin_amdgcn_mfma_f32_16x16x32_bf16(af[fm], bf[fn],
                                                                acc[fm][fn], 0, 0, 0);
    }
    __syncthreads();
  }
#pragma unroll
  for (int fm = 0; fm < 4; ++fm)
#pragma unroll
    for (int fn = 0; fn < 4; ++fn) {
      int cc = wn * 64 + fn * 16 + lr;
#pragma unroll
      for (int r = 0; r < 4; ++r) {
        int l = tok0 + t0 + wm * 64 + fm * 16 + kb * 4 + r;
        int b = l >> 14, rem = l & 16383;
        int hh = rem >> 7, ww = rem & 127;
        dout[(((size_t)(b * 128 + cc) * 128 + hh) * 128 + ww)] = acc[fm][fn][r];
      }
    }
}

extern "C" void kernel_launch(void* const* d_in, const int* in_sizes, int n_in,
                              void* d_out, int out_size, void* d_ws, size_t ws_size,
                              hipStream_t stream) {
  const void* x      = d_in[0];
  const void* dww    = d_in[1];
  const void* gng    = d_in[2];
  const void* gnb    = d_in[3];
  const void* pww    = d_in[4];
  const void* pwb    = d_in[5];
  const void* wproj  = d_in[6];
  const void* cw     = d_in[7];
  const void* cb     = d_in[8];
  const void* dtbias = d_in[9];
  const void* alog   = d_in[10];
  const void* dskip  = d_in[11];
  const void* ng     = d_in[12];
  const void* outw   = d_in[13];
  float* out = (float*)d_out;

  char* ws = (char*)d_ws;
  float* gst            = (float*)(ws + 0);
  float* mr             = (float*)(ws + 4096);
  float* P              = (float*)(ws + 8192);
  unsigned short* wpjh  = (unsigned short*)(ws + 40960);   // 648*128*2 = 165,888
  unsigned short* outwh = (unsigned short*)(ws + 372736);  // 128*256*2 = 65,536
  float* offf           = (float*)(ws + 503808);
  char* cbase           = ws + 1028096;

  // h1 (f32) lives in d_out's out_2d region.
  float* h1f = out;

  // Per-sequence chunk bytes:
  //   seqf 65536 + seqbf 32768 + z 131072 + xbc 196608 + dtb 4096
  //   + ys 131072 + ynbf 65536 = 626,688.
  const int opts[11] = {1024, 512, 256, 128, 64, 32, 16, 8, 4, 2, 1};
  int CH = 1;
  for (int i = 0; i < 11; ++i) {
    if (1028096ull + (unsigned long long)opts[i] * 626688ull <= (unsigned long long)ws_size) {
      CH = opts[i];
      break;
    }
  }
  int NC = 1024 / CH;

  float* seqf          = (float*)(cbase);
  unsigned short* seqb = (unsigned short*)(cbase + (size_t)CH * 65536);
  float* zf            = (float*)(cbase + (size_t)CH * 98304);
  float* xbcf          = (float*)(cbase + (size_t)CH * 229376);
  float* dtbf          = (float*)(cbase + (size_t)CH * 425984);
  float* ysf           = (float*)(cbase + (size_t)CH * 430080);
  unsigned short* ynbf = (unsigned short*)(cbase + (size_t)CH * 561152);

  k_prep_params<<<1, 256, 0, stream>>>(dww, cw, cb, gng, gnb, pww, pwb, dtbias,
                                       alog, dskip, ng, wproj, P, gst);
  k_prep_w<<<128, 256, 0, stream>>>(wproj, outw, gng, wpjh, outwh);
  k_dwconv_v2<<<1024, 256, 0, stream>>>(x, gng, P, h1f, gst);
  k_stats<<<1, 64, 0, stream>>>(gst, mr);
  k_gn_off<<<1024, 128, 0, stream>>>(h1f, mr, P, offf, out);

  for (int c = 0; c < NC; ++c) {
    int s0 = c * CH;
    k_deform_v3<<<CH, 256, 0, stream>>>(x, gng, offf, seqf, seqb, s0);
    k_gemm1_mf<<<dim3(CH, 5), 256, 0, stream>>>(seqb, wpjh, zf, xbcf);
    k_dt<<<CH * 4, 256, 0, stream>>>(seqf, P, dtbf);
    k_scan_v7<<<CH, 512, 0, stream>>>(xbcf, dtbf, P, ysf);
    k_gate_v4<<<CH * 128, 256, 0, stream>>>(ysf, zf, P, ynbf);
    k_gemm2_mf<<<CH, 256, 0, stream>>>(ynbf, outwh, out, s0 * 128);
  }
}

// Round 13
// 680.849 us; speedup vs baseline: 2.2568x; 1.1790x over previous
//
#include <hip/hip_runtime.h>
#include <math.h>

// B=8, C=128, H=128, W=128, D_INNER=256, D_STATE=64, HEADDIM=32, NHEADS=8,
// D_CONV=4, GN_GROUPS=8, D_XBC=384, D_INPROJ=648.
// Inputs f32 (probed via gn_g word0). OUTPUT IS F32 (reference output dtype).
// d_out = [out_2d: 16,777,216 f32][offset: 131,072 f32].
// h1 (f32) is staged in d_out's out_2d region.
//
// NOTE: Round 12 bench failed with UnresponsiveContainer (infra, same pod as
// Round 7); this is an unchanged resubmit for a clean measurement.
// Round-11 -> 12: scan (and deform/gemm2) capped at 1 block/CU because grid =
// CH = 256, and CH was workspace-limited (626,688 B/seq). Shrink to 495,616
// B/seq (drop f32 seq -- k_dt reads bf16 seqb with f32 weights; z stored bf16,
// it only feeds silu-gating) so CH=512 -> 2 blocks/CU for all per-chunk
// kernels, absorbing the measured ~35% latency slack in the scan.

typedef __bf16 bf16x8 __attribute__((ext_vector_type(8)));
typedef float f32x4 __attribute__((ext_vector_type(4)));

__device__ __forceinline__ float b2f(unsigned short u) {
  return __uint_as_float(((unsigned int)u) << 16);
}
__device__ __forceinline__ unsigned short f2b(float f) {
  unsigned int u = __float_as_uint(f);
  unsigned int r = (u + 0x7FFFu + ((u >> 16) & 1u)) >> 16;  // RNE
  return (unsigned short)r;
}
__device__ __forceinline__ bool in_is_f32(const void* gng) {
  return ((const unsigned int*)gng)[0] == 0x3F800000u;
}

// Sum over the 4-lane quad (lane&3 butterfly) on the VALU pipe.
__device__ __forceinline__ float quad_sum(float v) {
#if __has_builtin(__builtin_amdgcn_update_dpp)
  int p = __builtin_amdgcn_update_dpp(0, __float_as_int(v), 0xB1, 0xF, 0xF, true);
  v += __int_as_float(p);  // xor 1
  p = __builtin_amdgcn_update_dpp(0, __float_as_int(v), 0x4E, 0xF, 0xF, true);
  v += __int_as_float(p);  // xor 2
#else
  v += __shfl_xor(v, 1, 64);
  v += __shfl_xor(v, 2, 64);
#endif
  return v;
}

#define P_DWW 0
#define P_CW 3200
#define P_CB 4736
#define P_GNG 5120
#define P_GNB 5248
#define P_PWW 5376
#define P_PWB 5504
#define P_DTB 5505
#define P_ALOG 5513
#define P_DSKIP 5521
#define P_NG 5529
#define P_WDT 5792   // wproj rows 640..647 in f32 (8*128) for the dt path

__global__ void k_prep_params(const void* dww, const void* cw, const void* cb,
                              const void* gng, const void* gnb, const void* pww,
                              const void* pwb, const void* dtbias, const void* alog,
                              const void* dskip, const void* ng, const void* wproj,
                              float* __restrict__ P, float* __restrict__ gst) {
  bool f = in_is_f32(gng);
  int tid = threadIdx.x;
  if (tid < 128) gst[tid] = 0.f;
  auto cvt = [&](const void* src, int n, int off) {
    for (int i = tid; i < n; i += 256)
      P[off + i] = f ? ((const float*)src)[i] : b2f(((const unsigned short*)src)[i]);
  };
  cvt(dww, 3200, P_DWW);
  cvt(cw, 1536, P_CW);
  cvt(cb, 384, P_CB);
  cvt(gng, 128, P_GNG);
  cvt(gnb, 128, P_GNB);
  cvt(pww, 128, P_PWW);
  cvt(pwb, 1, P_PWB);
  cvt(dtbias, 8, P_DTB);
  cvt(alog, 8, P_ALOG);
  cvt(dskip, 8, P_DSKIP);
  cvt(ng, 256, P_NG);
  for (int i = tid; i < 1024; i += 256)
    P[P_WDT + i] = f ? ((const float*)wproj)[81920 + i]
                     : b2f(((const unsigned short*)wproj)[81920 + i]);
}

// Weights -> bf16 (direct copy if inputs already bf16).
__global__ void k_prep_w(const void* wproj, const void* outw, const void* gng,
                         unsigned short* __restrict__ wprojh,
                         unsigned short* __restrict__ outwh) {
  bool f = in_is_f32(gng);
  int stride = gridDim.x * blockDim.x;
  for (int i = blockIdx.x * blockDim.x + threadIdx.x; i < 82944; i += stride)
    wprojh[i] = f ? f2b(((const float*)wproj)[i]) : ((const unsigned short*)wproj)[i];
  for (int i = blockIdx.x * blockDim.x + threadIdx.x; i < 32768; i += stride)
    outwh[i] = f ? f2b(((const float*)outw)[i]) : ((const unsigned short*)outw)[i];
}

// ---------------- K1 v2: depthwise 5x5 conv + group stats ------------------------
template <int H0>
__device__ __forceinline__ void dw_col(const float* __restrict__ t,
                                       const float* __restrict__ w, int col,
                                       float* __restrict__ h1, size_t outbase,
                                       float& s, float& sq) {
  float acc[5] = {0.f, 0.f, 0.f, 0.f, 0.f};
#pragma unroll
  for (int u = 0; u < 5; ++u) {
    int r = H0 + u;
    const float* row = t + r * 136 + col + 2;
    float v0 = row[0], v1 = row[1], v2 = row[2], v3 = row[3], v4 = row[4];
#pragma unroll
    for (int ky = 0; ky <= u; ++ky) {
      int sl = (H0 + u + 5 - ky) % 5;
      acc[sl] += w[ky * 5 + 0] * v0 + w[ky * 5 + 1] * v1 + w[ky * 5 + 2] * v2 +
                 w[ky * 5 + 3] * v3 + w[ky * 5 + 4] * v4;
    }
    if (u == 4) {
      int sl = H0 % 5;
      float ov = acc[sl];
      h1[outbase + (size_t)H0 * 128 + col] = ov;
      s += ov; sq += ov * ov;
      acc[sl] = 0.f;
    }
  }
  for (int o = 1; o < 13; ++o) {
#pragma unroll
    for (int u = 0; u < 5; ++u) {
      int r = H0 + o * 5 + u;
      const float* row = t + r * 136 + col + 2;
      float v0 = row[0], v1 = row[1], v2 = row[2], v3 = row[3], v4 = row[4];
#pragma unroll
      for (int ky = 0; ky < 5; ++ky) {
        int sl = (H0 + u + 5 - ky) % 5;
        acc[sl] += w[ky * 5 + 0] * v0 + w[ky * 5 + 1] * v1 + w[ky * 5 + 2] * v2 +
                   w[ky * 5 + 3] * v3 + w[ky * 5 + 4] * v4;
      }
      int dy = r - 4;
      int sl = (H0 + u + 1) % 5;
      float ov = acc[sl];
      h1[outbase + (size_t)dy * 128 + col] = ov;
      s += ov; sq += ov * ov;
      acc[sl] = 0.f;
    }
  }
#pragma unroll
  for (int u = 0; u < 3; ++u) {
    int r = H0 + 65 + u;
    const float* row = t + r * 136 + col + 2;
    float v0 = row[0], v1 = row[1], v2 = row[2], v3 = row[3], v4 = row[4];
#pragma unroll
    for (int ky = 0; ky < 5; ++ky) {
      int sl = (H0 + u + 5 - ky) % 5;
      acc[sl] += w[ky * 5 + 0] * v0 + w[ky * 5 + 1] * v1 + w[ky * 5 + 2] * v2 +
                 w[ky * 5 + 3] * v3 + w[ky * 5 + 4] * v4;
    }
    int dy = r - 4;
    int sl = (H0 + u + 1) % 5;
    float ov = acc[sl];
    h1[outbase + (size_t)dy * 128 + col] = ov;
    s += ov; sq += ov * ov;
    acc[sl] = 0.f;
  }
}

__global__ __launch_bounds__(256) void k_dwconv_v2(const void* __restrict__ x,
                                                   const void* __restrict__ gng,
                                                   const float* __restrict__ P,
                                                   float* __restrict__ h1,
                                                   float* __restrict__ gst) {
  int bc = blockIdx.x;
  int b = bc >> 7, chan = bc & 127;
  bool f32x = in_is_f32(gng);
  __shared__ __align__(16) float t[132 * 136];  // 71,808 B
  __shared__ float red[8];
  for (int i = threadIdx.x; i < (132 * 136) / 4; i += 256)
    ((float4*)t)[i] = make_float4(0.f, 0.f, 0.f, 0.f);
  __syncthreads();
  const float* xf = (const float*)x + (size_t)bc * 16384;
  const unsigned short* xb = (const unsigned short*)x + (size_t)bc * 16384;
  for (int i = threadIdx.x; i < 4096; i += 256) {
    int dy = i >> 5, dc = (i & 31) * 4;
    float4 v;
    if (f32x) {
      v = *(const float4*)&xf[i * 4];
    } else {
      ushort4 r4 = *(const ushort4*)&xb[i * 4];
      v = make_float4(b2f(r4.x), b2f(r4.y), b2f(r4.z), b2f(r4.w));
    }
    *(float4*)&t[(dy + 2) * 136 + dc + 4] = v;
  }
  float w[25];
#pragma unroll
  for (int k = 0; k < 25; ++k) w[k] = P[P_DWW + chan * 25 + k];
  __syncthreads();
  int col = threadIdx.x & 127;
  float s = 0.f, sq = 0.f;
  size_t outbase = (size_t)bc * 16384;
  if (threadIdx.x < 128) dw_col<0>(t, w, col, h1, outbase, s, sq);
  else                   dw_col<64>(t, w, col, h1, outbase, s, sq);
  for (int o = 32; o; o >>= 1) { s += __shfl_down(s, o, 64); sq += __shfl_down(sq, o, 64); }
  int wv = threadIdx.x >> 6;
  if ((threadIdx.x & 63) == 0) { red[wv] = s; red[4 + wv] = sq; }
  __syncthreads();
  if (threadIdx.x == 0) {
    float ts = red[0] + red[1] + red[2] + red[3];
    float tq = red[4] + red[5] + red[6] + red[7];
    int g = (b << 3) + (chan >> 4);
    atomicAdd(&gst[g * 2], ts);
    atomicAdd(&gst[g * 2 + 1], tq);
  }
}

__global__ void k_stats(const float* __restrict__ gst, float* __restrict__ mr) {
  int g = threadIdx.x;
  if (g < 64) {
    const float invN = 1.f / 262144.f;
    float mean = gst[g * 2] * invN;
    float var = gst[g * 2 + 1] * invN - mean * mean;
    mr[g * 2] = mean;
    mr[g * 2 + 1] = rsqrtf(var + 1e-5f);
  }
}

// ---------------- K3: GN + exact GELU + 1x1 conv + tanh*8 -> offset (f32 out) ----
__global__ __launch_bounds__(128) void k_gn_off(const float* __restrict__ h1,
                                                const float* __restrict__ mr,
                                                const float* __restrict__ P,
                                                float* __restrict__ offf,
                                                float* __restrict__ dout) {
  int bh = blockIdx.x;
  int b = bh >> 7, h = bh & 127;
  int w = threadIdx.x;
  float acc = 0.f;
  for (int c = 0; c < 128; ++c) {
    float v = h1[(((size_t)(b * 128 + c)) * 128 + h) * 128 + w];
    int g = b * 8 + (c >> 4);
    float nv = (v - mr[g * 2]) * mr[g * 2 + 1] * P[P_GNG + c] + P[P_GNB + c];
    float ge = 0.5f * nv * (1.f + erff(nv * 0.70710678118f));
    acc += ge * P[P_PWW + c];
  }
  float off = acc + P[P_PWB];
  float ofv = tanhf(off) * 8.0f;
  offf[bh * 128 + w] = ofv;
  dout[16777216 + bh * 128 + w] = ofv;
}

// ---------------- K4 v4: grid sample + transpose -> seq bf16 ---------------------
__global__ __launch_bounds__(256) void k_deform_v4(const void* __restrict__ x,
                                                   const void* __restrict__ gng,
                                                   const float* __restrict__ offf,
                                                   unsigned short* __restrict__ seqb,
                                                   int s0) {
  int bh = s0 + blockIdx.x;
  int b = bh >> 7, h = bh & 127;
  int w = threadIdx.x & 127;
  int half = threadIdx.x >> 7;  // 0..1
  bool f32x = in_is_f32(gng);
  __shared__ float t[128 * 129];
  float ofv = offf[bh * 128 + w];
  float gy = -1.f + (2.f / 127.f) * (float)h + ofv * (2.f / 127.f);
  gy = fminf(fmaxf(gy, -1.f), 1.f);
  float py = (gy + 1.f) * 0.5f * 127.f;
  py = fminf(fmaxf(py, 0.f), 127.f);
  float y0f = floorf(py);
  float wy = py - y0f;
  int y0 = (int)y0f;
  int y1 = min(y0 + 1, 127);
  const float* xfb = (const float*)x + (size_t)b * 128 * 16384;
  const unsigned short* xbb = (const unsigned short*)x + (size_t)b * 128 * 16384;
  for (int c = half * 64; c < half * 64 + 64; ++c) {
    size_t o0 = (size_t)c * 16384 + y0 * 128 + w;
    size_t o1 = (size_t)c * 16384 + y1 * 128 + w;
    float v0, v1;
    if (f32x) { v0 = xfb[o0]; v1 = xfb[o1]; }
    else      { v0 = b2f(xbb[o0]); v1 = b2f(xbb[o1]); }
    t[c * 129 + w] = v0 + wy * (v1 - v0);
  }
  __syncthreads();
  int c = threadIdx.x & 127;
  unsigned short* spb = seqb + (size_t)blockIdx.x * 16384;
  for (int l = half * 64; l < half * 64 + 64; ++l)
    spb[l * 128 + c] = f2b(t[c * 129 + l]);
}

// ---------------- G1 MFMA: z(bf16)/xBC(f32) = seq @ wproj^T ----------------------
__global__ __launch_bounds__(256) void k_gemm1_mf(const unsigned short* __restrict__ seqb,
                                                  const unsigned short* __restrict__ wprojh,
                                                  unsigned short* __restrict__ zb,
                                                  float* __restrict__ xbc) {
  __shared__ __align__(16) unsigned short Al[128 * 136];
  __shared__ __align__(16) unsigned short Bl[128 * 136];
  int m0 = blockIdx.x * 128;
  int e0 = blockIdx.y * 128;   // 0..512; covers e<640 exactly
  for (int i = threadIdx.x; i < 2048; i += 256) {
    int row = i >> 4, ch = i & 15;
    *(float4*)&Al[row * 136 + ch * 8] =
        *(const float4*)&seqb[(size_t)(m0 + row) * 128 + ch * 8];
    *(float4*)&Bl[row * 136 + ch * 8] =
        *(const float4*)&wprojh[(size_t)(e0 + row) * 128 + ch * 8];
  }
  __syncthreads();
  int lane = threadIdx.x & 63;
  int wv = threadIdx.x >> 6;
  int wm = wv >> 1, wn = wv & 1;
  int lr = lane & 15;
  int kb = lane >> 4;
  f32x4 acc[4][4] = {};
#pragma unroll
  for (int kk = 0; kk < 4; ++kk) {
    bf16x8 af[4], bf[4];
#pragma unroll
    for (int f = 0; f < 4; ++f)
      af[f] = *(const bf16x8*)&Al[(wm * 64 + f * 16 + lr) * 136 + kk * 32 + kb * 8];
#pragma unroll
    for (int f = 0; f < 4; ++f)
      bf[f] = *(const bf16x8*)&Bl[(wn * 64 + f * 16 + lr) * 136 + kk * 32 + kb * 8];
#pragma unroll
    for (int fm = 0; fm < 4; ++fm)
#pragma unroll
      for (int fn = 0; fn < 4; ++fn)
        acc[fm][fn] = __builtin_amdgcn_mfma_f32_16x16x32_bf16(af[fm], bf[fn],
                                                              acc[fm][fn], 0, 0, 0);
  }
#pragma unroll
  for (int fm = 0; fm < 4; ++fm)
#pragma unroll
    for (int fn = 0; fn < 4; ++fn) {
      int e = e0 + wn * 64 + fn * 16 + lr;
#pragma unroll
      for (int r = 0; r < 4; ++r) {
        int m = m0 + wm * 64 + fm * 16 + kb * 4 + r;
        float v = acc[fm][fn][r];
        if (e < 256) zb[(size_t)m * 256 + e] = f2b(v);
        else         xbc[(size_t)m * 384 + (e - 256)] = v;
      }
    }
}

// ---------------- K_dt: dt columns (bf16 activations x f32 weights) --------------
__global__ __launch_bounds__(256) void k_dt(const unsigned short* __restrict__ seqb,
                                            const float* __restrict__ P,
                                            float* __restrict__ dtb) {
  int bb = blockIdx.x;            // CH*4 blocks; 32 tokens each
  int sq = bb >> 2, q = bb & 3;
  __shared__ float ss[32 * 133];
  __shared__ float wt[1024];
  const unsigned short* sp = seqb + (size_t)sq * 16384 + q * 32 * 128;
  for (int i = threadIdx.x; i < 1024; i += 256) {
    int idx = i * 4;
    int t = idx >> 7, k = idx & 127;
    ushort4 r4 = *(const ushort4*)&sp[idx];
    ss[t * 133 + k + 0] = b2f(r4.x);
    ss[t * 133 + k + 1] = b2f(r4.y);
    ss[t * 133 + k + 2] = b2f(r4.z);
    ss[t * 133 + k + 3] = b2f(r4.w);
  }
  for (int i = threadIdx.x; i < 1024; i += 256) wt[i] = P[P_WDT + i];
  __syncthreads();
  int head = threadIdx.x >> 5, t = threadIdx.x & 31;
  const float* wh = &wt[head * 128];
  const float* sr = &ss[t * 133];
  float acc = 0.f;
#pragma unroll 8
  for (int k = 0; k < 128; ++k) acc += sr[k] * wh[k];
  float dv = acc + P[P_DTB + head];
  float spv = (dv > 20.f) ? dv : log1pf(__expf(dv));
  dtb[((size_t)sq * 128 + q * 32 + t) * 8 + head] = spv;
}

// ---------------- K6 v7: fused conv1d+SiLU+scan, 512 threads / 8 waves -----------
__global__ __launch_bounds__(512) void k_scan_v7(const float* __restrict__ xbc,
                                                 const float* __restrict__ dtb,
                                                 const float* __restrict__ P,
                                                 float* __restrict__ ys) {
  int seq = blockIdx.x;
  int head = threadIdx.x >> 6;          // one wave per head
  int dduo = (threadIdx.x >> 2) & 15;   // d = dduo*2 + {0,1}
  int squad = threadIdx.x & 3;          // s-range squad*16 .. +15
  float A = -__expf(P[P_ALOG + head]);
  float Dk = P[P_DSKIP + head];
  float h0[16], h1[16];
#pragma unroll
  for (int s = 0; s < 16; ++s) { h0[s] = 0.f; h1[s] = 0.f; }
  __shared__ __align__(16) float sRAW[19][388];  // raw xbc rows lt-3..lt+15
  __shared__ __align__(16) float sROW[16][388];  // conv+SiLU rows lt..lt+15
  __shared__ float sDT[16][8];
  const float* base = xbc + (size_t)seq * 49152;
  const float* dtp = dtb + (size_t)seq * 1024;
  float* yp = ys + (size_t)seq * 32768;
  const int sbase = 256 + squad * 16;
  const int cbase = sbase + 64;
  for (int lt = 0; lt < 128; lt += 16) {
    for (int i = threadIdx.x; i < 1824; i += 512) {
      int r = i / 96, c4 = (i % 96) * 4;
      int l = lt - 3 + r;
      float4 v = make_float4(0.f, 0.f, 0.f, 0.f);
      if (l >= 0) v = *(const float4*)&base[(size_t)l * 384 + c4];
      *(float4*)&sRAW[r][c4] = v;
    }
    if (threadIdx.x < 128)
      sDT[threadIdx.x >> 3][threadIdx.x & 7] =
          dtp[(lt + (threadIdx.x >> 3)) * 8 + (threadIdx.x & 7)];
    __syncthreads();
    for (int i = threadIdx.x; i < 768; i += 512) {
      int hf = i / 384;
      int e = i - hf * 384;
      int r0 = hf * 8;
      float w0 = P[P_CW + e * 4 + 0], w1 = P[P_CW + e * 4 + 1];
      float w2 = P[P_CW + e * 4 + 2], w3 = P[P_CW + e * 4 + 3];
      float bb = P[P_CB + e];
      float x0 = sRAW[r0][e], x1 = sRAW[r0 + 1][e], x2 = sRAW[r0 + 2][e];
#pragma unroll
      for (int ll = 0; ll < 8; ++ll) {
        float x3 = sRAW[r0 + ll + 3][e];
        float a = bb + w0 * x0 + w1 * x1 + w2 * x2 + w3 * x3;
        sROW[r0 + ll][e] = a / (1.f + __expf(-a));
        x0 = x1; x1 = x2; x2 = x3;
      }
    }
    __syncthreads();
#pragma unroll 1
    for (int ll = 0; ll < 16; ++ll) {
      float dt = sDT[ll][head];
      float dA = __expf(dt * A);
      float2 xv = *(const float2*)&sROW[ll][head * 32 + dduo * 2];
      float c0 = dt * xv.x, c1 = dt * xv.y;
      float a0 = 0.f, b0 = 0.f, a1 = 0.f, b1 = 0.f;
#pragma unroll
      for (int s4 = 0; s4 < 4; ++s4) {
        float4 bb = *(const float4*)&sROW[ll][sbase + s4 * 4];
        float4 cc = *(const float4*)&sROW[ll][cbase + s4 * 4];
        h0[s4 * 4 + 0] = h0[s4 * 4 + 0] * dA + c0 * bb.x; a0 += h0[s4 * 4 + 0] * cc.x;
        h0[s4 * 4 + 1] = h0[s4 * 4 + 1] * dA + c0 * bb.y; b0 += h0[s4 * 4 + 1] * cc.y;
        h0[s4 * 4 + 2] = h0[s4 * 4 + 2] * dA + c0 * bb.z; a0 += h0[s4 * 4 + 2] * cc.z;
        h0[s4 * 4 + 3] = h0[s4 * 4 + 3] * dA + c0 * bb.w; b0 += h0[s4 * 4 + 3] * cc.w;
        h1[s4 * 4 + 0] = h1[s4 * 4 + 0] * dA + c1 * bb.x; a1 += h1[s4 * 4 + 0] * cc.x;
        h1[s4 * 4 + 1] = h1[s4 * 4 + 1] * dA + c1 * bb.y; b1 += h1[s4 * 4 + 1] * cc.y;
        h1[s4 * 4 + 2] = h1[s4 * 4 + 2] * dA + c1 * bb.z; a1 += h1[s4 * 4 + 2] * cc.z;
        h1[s4 * 4 + 3] = h1[s4 * 4 + 3] * dA + c1 * bb.w; b1 += h1[s4 * 4 + 3] * cc.w;
      }
      float y0 = quad_sum(a0 + b0);
      float y1 = quad_sum(a1 + b1);
      if (squad == 0) {
        float2 o = make_float2(y0 + Dk * xv.x, y1 + Dk * xv.y);
        *(float2*)&yp[(size_t)(lt + ll) * 256 + head * 32 + dduo * 2] = o;
      }
    }
    __syncthreads();
  }
}

// ---------------- K7 v5: gate + RMS norm (z bf16) -> ynorm bf16 ------------------
__global__ __launch_bounds__(256) void k_gate_v5(const float* __restrict__ ys,
                                                 const unsigned short* __restrict__ zb,
                                                 const float* __restrict__ P,
                                                 unsigned short* __restrict__ ynb) {
  int l = blockIdx.x;
  int e = threadIdx.x;
  __shared__ float red[4];
  float yv = ys[(size_t)l * 256 + e];
  float zv = b2f(zb[(size_t)l * 256 + e]);
  float g = zv / (1.f + __expf(-zv));
  float y = yv * g;
  float ss = y * y;
  for (int o = 32; o; o >>= 1) ss += __shfl_down(ss, o, 64);
  if ((threadIdx.x & 63) == 0) red[threadIdx.x >> 6] = ss;
  __syncthreads();
  float tot = red[0] + red[1] + red[2] + red[3];
  float r = rsqrtf(tot * (1.f / 256.f) + 1e-5f);
  ynb[(size_t)l * 256 + e] = f2b(y * r * P[P_NG + e]);
}

// ---------------- G2 MFMA: out = ynorm @ outw^T (bf16 in, f32 NCHW out) ----------
__global__ __launch_bounds__(256) void k_gemm2_mf(const unsigned short* __restrict__ ynb,
                                                  const unsigned short* __restrict__ outwh,
                                                  float* __restrict__ dout,
                                                  int tok0) {
  __shared__ __align__(16) unsigned short Al[128 * 136];
  __shared__ __align__(16) unsigned short Bl[128 * 136];
  int t0 = blockIdx.x * 128;
  int lane = threadIdx.x & 63;
  int wv = threadIdx.x >> 6;
  int wm = wv >> 1, wn = wv & 1;
  int lr = lane & 15;
  int kb = lane >> 4;
  f32x4 acc[4][4] = {};
  for (int kt = 0; kt < 256; kt += 128) {
    for (int i = threadIdx.x; i < 2048; i += 256) {
      int row = i >> 4, ch = i & 15;
      *(float4*)&Al[row * 136 + ch * 8] =
          *(const float4*)&ynb[(size_t)(t0 + row) * 256 + kt + ch * 8];
      *(float4*)&Bl[row * 136 + ch * 8] =
          *(const float4*)&outwh[(size_t)row * 256 + kt + ch * 8];
    }
    __syncthreads();
#pragma unroll
    for (int kk = 0; kk < 4; ++kk) {
      bf16x8 af[4], bf[4];
#pragma unroll
      for (int f = 0; f < 4; ++f)
        af[f] = *(const bf16x8*)&Al[(wm * 64 + f * 16 + lr) * 136 + kk * 32 + kb * 8];
#pragma unroll
      for (int f = 0; f < 4; ++f)
        bf[f] = *(const bf16x8*)&Bl[(wn * 64 + f * 16 + lr) * 136 + kk * 32 + kb * 8];
#pragma unroll
      for (int fm = 0; fm < 4; ++fm)
#pragma unroll
        for (int fn = 0; fn < 4; ++fn)
          acc[fm][fn] = __builtin_amdgcn_mfma_f32_16x16x32_bf16(af[fm], bf[fn],
                                                                acc[fm][fn], 0, 0, 0);
    }
    __syncthreads();
  }
#pragma unroll
  for (int fm = 0; fm < 4; ++fm)
#pragma unroll
    for (int fn = 0; fn < 4; ++fn) {
      int cc = wn * 64 + fn * 16 + lr;
#pragma unroll
      for (int r = 0; r < 4; ++r) {
        int l = tok0 + t0 + wm * 64 + fm * 16 + kb * 4 + r;
        int b = l >> 14, rem = l & 16383;
        int hh = rem >> 7, ww = rem & 127;
        dout[(((size_t)(b * 128 + cc) * 128 + hh) * 128 + ww)] = acc[fm][fn][r];
      }
    }
}

extern "C" void kernel_launch(void* const* d_in, const int* in_sizes, int n_in,
                              void* d_out, int out_size, void* d_ws, size_t ws_size,
                              hipStream_t stream) {
  const void* x      = d_in[0];
  const void* dww    = d_in[1];
  const void* gng    = d_in[2];
  const void* gnb    = d_in[3];
  const void* pww    = d_in[4];
  const void* pwb    = d_in[5];
  const void* wproj  = d_in[6];
  const void* cw     = d_in[7];
  const void* cb     = d_in[8];
  const void* dtbias = d_in[9];
  const void* alog   = d_in[10];
  const void* dskip  = d_in[11];
  const void* ng     = d_in[12];
  const void* outw   = d_in[13];
  float* out = (float*)d_out;

  char* ws = (char*)d_ws;
  float* gst            = (float*)(ws + 0);
  float* mr             = (float*)(ws + 4096);
  float* P              = (float*)(ws + 8192);
  unsigned short* wpjh  = (unsigned short*)(ws + 40960);   // 648*128*2 = 165,888
  unsigned short* outwh = (unsigned short*)(ws + 372736);  // 128*256*2 = 65,536
  float* offf           = (float*)(ws + 503808);
  char* cbase           = ws + 1028096;

  // h1 (f32) lives in d_out's out_2d region.
  float* h1f = out;

  // Per-sequence chunk bytes:
  //   seqb 32768 + zb 65536 + xbc 196608 + dtb 4096 + ys 131072 + ynb 65536
  //   = 495,616  (fits CH=512 in a 256MB ws -> 2 blocks/CU for chunk kernels).
  const int opts[11] = {1024, 512, 256, 128, 64, 32, 16, 8, 4, 2, 1};
  int CH = 1;
  for (int i = 0; i < 11; ++i) {
    if (1028096ull + (unsigned long long)opts[i] * 495616ull <= (unsigned long long)ws_size) {
      CH = opts[i];
      break;
    }
  }
  int NC = 1024 / CH;

  unsigned short* seqb = (unsigned short*)(cbase);
  unsigned short* zb   = (unsigned short*)(cbase + (size_t)CH * 32768);
  float* xbcf          = (float*)(cbase + (size_t)CH * 98304);
  float* dtbf          = (float*)(cbase + (size_t)CH * 294912);
  float* ysf           = (float*)(cbase + (size_t)CH * 299008);
  unsigned short* ynbf = (unsigned short*)(cbase + (size_t)CH * 430080);

  k_prep_params<<<1, 256, 0, stream>>>(dww, cw, cb, gng, gnb, pww, pwb, dtbias,
                                       alog, dskip, ng, wproj, P, gst);
  k_prep_w<<<128, 256, 0, stream>>>(wproj, outw, gng, wpjh, outwh);
  k_dwconv_v2<<<1024, 256, 0, stream>>>(x, gng, P, h1f, gst);
  k_stats<<<1, 64, 0, stream>>>(gst, mr);
  k_gn_off<<<1024, 128, 0, stream>>>(h1f, mr, P, offf, out);

  for (int c = 0; c < NC; ++c) {
    int s0 = c * CH;
    k_deform_v4<<<CH, 256, 0, stream>>>(x, gng, offf, seqb, s0);
    k_gemm1_mf<<<dim3(CH, 5), 256, 0, stream>>>(seqb, wpjh, zb, xbcf);
    k_dt<<<CH * 4, 256, 0, stream>>>(seqb, P, dtbf);
    k_scan_v7<<<CH, 512, 0, stream>>>(xbcf, dtbf, P, ysf);
    k_gate_v5<<<CH * 128, 256, 0, stream>>>(ysf, zb, P, ynbf);
    k_gemm2_mf<<<CH, 256, 0, stream>>>(ynbf, outwh, out, s0 * 128);
  }
}

// Round 14
// 628.495 us; speedup vs baseline: 2.4448x; 1.0833x over previous
//
#include <hip/hip_runtime.h>
#include <math.h>

// B=8, C=128, H=128, W=128, D_INNER=256, D_STATE=64, HEADDIM=32, NHEADS=8,
// D_CONV=4, GN_GROUPS=8, D_XBC=384, D_INPROJ=648.
// Inputs f32 (probed via gn_g word0). OUTPUT IS F32 (reference output dtype).
// d_out = [out_2d: 16,777,216 f32][offset: 131,072 f32].
// h1 (f32) is staged in d_out's out_2d region.
//
// Round-13 -> 14 (scan is VALU-bound at 65%; fusion/traffic round):
//  (a) gate+RMS fused into gemm2: out[t,c] = r[t]*sum_k (y[t,k]*ng[k])*w[c,k];
//      ng folded into bf16 weights at prep, r[t] from a pre-pass, applied at
//      store. Gate kernel + ynb buffer eliminated.
//  (b) xbc, ys -> bf16 (linear paths; dt stays f32 via k_dt): halves scan
//      FETCH and gemm1/scan write traffic.
//  (c) scan conv done IN-PLACE in sRAW (conv'd row ll overwrites raw row ll+3
//      after rolling registers consume it; 19 rows re-staged per tile so no
//      cross-tile hazard): LDS 55 -> 30 KB -> 4 blocks/CU possible.
//  (d) per-seq ws 495,616 -> 266,240 B -> CH=1024 (4 blocks/CU) if ws >= 274MB;
//      falls back to CH=512 harmlessly.

typedef __bf16 bf16x8 __attribute__((ext_vector_type(8)));
typedef float f32x4 __attribute__((ext_vector_type(4)));

__device__ __forceinline__ float b2f(unsigned short u) {
  return __uint_as_float(((unsigned int)u) << 16);
}
__device__ __forceinline__ unsigned short f2b(float f) {
  unsigned int u = __float_as_uint(f);
  unsigned int r = (u + 0x7FFFu + ((u >> 16) & 1u)) >> 16;  // RNE
  return (unsigned short)r;
}
__device__ __forceinline__ bool in_is_f32(const void* gng) {
  return ((const unsigned int*)gng)[0] == 0x3F800000u;
}

// Sum over the 4-lane quad (lane&3 butterfly) on the VALU pipe.
__device__ __forceinline__ float quad_sum(float v) {
#if __has_builtin(__builtin_amdgcn_update_dpp)
  int p = __builtin_amdgcn_update_dpp(0, __float_as_int(v), 0xB1, 0xF, 0xF, true);
  v += __int_as_float(p);  // xor 1
  p = __builtin_amdgcn_update_dpp(0, __float_as_int(v), 0x4E, 0xF, 0xF, true);
  v += __int_as_float(p);  // xor 2
#else
  v += __shfl_xor(v, 1, 64);
  v += __shfl_xor(v, 2, 64);
#endif
  return v;
}

#define P_DWW 0
#define P_CW 3200
#define P_CB 4736
#define P_GNG 5120
#define P_GNB 5248
#define P_PWW 5376
#define P_PWB 5504
#define P_DTB 5505
#define P_ALOG 5513
#define P_DSKIP 5521
#define P_NG 5529
#define P_WDT 5792   // wproj rows 640..647 in f32 (8*128) for the dt path

__global__ void k_prep_params(const void* dww, const void* cw, const void* cb,
                              const void* gng, const void* gnb, const void* pww,
                              const void* pwb, const void* dtbias, const void* alog,
                              const void* dskip, const void* ng, const void* wproj,
                              float* __restrict__ P, float* __restrict__ gst) {
  bool f = in_is_f32(gng);
  int tid = threadIdx.x;
  if (tid < 128) gst[tid] = 0.f;
  auto cvt = [&](const void* src, int n, int off) {
    for (int i = tid; i < n; i += 256)
      P[off + i] = f ? ((const float*)src)[i] : b2f(((const unsigned short*)src)[i]);
  };
  cvt(dww, 3200, P_DWW);
  cvt(cw, 1536, P_CW);
  cvt(cb, 384, P_CB);
  cvt(gng, 128, P_GNG);
  cvt(gnb, 128, P_GNB);
  cvt(pww, 128, P_PWW);
  cvt(pwb, 1, P_PWB);
  cvt(dtbias, 8, P_DTB);
  cvt(alog, 8, P_ALOG);
  cvt(dskip, 8, P_DSKIP);
  cvt(ng, 256, P_NG);
  for (int i = tid; i < 1024; i += 256)
    P[P_WDT + i] = f ? ((const float*)wproj)[81920 + i]
                     : b2f(((const unsigned short*)wproj)[81920 + i]);
}

// Weights -> bf16. outw gets ng[k] folded in (gate+RMS fusion: ng is per-k).
__global__ void k_prep_w(const void* wproj, const void* outw, const void* gng,
                         const void* ng,
                         unsigned short* __restrict__ wprojh,
                         unsigned short* __restrict__ outwh) {
  bool f = in_is_f32(gng);
  int stride = gridDim.x * blockDim.x;
  for (int i = blockIdx.x * blockDim.x + threadIdx.x; i < 82944; i += stride)
    wprojh[i] = f ? f2b(((const float*)wproj)[i]) : ((const unsigned short*)wproj)[i];
  for (int i = blockIdx.x * blockDim.x + threadIdx.x; i < 32768; i += stride) {
    int k = i & 255;
    float wv = f ? ((const float*)outw)[i] : b2f(((const unsigned short*)outw)[i]);
    float nv = f ? ((const float*)ng)[k] : b2f(((const unsigned short*)ng)[k]);
    outwh[i] = f2b(wv * nv);
  }
}

// ---------------- K1 v2: depthwise 5x5 conv + group stats ------------------------
template <int H0>
__device__ __forceinline__ void dw_col(const float* __restrict__ t,
                                       const float* __restrict__ w, int col,
                                       float* __restrict__ h1, size_t outbase,
                                       float& s, float& sq) {
  float acc[5] = {0.f, 0.f, 0.f, 0.f, 0.f};
#pragma unroll
  for (int u = 0; u < 5; ++u) {
    int r = H0 + u;
    const float* row = t + r * 136 + col + 2;
    float v0 = row[0], v1 = row[1], v2 = row[2], v3 = row[3], v4 = row[4];
#pragma unroll
    for (int ky = 0; ky <= u; ++ky) {
      int sl = (H0 + u + 5 - ky) % 5;
      acc[sl] += w[ky * 5 + 0] * v0 + w[ky * 5 + 1] * v1 + w[ky * 5 + 2] * v2 +
                 w[ky * 5 + 3] * v3 + w[ky * 5 + 4] * v4;
    }
    if (u == 4) {
      int sl = H0 % 5;
      float ov = acc[sl];
      h1[outbase + (size_t)H0 * 128 + col] = ov;
      s += ov; sq += ov * ov;
      acc[sl] = 0.f;
    }
  }
  for (int o = 1; o < 13; ++o) {
#pragma unroll
    for (int u = 0; u < 5; ++u) {
      int r = H0 + o * 5 + u;
      const float* row = t + r * 136 + col + 2;
      float v0 = row[0], v1 = row[1], v2 = row[2], v3 = row[3], v4 = row[4];
#pragma unroll
      for (int ky = 0; ky < 5; ++ky) {
        int sl = (H0 + u + 5 - ky) % 5;
        acc[sl] += w[ky * 5 + 0] * v0 + w[ky * 5 + 1] * v1 + w[ky * 5 + 2] * v2 +
                   w[ky * 5 + 3] * v3 + w[ky * 5 + 4] * v4;
      }
      int dy = r - 4;
      int sl = (H0 + u + 1) % 5;
      float ov = acc[sl];
      h1[outbase + (size_t)dy * 128 + col] = ov;
      s += ov; sq += ov * ov;
      acc[sl] = 0.f;
    }
  }
#pragma unroll
  for (int u = 0; u < 3; ++u) {
    int r = H0 + 65 + u;
    const float* row = t + r * 136 + col + 2;
    float v0 = row[0], v1 = row[1], v2 = row[2], v3 = row[3], v4 = row[4];
#pragma unroll
    for (int ky = 0; ky < 5; ++ky) {
      int sl = (H0 + u + 5 - ky) % 5;
      acc[sl] += w[ky * 5 + 0] * v0 + w[ky * 5 + 1] * v1 + w[ky * 5 + 2] * v2 +
                 w[ky * 5 + 3] * v3 + w[ky * 5 + 4] * v4;
    }
    int dy = r - 4;
    int sl = (H0 + u + 1) % 5;
    float ov = acc[sl];
    h1[outbase + (size_t)dy * 128 + col] = ov;
    s += ov; sq += ov * ov;
    acc[sl] = 0.f;
  }
}

__global__ __launch_bounds__(256) void k_dwconv_v2(const void* __restrict__ x,
                                                   const void* __restrict__ gng,
                                                   const float* __restrict__ P,
                                                   float* __restrict__ h1,
                                                   float* __restrict__ gst) {
  int bc = blockIdx.x;
  int b = bc >> 7, chan = bc & 127;
  bool f32x = in_is_f32(gng);
  __shared__ __align__(16) float t[132 * 136];  // 71,808 B
  __shared__ float red[8];
  for (int i = threadIdx.x; i < (132 * 136) / 4; i += 256)
    ((float4*)t)[i] = make_float4(0.f, 0.f, 0.f, 0.f);
  __syncthreads();
  const float* xf = (const float*)x + (size_t)bc * 16384;
  const unsigned short* xb = (const unsigned short*)x + (size_t)bc * 16384;
  for (int i = threadIdx.x; i < 4096; i += 256) {
    int dy = i >> 5, dc = (i & 31) * 4;
    float4 v;
    if (f32x) {
      v = *(const float4*)&xf[i * 4];
    } else {
      ushort4 r4 = *(const ushort4*)&xb[i * 4];
      v = make_float4(b2f(r4.x), b2f(r4.y), b2f(r4.z), b2f(r4.w));
    }
    *(float4*)&t[(dy + 2) * 136 + dc + 4] = v;
  }
  float w[25];
#pragma unroll
  for (int k = 0; k < 25; ++k) w[k] = P[P_DWW + chan * 25 + k];
  __syncthreads();
  int col = threadIdx.x & 127;
  float s = 0.f, sq = 0.f;
  size_t outbase = (size_t)bc * 16384;
  if (threadIdx.x < 128) dw_col<0>(t, w, col, h1, outbase, s, sq);
  else                   dw_col<64>(t, w, col, h1, outbase, s, sq);
  for (int o = 32; o; o >>= 1) { s += __shfl_down(s, o, 64); sq += __shfl_down(sq, o, 64); }
  int wv = threadIdx.x >> 6;
  if ((threadIdx.x & 63) == 0) { red[wv] = s; red[4 + wv] = sq; }
  __syncthreads();
  if (threadIdx.x == 0) {
    float ts = red[0] + red[1] + red[2] + red[3];
    float tq = red[4] + red[5] + red[6] + red[7];
    int g = (b << 3) + (chan >> 4);
    atomicAdd(&gst[g * 2], ts);
    atomicAdd(&gst[g * 2 + 1], tq);
  }
}

__global__ void k_stats(const float* __restrict__ gst, float* __restrict__ mr) {
  int g = threadIdx.x;
  if (g < 64) {
    const float invN = 1.f / 262144.f;
    float mean = gst[g * 2] * invN;
    float var = gst[g * 2 + 1] * invN - mean * mean;
    mr[g * 2] = mean;
    mr[g * 2 + 1] = rsqrtf(var + 1e-5f);
  }
}

// ---------------- K3: GN + exact GELU + 1x1 conv + tanh*8 -> offset (f32 out) ----
__global__ __launch_bounds__(128) void k_gn_off(const float* __restrict__ h1,
                                                const float* __restrict__ mr,
                                                const float* __restrict__ P,
                                                float* __restrict__ offf,
                                                float* __restrict__ dout) {
  int bh = blockIdx.x;
  int b = bh >> 7, h = bh & 127;
  int w = threadIdx.x;
  float acc = 0.f;
  for (int c = 0; c < 128; ++c) {
    float v = h1[(((size_t)(b * 128 + c)) * 128 + h) * 128 + w];
    int g = b * 8 + (c >> 4);
    float nv = (v - mr[g * 2]) * mr[g * 2 + 1] * P[P_GNG + c] + P[P_GNB + c];
    float ge = 0.5f * nv * (1.f + erff(nv * 0.70710678118f));
    acc += ge * P[P_PWW + c];
  }
  float off = acc + P[P_PWB];
  float ofv = tanhf(off) * 8.0f;
  offf[bh * 128 + w] = ofv;
  dout[16777216 + bh * 128 + w] = ofv;
}

// ---------------- K4 v4: grid sample + transpose -> seq bf16 ---------------------
__global__ __launch_bounds__(256) void k_deform_v4(const void* __restrict__ x,
                                                   const void* __restrict__ gng,
                                                   const float* __restrict__ offf,
                                                   unsigned short* __restrict__ seqb,
                                                   int s0) {
  int bh = s0 + blockIdx.x;
  int b = bh >> 7, h = bh & 127;
  int w = threadIdx.x & 127;
  int half = threadIdx.x >> 7;  // 0..1
  bool f32x = in_is_f32(gng);
  __shared__ float t[128 * 129];
  float ofv = offf[bh * 128 + w];
  float gy = -1.f + (2.f / 127.f) * (float)h + ofv * (2.f / 127.f);
  gy = fminf(fmaxf(gy, -1.f), 1.f);
  float py = (gy + 1.f) * 0.5f * 127.f;
  py = fminf(fmaxf(py, 0.f), 127.f);
  float y0f = floorf(py);
  float wy = py - y0f;
  int y0 = (int)y0f;
  int y1 = min(y0 + 1, 127);
  const float* xfb = (const float*)x + (size_t)b * 128 * 16384;
  const unsigned short* xbb = (const unsigned short*)x + (size_t)b * 128 * 16384;
  for (int c = half * 64; c < half * 64 + 64; ++c) {
    size_t o0 = (size_t)c * 16384 + y0 * 128 + w;
    size_t o1 = (size_t)c * 16384 + y1 * 128 + w;
    float v0, v1;
    if (f32x) { v0 = xfb[o0]; v1 = xfb[o1]; }
    else      { v0 = b2f(xbb[o0]); v1 = b2f(xbb[o1]); }
    t[c * 129 + w] = v0 + wy * (v1 - v0);
  }
  __syncthreads();
  int c = threadIdx.x & 127;
  unsigned short* spb = seqb + (size_t)blockIdx.x * 16384;
  for (int l = half * 64; l < half * 64 + 64; ++l)
    spb[l * 128 + c] = f2b(t[c * 129 + l]);
}

// ---------------- G1 MFMA: z(bf16)/xBC(bf16) = seq @ wproj^T ---------------------
__global__ __launch_bounds__(256) void k_gemm1_mf(const unsigned short* __restrict__ seqb,
                                                  const unsigned short* __restrict__ wprojh,
                                                  unsigned short* __restrict__ zb,
                                                  unsigned short* __restrict__ xbcb) {
  __shared__ __align__(16) unsigned short Al[128 * 136];
  __shared__ __align__(16) unsigned short Bl[128 * 136];
  int m0 = blockIdx.x * 128;
  int e0 = blockIdx.y * 128;   // 0..512; covers e<640 exactly
  for (int i = threadIdx.x; i < 2048; i += 256) {
    int row = i >> 4, ch = i & 15;
    *(float4*)&Al[row * 136 + ch * 8] =
        *(const float4*)&seqb[(size_t)(m0 + row) * 128 + ch * 8];
    *(float4*)&Bl[row * 136 + ch * 8] =
        *(const float4*)&wprojh[(size_t)(e0 + row) * 128 + ch * 8];
  }
  __syncthreads();
  int lane = threadIdx.x & 63;
  int wv = threadIdx.x >> 6;
  int wm = wv >> 1, wn = wv & 1;
  int lr = lane & 15;
  int kb = lane >> 4;
  f32x4 acc[4][4] = {};
#pragma unroll
  for (int kk = 0; kk < 4; ++kk) {
    bf16x8 af[4], bf[4];
#pragma unroll
    for (int f = 0; f < 4; ++f)
      af[f] = *(const bf16x8*)&Al[(wm * 64 + f * 16 + lr) * 136 + kk * 32 + kb * 8];
#pragma unroll
    for (int f = 0; f < 4; ++f)
      bf[f] = *(const bf16x8*)&Bl[(wn * 64 + f * 16 + lr) * 136 + kk * 32 + kb * 8];
#pragma unroll
    for (int fm = 0; fm < 4; ++fm)
#pragma unroll
      for (int fn = 0; fn < 4; ++fn)
        acc[fm][fn] = __builtin_amdgcn_mfma_f32_16x16x32_bf16(af[fm], bf[fn],
                                                              acc[fm][fn], 0, 0, 0);
  }
#pragma unroll
  for (int fm = 0; fm < 4; ++fm)
#pragma unroll
    for (int fn = 0; fn < 4; ++fn) {
      int e = e0 + wn * 64 + fn * 16 + lr;
#pragma unroll
      for (int r = 0; r < 4; ++r) {
        int m = m0 + wm * 64 + fm * 16 + kb * 4 + r;
        float v = acc[fm][fn][r];
        if (e < 256) zb[(size_t)m * 256 + e] = f2b(v);
        else         xbcb[(size_t)m * 384 + (e - 256)] = f2b(v);
      }
    }
}

// ---------------- K_dt: dt columns (bf16 activations x f32 weights) --------------
__global__ __launch_bounds__(256) void k_dt(const unsigned short* __restrict__ seqb,
                                            const float* __restrict__ P,
                                            float* __restrict__ dtb) {
  int bb = blockIdx.x;            // CH*4 blocks; 32 tokens each
  int sq = bb >> 2, q = bb & 3;
  __shared__ float ss[32 * 133];
  __shared__ float wt[1024];
  const unsigned short* sp = seqb + (size_t)sq * 16384 + q * 32 * 128;
  for (int i = threadIdx.x; i < 1024; i += 256) {
    int idx = i * 4;
    int t = idx >> 7, k = idx & 127;
    ushort4 r4 = *(const ushort4*)&sp[idx];
    ss[t * 133 + k + 0] = b2f(r4.x);
    ss[t * 133 + k + 1] = b2f(r4.y);
    ss[t * 133 + k + 2] = b2f(r4.z);
    ss[t * 133 + k + 3] = b2f(r4.w);
  }
  for (int i = threadIdx.x; i < 1024; i += 256) wt[i] = P[P_WDT + i];
  __syncthreads();
  int head = threadIdx.x >> 5, t = threadIdx.x & 31;
  const float* wh = &wt[head * 128];
  const float* sr = &ss[t * 133];
  float acc = 0.f;
#pragma unroll 8
  for (int k = 0; k < 128; ++k) acc += sr[k] * wh[k];
  float dv = acc + P[P_DTB + head];
  float spv = (dv > 20.f) ? dv : log1pf(__expf(dv));
  dtb[((size_t)sq * 128 + q * 32 + t) * 8 + head] = spv;
}

// ---------------- K6 v8: fused conv1d+SiLU+scan, in-place conv, bf16 I/O ---------
// LDS: single sRAW 19x388 f32 (~30KB) -> 4 blocks/CU possible at CH=1024.
// Conv is in-place: conv'd row ll overwrites raw row ll+3 after the rolling
// registers (x0..x2) consume it; column-exclusive serial walk (384 workers).
// Main loop reads conv'd rows at sRAW[ll+3]. xbc read bf16, ys written bf16.
__global__ __launch_bounds__(512) void k_scan_v8(const unsigned short* __restrict__ xbcb,
                                                 const float* __restrict__ dtb,
                                                 const float* __restrict__ P,
                                                 unsigned short* __restrict__ ys) {
  int seq = blockIdx.x;
  int head = threadIdx.x >> 6;          // one wave per head
  int dduo = (threadIdx.x >> 2) & 15;   // d = dduo*2 + {0,1}
  int squad = threadIdx.x & 3;          // s-range squad*16 .. +15
  float A = -__expf(P[P_ALOG + head]);
  float Dk = P[P_DSKIP + head];
  float h0[16], h1[16];
#pragma unroll
  for (int s = 0; s < 16; ++s) { h0[s] = 0.f; h1[s] = 0.f; }
  __shared__ __align__(16) float sRAW[19][388];  // raw rows lt-3..lt+15; conv'd in place
  __shared__ float sDT[16][8];
  const unsigned short* base = xbcb + (size_t)seq * 49152;
  const float* dtp = dtb + (size_t)seq * 1024;
  unsigned int* yp = (unsigned int*)(ys + (size_t)seq * 32768);
  const int sbase = 256 + squad * 16;
  const int cbase = sbase + 64;
  for (int lt = 0; lt < 128; lt += 16) {
    // Stage raw rows l = lt-3 .. lt+15 (19 rows x 384 bf16 -> f32 LDS).
    for (int i = threadIdx.x; i < 912; i += 512) {
      int r = i / 48, c8 = (i % 48) * 8;
      int l = lt - 3 + r;
      float4 lo = make_float4(0.f, 0.f, 0.f, 0.f), hi = lo;
      if (l >= 0) {
        ushort4 a = *(const ushort4*)&base[(size_t)l * 384 + c8];
        ushort4 b = *(const ushort4*)&base[(size_t)l * 384 + c8 + 4];
        lo = make_float4(b2f(a.x), b2f(a.y), b2f(a.z), b2f(a.w));
        hi = make_float4(b2f(b.x), b2f(b.y), b2f(b.z), b2f(b.w));
      }
      *(float4*)&sRAW[r][c8] = lo;
      *(float4*)&sRAW[r][c8 + 4] = hi;
    }
    if (threadIdx.x < 128)
      sDT[threadIdx.x >> 3][threadIdx.x & 7] =
          dtp[(lt + (threadIdx.x >> 3)) * 8 + (threadIdx.x & 7)];
    __syncthreads();
    // In-place conv: thread e (e<384) owns column e, serial over 16 rows.
    if (threadIdx.x < 384) {
      int e = threadIdx.x;
      float w0 = P[P_CW + e * 4 + 0], w1 = P[P_CW + e * 4 + 1];
      float w2 = P[P_CW + e * 4 + 2], w3 = P[P_CW + e * 4 + 3];
      float bb = P[P_CB + e];
      float x0 = sRAW[0][e], x1 = sRAW[1][e], x2 = sRAW[2][e];
#pragma unroll
      for (int ll = 0; ll < 16; ++ll) {
        float x3 = sRAW[ll + 3][e];
        float a = bb + w0 * x0 + w1 * x1 + w2 * x2 + w3 * x3;
        sRAW[ll + 3][e] = a / (1.f + __expf(-a));  // conv'd row ll
        x0 = x1; x1 = x2; x2 = x3;
      }
    }
    __syncthreads();
#pragma unroll 1
    for (int ll = 0; ll < 16; ++ll) {
      const float* row = sRAW[ll + 3];
      float dt = sDT[ll][head];
      float dA = __expf(dt * A);
      float2 xv = *(const float2*)&row[head * 32 + dduo * 2];
      float c0 = dt * xv.x, c1 = dt * xv.y;
      float a0 = 0.f, b0 = 0.f, a1 = 0.f, b1 = 0.f;
#pragma unroll
      for (int s4 = 0; s4 < 4; ++s4) {
        float4 bb = *(const float4*)&row[sbase + s4 * 4];
        float4 cc = *(const float4*)&row[cbase + s4 * 4];
        h0[s4 * 4 + 0] = h0[s4 * 4 + 0] * dA + c0 * bb.x; a0 += h0[s4 * 4 + 0] * cc.x;
        h0[s4 * 4 + 1] = h0[s4 * 4 + 1] * dA + c0 * bb.y; b0 += h0[s4 * 4 + 1] * cc.y;
        h0[s4 * 4 + 2] = h0[s4 * 4 + 2] * dA + c0 * bb.z; a0 += h0[s4 * 4 + 2] * cc.z;
        h0[s4 * 4 + 3] = h0[s4 * 4 + 3] * dA + c0 * bb.w; b0 += h0[s4 * 4 + 3] * cc.w;
        h1[s4 * 4 + 0] = h1[s4 * 4 + 0] * dA + c1 * bb.x; a1 += h1[s4 * 4 + 0] * cc.x;
        h1[s4 * 4 + 1] = h1[s4 * 4 + 1] * dA + c1 * bb.y; b1 += h1[s4 * 4 + 1] * cc.y;
        h1[s4 * 4 + 2] = h1[s4 * 4 + 2] * dA + c1 * bb.z; a1 += h1[s4 * 4 + 2] * cc.z;
        h1[s4 * 4 + 3] = h1[s4 * 4 + 3] * dA + c1 * bb.w; b1 += h1[s4 * 4 + 3] * cc.w;
      }
      float y0 = quad_sum(a0 + b0);
      float y1 = quad_sum(a1 + b1);
      if (squad == 0) {
        unsigned int pk = (unsigned int)f2b(y0 + Dk * xv.x) |
                          ((unsigned int)f2b(y1 + Dk * xv.y) << 16);
        yp[((lt + ll) * 256 + head * 32 + dduo * 2) >> 1] = pk;
      }
    }
    __syncthreads();
  }
}

// ---------------- G2 v2: FUSED gate+RMS + out GEMM -------------------------------
// out[t,c] = r[t] * sum_k (y[t,k]*ng[k]) * w[c,k], y = ys*silu(z).
// ng pre-folded into outwh; r[t]=rsqrt(mean(y^2)+eps) from a pre-pass; applied
// at store. A-staging computes gated y -> bf16 on the fly.
__global__ __launch_bounds__(256) void k_gemm2_f(const unsigned short* __restrict__ ysb,
                                                 const unsigned short* __restrict__ zb,
                                                 const unsigned short* __restrict__ outwh,
                                                 float* __restrict__ dout,
                                                 int tok0) {
  __shared__ __align__(16) unsigned short Al[128 * 136];
  __shared__ __align__(16) unsigned short Bl[128 * 136];
  __shared__ float rr[128];
  int t0 = blockIdx.x * 128;
  // Pre-pass: r[t]. Thread -> (row = tid>>1, half = tid&1), 128 elems each.
  {
    int row = threadIdx.x >> 1, half = threadIdx.x & 1;
    const unsigned short* yrow = &ysb[(size_t)(t0 + row) * 256 + half * 128];
    const unsigned short* zrow = &zb[(size_t)(t0 + row) * 256 + half * 128];
    float ssum = 0.f;
#pragma unroll 4
    for (int it = 0; it < 16; ++it) {
      ushort4 ya = *(const ushort4*)&yrow[it * 8];
      ushort4 yb4 = *(const ushort4*)&yrow[it * 8 + 4];
      ushort4 za = *(const ushort4*)&zrow[it * 8];
      ushort4 zb4 = *(const ushort4*)&zrow[it * 8 + 4];
      float yv[8] = {b2f(ya.x), b2f(ya.y), b2f(ya.z), b2f(ya.w),
                     b2f(yb4.x), b2f(yb4.y), b2f(yb4.z), b2f(yb4.w)};
      float zv[8] = {b2f(za.x), b2f(za.y), b2f(za.z), b2f(za.w),
                     b2f(zb4.x), b2f(zb4.y), b2f(zb4.z), b2f(zb4.w)};
#pragma unroll
      for (int j = 0; j < 8; ++j) {
        float y = yv[j] * (zv[j] / (1.f + __expf(-zv[j])));
        ssum += y * y;
      }
    }
    ssum += __shfl_xor(ssum, 1, 64);
    if (half == 0) rr[row] = rsqrtf(ssum * (1.f / 256.f) + 1e-5f);
  }
  __syncthreads();
  int lane = threadIdx.x & 63;
  int wv = threadIdx.x >> 6;
  int wm = wv >> 1, wn = wv & 1;
  int lr = lane & 15;
  int kb = lane >> 4;
  f32x4 acc[4][4] = {};
  for (int kt = 0; kt < 256; kt += 128) {
    for (int i = threadIdx.x; i < 2048; i += 256) {
      int row = i >> 4, ch = i & 15;
      const unsigned short* yrow = &ysb[(size_t)(t0 + row) * 256 + kt + ch * 8];
      const unsigned short* zrow = &zb[(size_t)(t0 + row) * 256 + kt + ch * 8];
      ushort4 ya = *(const ushort4*)yrow;
      ushort4 yb4 = *(const ushort4*)(yrow + 4);
      ushort4 za = *(const ushort4*)zrow;
      ushort4 zb4 = *(const ushort4*)(zrow + 4);
      float yv[8] = {b2f(ya.x), b2f(ya.y), b2f(ya.z), b2f(ya.w),
                     b2f(yb4.x), b2f(yb4.y), b2f(yb4.z), b2f(yb4.w)};
      float zv[8] = {b2f(za.x), b2f(za.y), b2f(za.z), b2f(za.w),
                     b2f(zb4.x), b2f(zb4.y), b2f(zb4.z), b2f(zb4.w)};
      unsigned short o[8];
#pragma unroll
      for (int j = 0; j < 8; ++j)
        o[j] = f2b(yv[j] * (zv[j] / (1.f + __expf(-zv[j]))));
      *(ushort4*)&Al[row * 136 + ch * 8] = make_ushort4(o[0], o[1], o[2], o[3]);
      *(ushort4*)&Al[row * 136 + ch * 8 + 4] = make_ushort4(o[4], o[5], o[6], o[7]);
      *(float4*)&Bl[row * 136 + ch * 8] =
          *(const float4*)&outwh[(size_t)row * 256 + kt + ch * 8];
    }
    __syncthreads();
#pragma unroll
    for (int kk = 0; kk < 4; ++kk) {
      bf16x8 af[4], bf[4];
#pragma unroll
      for (int f = 0; f < 4; ++f)
        af[f] = *(const bf16x8*)&Al[(wm * 64 + f * 16 + lr) * 136 + kk * 32 + kb * 8];
#pragma unroll
      for (int f = 0; f < 4; ++f)
        bf[f] = *(const bf16x8*)&Bl[(wn * 64 + f * 16 + lr) * 136 + kk * 32 + kb * 8];
#pragma unroll
      for (int fm = 0; fm < 4; ++fm)
#pragma unroll
        for (int fn = 0; fn < 4; ++fn)
          acc[fm][fn] = __builtin_amdgcn_mfma_f32_16x16x32_bf16(af[fm], bf[fn],
                                                                acc[fm][fn], 0, 0, 0);
    }
    __syncthreads();
  }
#pragma unroll
  for (int fm = 0; fm < 4; ++fm)
#pragma unroll
    for (int fn = 0; fn < 4; ++fn) {
      int cc = wn * 64 + fn * 16 + lr;
#pragma unroll
      for (int r = 0; r < 4; ++r) {
        int rowl = wm * 64 + fm * 16 + kb * 4 + r;
        int l = tok0 + t0 + rowl;
        int b = l >> 14, rem = l & 16383;
        int hh = rem >> 7, ww = rem & 127;
        dout[(((size_t)(b * 128 + cc) * 128 + hh) * 128 + ww)] =
            acc[fm][fn][r] * rr[rowl];
      }
    }
}

extern "C" void kernel_launch(void* const* d_in, const int* in_sizes, int n_in,
                              void* d_out, int out_size, void* d_ws, size_t ws_size,
                              hipStream_t stream) {
  const void* x      = d_in[0];
  const void* dww    = d_in[1];
  const void* gng    = d_in[2];
  const void* gnb    = d_in[3];
  const void* pww    = d_in[4];
  const void* pwb    = d_in[5];
  const void* wproj  = d_in[6];
  const void* cw     = d_in[7];
  const void* cb     = d_in[8];
  const void* dtbias = d_in[9];
  const void* alog   = d_in[10];
  const void* dskip  = d_in[11];
  const void* ng     = d_in[12];
  const void* outw   = d_in[13];
  float* out = (float*)d_out;

  char* ws = (char*)d_ws;
  float* gst            = (float*)(ws + 0);
  float* mr             = (float*)(ws + 4096);
  float* P              = (float*)(ws + 8192);
  unsigned short* wpjh  = (unsigned short*)(ws + 40960);   // 648*128*2 = 165,888
  unsigned short* outwh = (unsigned short*)(ws + 372736);  // 128*256*2 = 65,536
  float* offf           = (float*)(ws + 503808);
  char* cbase           = ws + 1028096;

  // h1 (f32) lives in d_out's out_2d region.
  float* h1f = out;

  // Per-sequence chunk bytes:
  //   seqb 32768 + zb 65536 + xbcb 98304 + dtb 4096 + ysb 65536 = 266,240.
  //   CH=1024 needs ~274MB; falls back to 512 otherwise.
  const int opts[11] = {1024, 512, 256, 128, 64, 32, 16, 8, 4, 2, 1};
  int CH = 1;
  for (int i = 0; i < 11; ++i) {
    if (1028096ull + (unsigned long long)opts[i] * 266240ull <= (unsigned long long)ws_size) {
      CH = opts[i];
      break;
    }
  }
  int NC = 1024 / CH;

  unsigned short* seqb = (unsigned short*)(cbase);
  unsigned short* zb   = (unsigned short*)(cbase + (size_t)CH * 32768);
  unsigned short* xbcb = (unsigned short*)(cbase + (size_t)CH * 98304);
  float* dtbf          = (float*)(cbase + (size_t)CH * 196608);
  unsigned short* ysb  = (unsigned short*)(cbase + (size_t)CH * 200704);

  k_prep_params<<<1, 256, 0, stream>>>(dww, cw, cb, gng, gnb, pww, pwb, dtbias,
                                       alog, dskip, ng, wproj, P, gst);
  k_prep_w<<<128, 256, 0, stream>>>(wproj, outw, gng, ng, wpjh, outwh);
  k_dwconv_v2<<<1024, 256, 0, stream>>>(x, gng, P, h1f, gst);
  k_stats<<<1, 64, 0, stream>>>(gst, mr);
  k_gn_off<<<1024, 128, 0, stream>>>(h1f, mr, P, offf, out);

  for (int c = 0; c < NC; ++c) {
    int s0 = c * CH;
    k_deform_v4<<<CH, 256, 0, stream>>>(x, gng, offf, seqb, s0);
    k_gemm1_mf<<<dim3(CH, 5), 256, 0, stream>>>(seqb, wpjh, zb, xbcb);
    k_dt<<<CH * 4, 256, 0, stream>>>(seqb, P, dtbf);
    k_scan_v8<<<CH, 512, 0, stream>>>(xbcb, dtbf, P, ysb);
    k_gemm2_f<<<CH, 256, 0, stream>>>(ysb, zb, outwh, out, s0 * 128);
  }
}

// Round 15
// 609.190 us; speedup vs baseline: 2.5223x; 1.0317x over previous
//
#include <hip/hip_runtime.h>
#include <math.h>

// B=8, C=128, H=128, W=128, D_INNER=256, D_STATE=64, HEADDIM=32, NHEADS=8,
// D_CONV=4, GN_GROUPS=8, D_XBC=384, D_INPROJ=648.
// Inputs f32 (probed via gn_g word0). OUTPUT IS F32 (reference output dtype).
// d_out = [out_2d: 16,777,216 f32][offset: 131,072 f32].
// h1 (f32) is staged in d_out's out_2d region.
//
// Round-14 -> 15: ws ~256MB bounded CH at 512 (occupancy 36%, scan 2x132us,
// VALU 67%). Overlay: seqb is dead after k_dt (stream order), so ys tokens
// 0..63 (ys_lo) reuse seqb's storage; only ys_hi (tokens 64..127) is fresh.
// Per-seq 266,240 -> 233,472 B -> CH=1024 fits in 240MB -> NC=1, 4 blocks/CU
// for scan/deform/k_dt/gemm2. Scan & gemm2 take split lo/hi ys pointers
// (wave-uniform branch: l<64 constant per 16-row tile).

typedef __bf16 bf16x8 __attribute__((ext_vector_type(8)));
typedef float f32x4 __attribute__((ext_vector_type(4)));

__device__ __forceinline__ float b2f(unsigned short u) {
  return __uint_as_float(((unsigned int)u) << 16);
}
__device__ __forceinline__ unsigned short f2b(float f) {
  unsigned int u = __float_as_uint(f);
  unsigned int r = (u + 0x7FFFu + ((u >> 16) & 1u)) >> 16;  // RNE
  return (unsigned short)r;
}
__device__ __forceinline__ bool in_is_f32(const void* gng) {
  return ((const unsigned int*)gng)[0] == 0x3F800000u;
}

// Sum over the 4-lane quad (lane&3 butterfly) on the VALU pipe.
__device__ __forceinline__ float quad_sum(float v) {
#if __has_builtin(__builtin_amdgcn_update_dpp)
  int p = __builtin_amdgcn_update_dpp(0, __float_as_int(v), 0xB1, 0xF, 0xF, true);
  v += __int_as_float(p);  // xor 1
  p = __builtin_amdgcn_update_dpp(0, __float_as_int(v), 0x4E, 0xF, 0xF, true);
  v += __int_as_float(p);  // xor 2
#else
  v += __shfl_xor(v, 1, 64);
  v += __shfl_xor(v, 2, 64);
#endif
  return v;
}

#define P_DWW 0
#define P_CW 3200
#define P_CB 4736
#define P_GNG 5120
#define P_GNB 5248
#define P_PWW 5376
#define P_PWB 5504
#define P_DTB 5505
#define P_ALOG 5513
#define P_DSKIP 5521
#define P_NG 5529
#define P_WDT 5792   // wproj rows 640..647 in f32 (8*128) for the dt path

__global__ void k_prep_params(const void* dww, const void* cw, const void* cb,
                              const void* gng, const void* gnb, const void* pww,
                              const void* pwb, const void* dtbias, const void* alog,
                              const void* dskip, const void* ng, const void* wproj,
                              float* __restrict__ P, float* __restrict__ gst) {
  bool f = in_is_f32(gng);
  int tid = threadIdx.x;
  if (tid < 128) gst[tid] = 0.f;
  auto cvt = [&](const void* src, int n, int off) {
    for (int i = tid; i < n; i += 256)
      P[off + i] = f ? ((const float*)src)[i] : b2f(((const unsigned short*)src)[i]);
  };
  cvt(dww, 3200, P_DWW);
  cvt(cw, 1536, P_CW);
  cvt(cb, 384, P_CB);
  cvt(gng, 128, P_GNG);
  cvt(gnb, 128, P_GNB);
  cvt(pww, 128, P_PWW);
  cvt(pwb, 1, P_PWB);
  cvt(dtbias, 8, P_DTB);
  cvt(alog, 8, P_ALOG);
  cvt(dskip, 8, P_DSKIP);
  cvt(ng, 256, P_NG);
  for (int i = tid; i < 1024; i += 256)
    P[P_WDT + i] = f ? ((const float*)wproj)[81920 + i]
                     : b2f(((const unsigned short*)wproj)[81920 + i]);
}

// Weights -> bf16. outw gets ng[k] folded in (gate+RMS fusion: ng is per-k).
__global__ void k_prep_w(const void* wproj, const void* outw, const void* gng,
                         const void* ng,
                         unsigned short* __restrict__ wprojh,
                         unsigned short* __restrict__ outwh) {
  bool f = in_is_f32(gng);
  int stride = gridDim.x * blockDim.x;
  for (int i = blockIdx.x * blockDim.x + threadIdx.x; i < 82944; i += stride)
    wprojh[i] = f ? f2b(((const float*)wproj)[i]) : ((const unsigned short*)wproj)[i];
  for (int i = blockIdx.x * blockDim.x + threadIdx.x; i < 32768; i += stride) {
    int k = i & 255;
    float wv = f ? ((const float*)outw)[i] : b2f(((const unsigned short*)outw)[i]);
    float nv = f ? ((const float*)ng)[k] : b2f(((const unsigned short*)ng)[k]);
    outwh[i] = f2b(wv * nv);
  }
}

// ---------------- K1 v2: depthwise 5x5 conv + group stats ------------------------
template <int H0>
__device__ __forceinline__ void dw_col(const float* __restrict__ t,
                                       const float* __restrict__ w, int col,
                                       float* __restrict__ h1, size_t outbase,
                                       float& s, float& sq) {
  float acc[5] = {0.f, 0.f, 0.f, 0.f, 0.f};
#pragma unroll
  for (int u = 0; u < 5; ++u) {
    int r = H0 + u;
    const float* row = t + r * 136 + col + 2;
    float v0 = row[0], v1 = row[1], v2 = row[2], v3 = row[3], v4 = row[4];
#pragma unroll
    for (int ky = 0; ky <= u; ++ky) {
      int sl = (H0 + u + 5 - ky) % 5;
      acc[sl] += w[ky * 5 + 0] * v0 + w[ky * 5 + 1] * v1 + w[ky * 5 + 2] * v2 +
                 w[ky * 5 + 3] * v3 + w[ky * 5 + 4] * v4;
    }
    if (u == 4) {
      int sl = H0 % 5;
      float ov = acc[sl];
      h1[outbase + (size_t)H0 * 128 + col] = ov;
      s += ov; sq += ov * ov;
      acc[sl] = 0.f;
    }
  }
  for (int o = 1; o < 13; ++o) {
#pragma unroll
    for (int u = 0; u < 5; ++u) {
      int r = H0 + o * 5 + u;
      const float* row = t + r * 136 + col + 2;
      float v0 = row[0], v1 = row[1], v2 = row[2], v3 = row[3], v4 = row[4];
#pragma unroll
      for (int ky = 0; ky < 5; ++ky) {
        int sl = (H0 + u + 5 - ky) % 5;
        acc[sl] += w[ky * 5 + 0] * v0 + w[ky * 5 + 1] * v1 + w[ky * 5 + 2] * v2 +
                   w[ky * 5 + 3] * v3 + w[ky * 5 + 4] * v4;
      }
      int dy = r - 4;
      int sl = (H0 + u + 1) % 5;
      float ov = acc[sl];
      h1[outbase + (size_t)dy * 128 + col] = ov;
      s += ov; sq += ov * ov;
      acc[sl] = 0.f;
    }
  }
#pragma unroll
  for (int u = 0; u < 3; ++u) {
    int r = H0 + 65 + u;
    const float* row = t + r * 136 + col + 2;
    float v0 = row[0], v1 = row[1], v2 = row[2], v3 = row[3], v4 = row[4];
#pragma unroll
    for (int ky = 0; ky < 5; ++ky) {
      int sl = (H0 + u + 5 - ky) % 5;
      acc[sl] += w[ky * 5 + 0] * v0 + w[ky * 5 + 1] * v1 + w[ky * 5 + 2] * v2 +
                 w[ky * 5 + 3] * v3 + w[ky * 5 + 4] * v4;
    }
    int dy = r - 4;
    int sl = (H0 + u + 1) % 5;
    float ov = acc[sl];
    h1[outbase + (size_t)dy * 128 + col] = ov;
    s += ov; sq += ov * ov;
    acc[sl] = 0.f;
  }
}

__global__ __launch_bounds__(256) void k_dwconv_v2(const void* __restrict__ x,
                                                   const void* __restrict__ gng,
                                                   const float* __restrict__ P,
                                                   float* __restrict__ h1,
                                                   float* __restrict__ gst) {
  int bc = blockIdx.x;
  int b = bc >> 7, chan = bc & 127;
  bool f32x = in_is_f32(gng);
  __shared__ __align__(16) float t[132 * 136];  // 71,808 B
  __shared__ float red[8];
  for (int i = threadIdx.x; i < (132 * 136) / 4; i += 256)
    ((float4*)t)[i] = make_float4(0.f, 0.f, 0.f, 0.f);
  __syncthreads();
  const float* xf = (const float*)x + (size_t)bc * 16384;
  const unsigned short* xb = (const unsigned short*)x + (size_t)bc * 16384;
  for (int i = threadIdx.x; i < 4096; i += 256) {
    int dy = i >> 5, dc = (i & 31) * 4;
    float4 v;
    if (f32x) {
      v = *(const float4*)&xf[i * 4];
    } else {
      ushort4 r4 = *(const ushort4*)&xb[i * 4];
      v = make_float4(b2f(r4.x), b2f(r4.y), b2f(r4.z), b2f(r4.w));
    }
    *(float4*)&t[(dy + 2) * 136 + dc + 4] = v;
  }
  float w[25];
#pragma unroll
  for (int k = 0; k < 25; ++k) w[k] = P[P_DWW + chan * 25 + k];
  __syncthreads();
  int col = threadIdx.x & 127;
  float s = 0.f, sq = 0.f;
  size_t outbase = (size_t)bc * 16384;
  if (threadIdx.x < 128) dw_col<0>(t, w, col, h1, outbase, s, sq);
  else                   dw_col<64>(t, w, col, h1, outbase, s, sq);
  for (int o = 32; o; o >>= 1) { s += __shfl_down(s, o, 64); sq += __shfl_down(sq, o, 64); }
  int wv = threadIdx.x >> 6;
  if ((threadIdx.x & 63) == 0) { red[wv] = s; red[4 + wv] = sq; }
  __syncthreads();
  if (threadIdx.x == 0) {
    float ts = red[0] + red[1] + red[2] + red[3];
    float tq = red[4] + red[5] + red[6] + red[7];
    int g = (b << 3) + (chan >> 4);
    atomicAdd(&gst[g * 2], ts);
    atomicAdd(&gst[g * 2 + 1], tq);
  }
}

__global__ void k_stats(const float* __restrict__ gst, float* __restrict__ mr) {
  int g = threadIdx.x;
  if (g < 64) {
    const float invN = 1.f / 262144.f;
    float mean = gst[g * 2] * invN;
    float var = gst[g * 2 + 1] * invN - mean * mean;
    mr[g * 2] = mean;
    mr[g * 2 + 1] = rsqrtf(var + 1e-5f);
  }
}

// ---------------- K3: GN + exact GELU + 1x1 conv + tanh*8 -> offset (f32 out) ----
__global__ __launch_bounds__(128) void k_gn_off(const float* __restrict__ h1,
                                                const float* __restrict__ mr,
                                                const float* __restrict__ P,
                                                float* __restrict__ offf,
                                                float* __restrict__ dout) {
  int bh = blockIdx.x;
  int b = bh >> 7, h = bh & 127;
  int w = threadIdx.x;
  float acc = 0.f;
  for (int c = 0; c < 128; ++c) {
    float v = h1[(((size_t)(b * 128 + c)) * 128 + h) * 128 + w];
    int g = b * 8 + (c >> 4);
    float nv = (v - mr[g * 2]) * mr[g * 2 + 1] * P[P_GNG + c] + P[P_GNB + c];
    float ge = 0.5f * nv * (1.f + erff(nv * 0.70710678118f));
    acc += ge * P[P_PWW + c];
  }
  float off = acc + P[P_PWB];
  float ofv = tanhf(off) * 8.0f;
  offf[bh * 128 + w] = ofv;
  dout[16777216 + bh * 128 + w] = ofv;
}

// ---------------- K4 v4: grid sample + transpose -> seq bf16 ---------------------
__global__ __launch_bounds__(256) void k_deform_v4(const void* __restrict__ x,
                                                   const void* __restrict__ gng,
                                                   const float* __restrict__ offf,
                                                   unsigned short* __restrict__ seqb,
                                                   int s0) {
  int bh = s0 + blockIdx.x;
  int b = bh >> 7, h = bh & 127;
  int w = threadIdx.x & 127;
  int half = threadIdx.x >> 7;  // 0..1
  bool f32x = in_is_f32(gng);
  __shared__ float t[128 * 129];
  float ofv = offf[bh * 128 + w];
  float gy = -1.f + (2.f / 127.f) * (float)h + ofv * (2.f / 127.f);
  gy = fminf(fmaxf(gy, -1.f), 1.f);
  float py = (gy + 1.f) * 0.5f * 127.f;
  py = fminf(fmaxf(py, 0.f), 127.f);
  float y0f = floorf(py);
  float wy = py - y0f;
  int y0 = (int)y0f;
  int y1 = min(y0 + 1, 127);
  const float* xfb = (const float*)x + (size_t)b * 128 * 16384;
  const unsigned short* xbb = (const unsigned short*)x + (size_t)b * 128 * 16384;
  for (int c = half * 64; c < half * 64 + 64; ++c) {
    size_t o0 = (size_t)c * 16384 + y0 * 128 + w;
    size_t o1 = (size_t)c * 16384 + y1 * 128 + w;
    float v0, v1;
    if (f32x) { v0 = xfb[o0]; v1 = xfb[o1]; }
    else      { v0 = b2f(xbb[o0]); v1 = b2f(xbb[o1]); }
    t[c * 129 + w] = v0 + wy * (v1 - v0);
  }
  __syncthreads();
  int c = threadIdx.x & 127;
  unsigned short* spb = seqb + (size_t)blockIdx.x * 16384;
  for (int l = half * 64; l < half * 64 + 64; ++l)
    spb[l * 128 + c] = f2b(t[c * 129 + l]);
}

// ---------------- G1 MFMA: z(bf16)/xBC(bf16) = seq @ wproj^T ---------------------
__global__ __launch_bounds__(256) void k_gemm1_mf(const unsigned short* __restrict__ seqb,
                                                  const unsigned short* __restrict__ wprojh,
                                                  unsigned short* __restrict__ zb,
                                                  unsigned short* __restrict__ xbcb) {
  __shared__ __align__(16) unsigned short Al[128 * 136];
  __shared__ __align__(16) unsigned short Bl[128 * 136];
  int m0 = blockIdx.x * 128;
  int e0 = blockIdx.y * 128;   // 0..512; covers e<640 exactly
  for (int i = threadIdx.x; i < 2048; i += 256) {
    int row = i >> 4, ch = i & 15;
    *(float4*)&Al[row * 136 + ch * 8] =
        *(const float4*)&seqb[(size_t)(m0 + row) * 128 + ch * 8];
    *(float4*)&Bl[row * 136 + ch * 8] =
        *(const float4*)&wprojh[(size_t)(e0 + row) * 128 + ch * 8];
  }
  __syncthreads();
  int lane = threadIdx.x & 63;
  int wv = threadIdx.x >> 6;
  int wm = wv >> 1, wn = wv & 1;
  int lr = lane & 15;
  int kb = lane >> 4;
  f32x4 acc[4][4] = {};
#pragma unroll
  for (int kk = 0; kk < 4; ++kk) {
    bf16x8 af[4], bf[4];
#pragma unroll
    for (int f = 0; f < 4; ++f)
      af[f] = *(const bf16x8*)&Al[(wm * 64 + f * 16 + lr) * 136 + kk * 32 + kb * 8];
#pragma unroll
    for (int f = 0; f < 4; ++f)
      bf[f] = *(const bf16x8*)&Bl[(wn * 64 + f * 16 + lr) * 136 + kk * 32 + kb * 8];
#pragma unroll
    for (int fm = 0; fm < 4; ++fm)
#pragma unroll
      for (int fn = 0; fn < 4; ++fn)
        acc[fm][fn] = __builtin_amdgcn_mfma_f32_16x16x32_bf16(af[fm], bf[fn],
                                                              acc[fm][fn], 0, 0, 0);
  }
#pragma unroll
  for (int fm = 0; fm < 4; ++fm)
#pragma unroll
    for (int fn = 0; fn < 4; ++fn) {
      int e = e0 + wn * 64 + fn * 16 + lr;
#pragma unroll
      for (int r = 0; r < 4; ++r) {
        int m = m0 + wm * 64 + fm * 16 + kb * 4 + r;
        float v = acc[fm][fn][r];
        if (e < 256) zb[(size_t)m * 256 + e] = f2b(v);
        else         xbcb[(size_t)m * 384 + (e - 256)] = f2b(v);
      }
    }
}

// ---------------- K_dt: dt columns (bf16 activations x f32 weights) --------------
__global__ __launch_bounds__(256) void k_dt(const unsigned short* __restrict__ seqb,
                                            const float* __restrict__ P,
                                            float* __restrict__ dtb) {
  int bb = blockIdx.x;            // CH*4 blocks; 32 tokens each
  int sq = bb >> 2, q = bb & 3;
  __shared__ float ss[32 * 133];
  __shared__ float wt[1024];
  const unsigned short* sp = seqb + (size_t)sq * 16384 + q * 32 * 128;
  for (int i = threadIdx.x; i < 1024; i += 256) {
    int idx = i * 4;
    int t = idx >> 7, k = idx & 127;
    ushort4 r4 = *(const ushort4*)&sp[idx];
    ss[t * 133 + k + 0] = b2f(r4.x);
    ss[t * 133 + k + 1] = b2f(r4.y);
    ss[t * 133 + k + 2] = b2f(r4.z);
    ss[t * 133 + k + 3] = b2f(r4.w);
  }
  for (int i = threadIdx.x; i < 1024; i += 256) wt[i] = P[P_WDT + i];
  __syncthreads();
  int head = threadIdx.x >> 5, t = threadIdx.x & 31;
  const float* wh = &wt[head * 128];
  const float* sr = &ss[t * 133];
  float acc = 0.f;
#pragma unroll 8
  for (int k = 0; k < 128; ++k) acc += sr[k] * wh[k];
  float dv = acc + P[P_DTB + head];
  float spv = (dv > 20.f) ? dv : log1pf(__expf(dv));
  dtb[((size_t)sq * 128 + q * 32 + t) * 8 + head] = spv;
}

// ---------------- K6 v9: fused conv1d+SiLU+scan, split ys (lo aliases seqb) ------
__global__ __launch_bounds__(512) void k_scan_v9(const unsigned short* __restrict__ xbcb,
                                                 const float* __restrict__ dtb,
                                                 const float* __restrict__ P,
                                                 unsigned short* __restrict__ ys_lo,
                                                 unsigned short* __restrict__ ys_hi) {
  int seq = blockIdx.x;
  int head = threadIdx.x >> 6;          // one wave per head
  int dduo = (threadIdx.x >> 2) & 15;   // d = dduo*2 + {0,1}
  int squad = threadIdx.x & 3;          // s-range squad*16 .. +15
  float A = -__expf(P[P_ALOG + head]);
  float Dk = P[P_DSKIP + head];
  float h0[16], h1[16];
#pragma unroll
  for (int s = 0; s < 16; ++s) { h0[s] = 0.f; h1[s] = 0.f; }
  __shared__ __align__(16) float sRAW[19][388];  // raw rows lt-3..lt+15; conv'd in place
  __shared__ float sDT[16][8];
  const unsigned short* base = xbcb + (size_t)seq * 49152;
  const float* dtp = dtb + (size_t)seq * 1024;
  unsigned int* ylo = (unsigned int*)(ys_lo + (size_t)seq * 16384);
  unsigned int* yhi = (unsigned int*)(ys_hi + (size_t)seq * 16384);
  const int sbase = 256 + squad * 16;
  const int cbase = sbase + 64;
  for (int lt = 0; lt < 128; lt += 16) {
    // Stage raw rows l = lt-3 .. lt+15 (19 rows x 384 bf16 -> f32 LDS).
    for (int i = threadIdx.x; i < 912; i += 512) {
      int r = i / 48, c8 = (i % 48) * 8;
      int l = lt - 3 + r;
      float4 lo = make_float4(0.f, 0.f, 0.f, 0.f), hi = lo;
      if (l >= 0) {
        ushort4 a = *(const ushort4*)&base[(size_t)l * 384 + c8];
        ushort4 b = *(const ushort4*)&base[(size_t)l * 384 + c8 + 4];
        lo = make_float4(b2f(a.x), b2f(a.y), b2f(a.z), b2f(a.w));
        hi = make_float4(b2f(b.x), b2f(b.y), b2f(b.z), b2f(b.w));
      }
      *(float4*)&sRAW[r][c8] = lo;
      *(float4*)&sRAW[r][c8 + 4] = hi;
    }
    if (threadIdx.x < 128)
      sDT[threadIdx.x >> 3][threadIdx.x & 7] =
          dtp[(lt + (threadIdx.x >> 3)) * 8 + (threadIdx.x & 7)];
    __syncthreads();
    // In-place conv: thread e (e<384) owns column e, serial over 16 rows.
    if (threadIdx.x < 384) {
      int e = threadIdx.x;
      float w0 = P[P_CW + e * 4 + 0], w1 = P[P_CW + e * 4 + 1];
      float w2 = P[P_CW + e * 4 + 2], w3 = P[P_CW + e * 4 + 3];
      float bb = P[P_CB + e];
      float x0 = sRAW[0][e], x1 = sRAW[1][e], x2 = sRAW[2][e];
#pragma unroll
      for (int ll = 0; ll < 16; ++ll) {
        float x3 = sRAW[ll + 3][e];
        float a = bb + w0 * x0 + w1 * x1 + w2 * x2 + w3 * x3;
        sRAW[ll + 3][e] = a / (1.f + __expf(-a));  // conv'd row ll
        x0 = x1; x1 = x2; x2 = x3;
      }
    }
    __syncthreads();
    unsigned int* yp = (lt < 64) ? ylo : yhi;
    int lrel0 = (lt < 64) ? lt : lt - 64;
#pragma unroll 1
    for (int ll = 0; ll < 16; ++ll) {
      const float* row = sRAW[ll + 3];
      float dt = sDT[ll][head];
      float dA = __expf(dt * A);
      float2 xv = *(const float2*)&row[head * 32 + dduo * 2];
      float c0 = dt * xv.x, c1 = dt * xv.y;
      float a0 = 0.f, b0 = 0.f, a1 = 0.f, b1 = 0.f;
#pragma unroll
      for (int s4 = 0; s4 < 4; ++s4) {
        float4 bb = *(const float4*)&row[sbase + s4 * 4];
        float4 cc = *(const float4*)&row[cbase + s4 * 4];
        h0[s4 * 4 + 0] = h0[s4 * 4 + 0] * dA + c0 * bb.x; a0 += h0[s4 * 4 + 0] * cc.x;
        h0[s4 * 4 + 1] = h0[s4 * 4 + 1] * dA + c0 * bb.y; b0 += h0[s4 * 4 + 1] * cc.y;
        h0[s4 * 4 + 2] = h0[s4 * 4 + 2] * dA + c0 * bb.z; a0 += h0[s4 * 4 + 2] * cc.z;
        h0[s4 * 4 + 3] = h0[s4 * 4 + 3] * dA + c0 * bb.w; b0 += h0[s4 * 4 + 3] * cc.w;
        h1[s4 * 4 + 0] = h1[s4 * 4 + 0] * dA + c1 * bb.x; a1 += h1[s4 * 4 + 0] * cc.x;
        h1[s4 * 4 + 1] = h1[s4 * 4 + 1] * dA + c1 * bb.y; b1 += h1[s4 * 4 + 1] * cc.y;
        h1[s4 * 4 + 2] = h1[s4 * 4 + 2] * dA + c1 * bb.z; a1 += h1[s4 * 4 + 2] * cc.z;
        h1[s4 * 4 + 3] = h1[s4 * 4 + 3] * dA + c1 * bb.w; b1 += h1[s4 * 4 + 3] * cc.w;
      }
      float y0 = quad_sum(a0 + b0);
      float y1 = quad_sum(a1 + b1);
      if (squad == 0) {
        unsigned int pk = (unsigned int)f2b(y0 + Dk * xv.x) |
                          ((unsigned int)f2b(y1 + Dk * xv.y) << 16);
        yp[((lrel0 + ll) * 256 + head * 32 + dduo * 2) >> 1] = pk;
      }
    }
    __syncthreads();
  }
}

// ---------------- G2 v3: FUSED gate+RMS + out GEMM, split ys ---------------------
// out[t,c] = r[t] * sum_k (y[t,k]*ng[k]) * w[c,k], y = ys*silu(z).
// Block = one seq (128 tokens); tokens 0..63 in ys_lo, 64..127 in ys_hi.
__global__ __launch_bounds__(256) void k_gemm2_f(const unsigned short* __restrict__ ys_lo,
                                                 const unsigned short* __restrict__ ys_hi,
                                                 const unsigned short* __restrict__ zb,
                                                 const unsigned short* __restrict__ outwh,
                                                 float* __restrict__ dout,
                                                 int tok0) {
  __shared__ __align__(16) unsigned short Al[128 * 136];
  __shared__ __align__(16) unsigned short Bl[128 * 136];
  __shared__ float rr[128];
  int seq = blockIdx.x;
  int t0 = seq * 128;
  const unsigned short* ylo = ys_lo + (size_t)seq * 16384;
  const unsigned short* yhi = ys_hi + (size_t)seq * 16384;
  // Pre-pass: r[t]. Thread -> (row = tid>>1, half = tid&1), 128 elems each.
  {
    int row = threadIdx.x >> 1, half = threadIdx.x & 1;
    const unsigned short* yrow = (row < 64)
        ? &ylo[(size_t)row * 256 + half * 128]
        : &yhi[(size_t)(row - 64) * 256 + half * 128];
    const unsigned short* zrow = &zb[(size_t)(t0 + row) * 256 + half * 128];
    float ssum = 0.f;
#pragma unroll 4
    for (int it = 0; it < 16; ++it) {
      ushort4 ya = *(const ushort4*)&yrow[it * 8];
      ushort4 yb4 = *(const ushort4*)&yrow[it * 8 + 4];
      ushort4 za = *(const ushort4*)&zrow[it * 8];
      ushort4 zb4 = *(const ushort4*)&zrow[it * 8 + 4];
      float yv[8] = {b2f(ya.x), b2f(ya.y), b2f(ya.z), b2f(ya.w),
                     b2f(yb4.x), b2f(yb4.y), b2f(yb4.z), b2f(yb4.w)};
      float zv[8] = {b2f(za.x), b2f(za.y), b2f(za.z), b2f(za.w),
                     b2f(zb4.x), b2f(zb4.y), b2f(zb4.z), b2f(zb4.w)};
#pragma unroll
      for (int j = 0; j < 8; ++j) {
        float y = yv[j] * (zv[j] / (1.f + __expf(-zv[j])));
        ssum += y * y;
      }
    }
    ssum += __shfl_xor(ssum, 1, 64);
    if (half == 0) rr[row] = rsqrtf(ssum * (1.f / 256.f) + 1e-5f);
  }
  __syncthreads();
  int lane = threadIdx.x & 63;
  int wv = threadIdx.x >> 6;
  int wm = wv >> 1, wn = wv & 1;
  int lr = lane & 15;
  int kb = lane >> 4;
  f32x4 acc[4][4] = {};
  for (int kt = 0; kt < 256; kt += 128) {
    for (int i = threadIdx.x; i < 2048; i += 256) {
      int row = i >> 4, ch = i & 15;
      const unsigned short* yrow = (row < 64)
          ? &ylo[(size_t)row * 256 + kt + ch * 8]
          : &yhi[(size_t)(row - 64) * 256 + kt + ch * 8];
      const unsigned short* zrow = &zb[(size_t)(t0 + row) * 256 + kt + ch * 8];
      ushort4 ya = *(const ushort4*)yrow;
      ushort4 yb4 = *(const ushort4*)(yrow + 4);
      ushort4 za = *(const ushort4*)zrow;
      ushort4 zb4 = *(const ushort4*)(zrow + 4);
      float yv[8] = {b2f(ya.x), b2f(ya.y), b2f(ya.z), b2f(ya.w),
                     b2f(yb4.x), b2f(yb4.y), b2f(yb4.z), b2f(yb4.w)};
      float zv[8] = {b2f(za.x), b2f(za.y), b2f(za.z), b2f(za.w),
                     b2f(zb4.x), b2f(zb4.y), b2f(zb4.z), b2f(zb4.w)};
      unsigned short o[8];
#pragma unroll
      for (int j = 0; j < 8; ++j)
        o[j] = f2b(yv[j] * (zv[j] / (1.f + __expf(-zv[j]))));
      *(ushort4*)&Al[row * 136 + ch * 8] = make_ushort4(o[0], o[1], o[2], o[3]);
      *(ushort4*)&Al[row * 136 + ch * 8 + 4] = make_ushort4(o[4], o[5], o[6], o[7]);
      *(float4*)&Bl[row * 136 + ch * 8] =
          *(const float4*)&outwh[(size_t)row * 256 + kt + ch * 8];
    }
    __syncthreads();
#pragma unroll
    for (int kk = 0; kk < 4; ++kk) {
      bf16x8 af[4], bf[4];
#pragma unroll
      for (int f = 0; f < 4; ++f)
        af[f] = *(const bf16x8*)&Al[(wm * 64 + f * 16 + lr) * 136 + kk * 32 + kb * 8];
#pragma unroll
      for (int f = 0; f < 4; ++f)
        bf[f] = *(const bf16x8*)&Bl[(wn * 64 + f * 16 + lr) * 136 + kk * 32 + kb * 8];
#pragma unroll
      for (int fm = 0; fm < 4; ++fm)
#pragma unroll
        for (int fn = 0; fn < 4; ++fn)
          acc[fm][fn] = __builtin_amdgcn_mfma_f32_16x16x32_bf16(af[fm], bf[fn],
                                                                acc[fm][fn], 0, 0, 0);
    }
    __syncthreads();
  }
#pragma unroll
  for (int fm = 0; fm < 4; ++fm)
#pragma unroll
    for (int fn = 0; fn < 4; ++fn) {
      int cc = wn * 64 + fn * 16 + lr;
#pragma unroll
      for (int r = 0; r < 4; ++r) {
        int rowl = wm * 64 + fm * 16 + kb * 4 + r;
        int l = tok0 + t0 + rowl;
        int b = l >> 14, rem = l & 16383;
        int hh = rem >> 7, ww = rem & 127;
        dout[(((size_t)(b * 128 + cc) * 128 + hh) * 128 + ww)] =
            acc[fm][fn][r] * rr[rowl];
      }
    }
}

extern "C" void kernel_launch(void* const* d_in, const int* in_sizes, int n_in,
                              void* d_out, int out_size, void* d_ws, size_t ws_size,
                              hipStream_t stream) {
  const void* x      = d_in[0];
  const void* dww    = d_in[1];
  const void* gng    = d_in[2];
  const void* gnb    = d_in[3];
  const void* pww    = d_in[4];
  const void* pwb    = d_in[5];
  const void* wproj  = d_in[6];
  const void* cw     = d_in[7];
  const void* cb     = d_in[8];
  const void* dtbias = d_in[9];
  const void* alog   = d_in[10];
  const void* dskip  = d_in[11];
  const void* ng     = d_in[12];
  const void* outw   = d_in[13];
  float* out = (float*)d_out;

  char* ws = (char*)d_ws;
  float* gst            = (float*)(ws + 0);
  float* mr             = (float*)(ws + 4096);
  float* P              = (float*)(ws + 8192);
  unsigned short* wpjh  = (unsigned short*)(ws + 40960);   // 648*128*2 = 165,888
  unsigned short* outwh = (unsigned short*)(ws + 372736);  // 128*256*2 = 65,536
  float* offf           = (float*)(ws + 503808);
  char* cbase           = ws + 1028096;

  // h1 (f32) lives in d_out's out_2d region.
  float* h1f = out;

  // Per-sequence chunk bytes with ys_lo aliasing seqb (seqb dead after k_dt):
  //   seqb/ys_lo 32768 + zb 65536 + xbcb 98304 + dtb 4096 + ys_hi 32768
  //   = 233,472  -> CH=1024 needs 240MB (ws ~256MB) -> NC=1.
  const int opts[11] = {1024, 512, 256, 128, 64, 32, 16, 8, 4, 2, 1};
  int CH = 1;
  for (int i = 0; i < 11; ++i) {
    if (1028096ull + (unsigned long long)opts[i] * 233472ull <= (unsigned long long)ws_size) {
      CH = opts[i];
      break;
    }
  }
  int NC = 1024 / CH;

  unsigned short* seqb = (unsigned short*)(cbase);           // aliased by ys_lo
  unsigned short* zb   = (unsigned short*)(cbase + (size_t)CH * 32768);
  unsigned short* xbcb = (unsigned short*)(cbase + (size_t)CH * 98304);
  float* dtbf          = (float*)(cbase + (size_t)CH * 196608);
  unsigned short* yshi = (unsigned short*)(cbase + (size_t)CH * 200704);

  k_prep_params<<<1, 256, 0, stream>>>(dww, cw, cb, gng, gnb, pww, pwb, dtbias,
                                       alog, dskip, ng, wproj, P, gst);
  k_prep_w<<<128, 256, 0, stream>>>(wproj, outw, gng, ng, wpjh, outwh);
  k_dwconv_v2<<<1024, 256, 0, stream>>>(x, gng, P, h1f, gst);
  k_stats<<<1, 64, 0, stream>>>(gst, mr);
  k_gn_off<<<1024, 128, 0, stream>>>(h1f, mr, P, offf, out);

  for (int c = 0; c < NC; ++c) {
    int s0 = c * CH;
    k_deform_v4<<<CH, 256, 0, stream>>>(x, gng, offf, seqb, s0);
    k_gemm1_mf<<<dim3(CH, 5), 256, 0, stream>>>(seqb, wpjh, zb, xbcb);
    k_dt<<<CH * 4, 256, 0, stream>>>(seqb, P, dtbf);
    k_scan_v9<<<CH, 512, 0, stream>>>(xbcb, dtbf, P, seqb /*ys_lo*/, yshi);
    k_gemm2_f<<<CH, 256, 0, stream>>>(seqb /*ys_lo*/, yshi, zb, outwh, out, s0 * 128);
  }
}